// Round 1
// baseline (6950.629 us; speedup 1.0000x reference)
//
#include <hip/hip_runtime.h>

constexpr int F_IN = 128;
constexpr int KC   = 128;   // K_CLUST == F_EMB == 128
constexpr int F2   = 256;   // K_CLUST + F_EMB

// ---------------------------------------------------------------------------
// K1: XW = x @ [W_pool | W_embed]   ([N,128] @ [128,256] -> [N,256])
// One block = 32 rows x 256 cols. x tile in LDS (broadcast reads), W streamed
// from L2 (128 KB total, resident).
// ---------------------------------------------------------------------------
__global__ __launch_bounds__(256) void gemm_xw_kernel(
    const float* __restrict__ x, const float* __restrict__ Wp,
    const float* __restrict__ We, float* __restrict__ xw, int n_nodes)
{
    constexpr int RPB = 32;
    __shared__ float xs[RPB][F_IN];
    const int r0 = blockIdx.x * RPB;
    const int tid = threadIdx.x;
    for (int i = tid; i < RPB * F_IN; i += 256) {
        int r = i >> 7, c = i & 127;
        int gr = r0 + r;
        xs[r][c] = (gr < n_nodes) ? x[(size_t)gr * F_IN + c] : 0.f;
    }
    __syncthreads();
    const int col = tid;                       // 0..255
    const float* W = (col < KC) ? (Wp + col) : (We + (col - KC));
    float acc[RPB];
#pragma unroll
    for (int r = 0; r < RPB; ++r) acc[r] = 0.f;
    for (int k = 0; k < F_IN; ++k) {
        float w = W[(size_t)k * KC];
        const float* xk = &xs[0][k];
#pragma unroll
        for (int r = 0; r < RPB; ++r) acc[r] += xk[r * F_IN] * w;  // LDS broadcast
    }
#pragma unroll
    for (int r = 0; r < RPB; ++r) {
        int gr = r0 + r;
        if (gr < n_nodes) xw[(size_t)gr * F2 + col] = acc[r];
    }
}

// ---------------------------------------------------------------------------
// K2: pq[row] += val * xw[col]  over all edges (256 cols). One wave per edge,
// float4 gather (1 KB contiguous per wave), 4 atomicAdds per lane.
// ---------------------------------------------------------------------------
__global__ __launch_bounds__(256) void spmm_dual_kernel(
    const int* __restrict__ erow, const int* __restrict__ ecol,
    const float* __restrict__ eval_, const float* __restrict__ xw,
    float* __restrict__ pq, int n_edges)
{
    int e = blockIdx.x * 4 + (threadIdx.x >> 6);
    if (e >= n_edges) return;
    int lane = threadIdx.x & 63;
    int r = erow[e], c = ecol[e];
    float v = eval_[e];
    const float4* src = (const float4*)(xw + (size_t)c * F2);
    float* dst = pq + (size_t)r * F2;
    float4 s = src[lane];
    int f = lane * 4;
    atomicAdd(&dst[f + 0], v * s.x);
    atomicAdd(&dst[f + 1], v * s.y);
    atomicAdd(&dst[f + 2], v * s.z);
    atomicAdd(&dst[f + 3], v * s.w);
}

// ---------------------------------------------------------------------------
// K3: S = softmax(relu(P)) rowwise (cols 0..127 of pq), Z = relu(Q) in place
// (cols 128..255). One wave per node.
// ---------------------------------------------------------------------------
__global__ __launch_bounds__(64) void softmax_relu_kernel(
    float* __restrict__ pq, int n_nodes)
{
    int n = blockIdx.x;
    if (n >= n_nodes) return;
    int lane = threadIdx.x;
    float* p = pq + (size_t)n * F2;
    float a0 = fmaxf(p[lane], 0.f);
    float a1 = fmaxf(p[lane + 64], 0.f);
    float m = fmaxf(a0, a1);
#pragma unroll
    for (int off = 32; off; off >>= 1) m = fmaxf(m, __shfl_xor(m, off));
    float e0 = __expf(a0 - m), e1 = __expf(a1 - m);
    float ssum = e0 + e1;
#pragma unroll
    for (int off = 32; off; off >>= 1) ssum += __shfl_xor(ssum, off);
    float inv = 1.f / ssum;
    p[lane]      = e0 * inv;
    p[lane + 64] = e1 * inv;
    p[lane + 128] = fmaxf(p[lane + 128], 0.f);
    p[lane + 192] = fmaxf(p[lane + 192], 0.f);
}

// ---------------------------------------------------------------------------
// K4: AS[row] += val * S[col]  (128 cols; S = pq[:, 0:128], stride 256).
// ---------------------------------------------------------------------------
__global__ __launch_bounds__(256) void spmm_s_kernel(
    const int* __restrict__ erow, const int* __restrict__ ecol,
    const float* __restrict__ eval_, const float* __restrict__ pq,
    float* __restrict__ as_, int n_edges)
{
    int e = blockIdx.x * 4 + (threadIdx.x >> 6);
    if (e >= n_edges) return;
    int lane = threadIdx.x & 63;
    int r = erow[e], c = ecol[e];
    float v = eval_[e];
    const float2* src = (const float2*)(pq + (size_t)c * F2);
    float* dst = as_ + (size_t)r * KC;
    float2 s = src[lane];
    int f = lane * 2;
    atomicAdd(&dst[f + 0], v * s.x);
    atomicAdd(&dst[f + 1], v * s.y);
}

// ---------------------------------------------------------------------------
// K5: coarse_A = S^T @ AS (which=0), coarse_X = S^T @ Z (which=1).
// Each block: 256 threads hold a full 128x128 partial in registers
// (64 f32/thread), S rows staged 8-at-a-time in LDS (broadcast float4 reads),
// one atomicAdd pass at the end.
// ---------------------------------------------------------------------------
__global__ __launch_bounds__(256) void coarse_kernel(
    const float* __restrict__ pq, const float* __restrict__ as_,
    float* __restrict__ out, int n_nodes)
{
    const int which = blockIdx.y;
    const int tid = threadIdx.x;
    const int f  = tid & 127;          // output column
    const int k0 = (tid >> 7) * 64;    // output row range [k0, k0+64)
    __shared__ float sS[8][128];
    float acc[64];
#pragma unroll
    for (int i = 0; i < 64; ++i) acc[i] = 0.f;
    const int stride = gridDim.x * 8;
    for (int n0 = blockIdx.x * 8; n0 < n_nodes; n0 += stride) {
        __syncthreads();
        for (int i = tid; i < 8 * 128; i += 256) {
            int rr = i >> 7, cc = i & 127;
            int n = n0 + rr;
            sS[rr][cc] = (n < n_nodes) ? pq[(size_t)n * F2 + cc] : 0.f;
        }
        __syncthreads();
        int rmax = (n_nodes - n0 < 8) ? (n_nodes - n0) : 8;
        for (int rr = 0; rr < rmax; ++rr) {
            int n = n0 + rr;
            float v = which ? pq[(size_t)n * F2 + KC + f]
                            : as_[(size_t)n * KC + f];
            const float4* s4 = (const float4*)(&sS[rr][k0]);
#pragma unroll
            for (int i = 0; i < 16; ++i) {
                float4 sv = s4[i];
                acc[4 * i + 0] += sv.x * v;
                acc[4 * i + 1] += sv.y * v;
                acc[4 * i + 2] += sv.z * v;
                acc[4 * i + 3] += sv.w * v;
            }
        }
    }
    float* o = out + (size_t)which * (KC * KC);
#pragma unroll
    for (int i = 0; i < 64; ++i)
        atomicAdd(&o[(size_t)(k0 + i) * KC + f], acc[i]);
}

// ---------------------------------------------------------------------------
extern "C" void kernel_launch(void* const* d_in, const int* in_sizes, int n_in,
                              void* d_out, int out_size, void* d_ws, size_t ws_size,
                              hipStream_t stream)
{
    const float* x     = (const float*)d_in[0];
    const int*   erow  = (const int*)d_in[1];
    const int*   ecol  = (const int*)d_in[2];
    const float* eval_ = (const float*)d_in[3];
    const float* Wp    = (const float*)d_in[4];
    const float* We    = (const float*)d_in[5];
    float* out = (float*)d_out;

    const int n_nodes = in_sizes[0] / F_IN;
    const int n_edges = in_sizes[1];

    // Workspace layout (needs 2 * N * 256 * 4 = 102.4 MB):
    //   xw : [N,256]  (x@Wp | x@We); first 128 cols reused later as AS [N,128]
    //   pq : [N,256]  (P|Q) -> after softmax kernel holds (S|Z)
    float* xw  = (float*)d_ws;
    float* pq  = xw + (size_t)n_nodes * F2;
    float* as_ = xw;  // reuse: xw dead after spmm_dual

    hipMemsetAsync(pq, 0, (size_t)n_nodes * F2 * sizeof(float), stream);
    hipMemsetAsync(d_out, 0, (size_t)out_size * sizeof(float), stream);

    gemm_xw_kernel<<<(n_nodes + 31) / 32, 256, 0, stream>>>(x, Wp, We, xw, n_nodes);
    spmm_dual_kernel<<<(n_edges + 3) / 4, 256, 0, stream>>>(erow, ecol, eval_, xw, pq, n_edges);
    softmax_relu_kernel<<<n_nodes, 64, 0, stream>>>(pq, n_nodes);
    hipMemsetAsync(as_, 0, (size_t)n_nodes * KC * sizeof(float), stream);
    spmm_s_kernel<<<(n_edges + 3) / 4, 256, 0, stream>>>(erow, ecol, eval_, pq, as_, n_edges);
    coarse_kernel<<<dim3(128, 2), 256, 0, stream>>>(pq, as_, out, n_nodes);
}

// Round 2
// 917.740 us; speedup vs baseline: 7.5736x; 7.5736x over previous
//
#include <hip/hip_runtime.h>

constexpr int F_IN = 128;
constexpr int KC   = 128;   // K_CLUST == F_EMB == 128
constexpr int F2   = 256;   // K_CLUST + F_EMB

// ---------------------------------------------------------------------------
// K1: XW = x @ [W_pool | W_embed]   ([N,128] @ [128,256] -> [N,256])
// ---------------------------------------------------------------------------
__global__ __launch_bounds__(256) void gemm_xw_kernel(
    const float* __restrict__ x, const float* __restrict__ Wp,
    const float* __restrict__ We, float* __restrict__ xw, int n_nodes)
{
    constexpr int RPB = 32;
    __shared__ float xs[RPB][F_IN];
    const int r0 = blockIdx.x * RPB;
    const int tid = threadIdx.x;
    for (int i = tid; i < RPB * F_IN; i += 256) {
        int r = i >> 7, c = i & 127;
        int gr = r0 + r;
        xs[r][c] = (gr < n_nodes) ? x[(size_t)gr * F_IN + c] : 0.f;
    }
    __syncthreads();
    const int col = tid;
    const float* W = (col < KC) ? (Wp + col) : (We + (col - KC));
    float acc[RPB];
#pragma unroll
    for (int r = 0; r < RPB; ++r) acc[r] = 0.f;
    for (int k = 0; k < F_IN; ++k) {
        float w = W[(size_t)k * KC];
        const float* xk = &xs[0][k];
#pragma unroll
        for (int r = 0; r < RPB; ++r) acc[r] += xk[r * F_IN] * w;
    }
#pragma unroll
    for (int r = 0; r < RPB; ++r) {
        int gr = r0 + r;
        if (gr < n_nodes) xw[(size_t)gr * F2 + col] = acc[r];
    }
}

// ---------------------------------------------------------------------------
// CSR build: histogram -> exclusive scan -> scatter
// ---------------------------------------------------------------------------
__global__ __launch_bounds__(256) void hist_kernel(
    const int* __restrict__ erow, int* __restrict__ cnt, int n_edges)
{
    int e = blockIdx.x * 256 + threadIdx.x;
    if (e < n_edges) atomicAdd(&cnt[erow[e]], 1);
}

__global__ __launch_bounds__(1024) void scan_kernel(
    const int* __restrict__ cnt, int* __restrict__ row_start, int n)
{
    __shared__ int wsum[16];
    __shared__ int sbase;
    const int tid = threadIdx.x;
    const int lane = tid & 63, wid = tid >> 6;
    if (tid == 0) sbase = 0;
    __syncthreads();
    for (int base = 0; base < n; base += 1024) {
        int i = base + tid;
        int v = (i < n) ? cnt[i] : 0;
        int incl = v;
#pragma unroll
        for (int off = 1; off < 64; off <<= 1) {
            int t = __shfl_up(incl, off);
            if (lane >= off) incl += t;
        }
        if (lane == 63) wsum[wid] = incl;
        __syncthreads();
        if (tid == 0) {
            int s = 0;
#pragma unroll
            for (int w = 0; w < 16; ++w) { int t = wsum[w]; wsum[w] = s; s += t; }
        }
        __syncthreads();
        if (i < n) row_start[i] = sbase + wsum[wid] + incl - v;
        __syncthreads();
        if (tid == 1023) sbase += wsum[15] + incl;
        __syncthreads();
    }
    if (tid == 0) row_start[n] = sbase;
}

__global__ __launch_bounds__(256) void scatter_kernel(
    const int* __restrict__ erow, const int* __restrict__ ecol,
    const float* __restrict__ eval_, const int* __restrict__ row_start,
    int* __restrict__ cursor, int* __restrict__ ecol_s,
    float* __restrict__ eval_s, int n_edges)
{
    int e = blockIdx.x * 256 + threadIdx.x;
    if (e >= n_edges) return;
    int r = erow[e];
    int pos = row_start[r] + atomicAdd(&cursor[r], 1);
    ecol_s[pos] = ecol[e];
    eval_s[pos] = eval_[e];
}

// ---------------------------------------------------------------------------
// K2: CSR SpMM over 256 cols, one wave per row, fused relu+softmax epilogue.
// Lane l holds cols 4l..4l+3: lanes 0..31 = P (softmax), lanes 32..63 = Q (relu).
// ---------------------------------------------------------------------------
__global__ __launch_bounds__(256) void spmm_dual_csr(
    const int* __restrict__ row_start, const int* __restrict__ ecol_s,
    const float* __restrict__ eval_s, const float* __restrict__ xw,
    float* __restrict__ pq, int n_nodes)
{
    int row = blockIdx.x * 4 + (threadIdx.x >> 6);
    if (row >= n_nodes) return;
    int lane = threadIdx.x & 63;
    int beg = row_start[row], end = row_start[row + 1];

    float4 a0 = {0,0,0,0}, a1 = {0,0,0,0}, a2 = {0,0,0,0}, a3 = {0,0,0,0};
    int j = beg;
    for (; j + 3 < end; j += 4) {
        int   c0 = ecol_s[j],     c1 = ecol_s[j + 1];
        int   c2 = ecol_s[j + 2], c3 = ecol_s[j + 3];
        float v0 = eval_s[j],     v1 = eval_s[j + 1];
        float v2 = eval_s[j + 2], v3 = eval_s[j + 3];
        float4 s0 = ((const float4*)(xw + (size_t)c0 * F2))[lane];
        float4 s1 = ((const float4*)(xw + (size_t)c1 * F2))[lane];
        float4 s2 = ((const float4*)(xw + (size_t)c2 * F2))[lane];
        float4 s3 = ((const float4*)(xw + (size_t)c3 * F2))[lane];
        a0.x += v0 * s0.x; a0.y += v0 * s0.y; a0.z += v0 * s0.z; a0.w += v0 * s0.w;
        a1.x += v1 * s1.x; a1.y += v1 * s1.y; a1.z += v1 * s1.z; a1.w += v1 * s1.w;
        a2.x += v2 * s2.x; a2.y += v2 * s2.y; a2.z += v2 * s2.z; a2.w += v2 * s2.w;
        a3.x += v3 * s3.x; a3.y += v3 * s3.y; a3.z += v3 * s3.z; a3.w += v3 * s3.w;
    }
    for (; j < end; ++j) {
        int c = ecol_s[j];
        float v = eval_s[j];
        float4 s = ((const float4*)(xw + (size_t)c * F2))[lane];
        a0.x += v * s.x; a0.y += v * s.y; a0.z += v * s.z; a0.w += v * s.w;
    }
    float4 a;
    a.x = a0.x + a1.x + a2.x + a3.x;
    a.y = a0.y + a1.y + a2.y + a3.y;
    a.z = a0.z + a1.z + a2.z + a3.z;
    a.w = a0.w + a1.w + a2.w + a3.w;

    // relu
    a.x = fmaxf(a.x, 0.f); a.y = fmaxf(a.y, 0.f);
    a.z = fmaxf(a.z, 0.f); a.w = fmaxf(a.w, 0.f);

    // softmax over the 128 P values (lanes 0..31); xor offsets <32 stay in-half
    float m = fmaxf(fmaxf(a.x, a.y), fmaxf(a.z, a.w));
#pragma unroll
    for (int off = 16; off; off >>= 1) m = fmaxf(m, __shfl_xor(m, off));
    float ex = __expf(a.x - m), ey = __expf(a.y - m);
    float ez = __expf(a.z - m), ew = __expf(a.w - m);
    float ssum = ex + ey + ez + ew;
#pragma unroll
    for (int off = 16; off; off >>= 1) ssum += __shfl_xor(ssum, off);
    float inv = 1.f / ssum;

    float4 w;
    bool isP = lane < 32;
    w.x = isP ? ex * inv : a.x;
    w.y = isP ? ey * inv : a.y;
    w.z = isP ? ez * inv : a.z;
    w.w = isP ? ew * inv : a.w;
    ((float4*)(pq + (size_t)row * F2))[lane] = w;
}

// ---------------------------------------------------------------------------
// K4: AS = A @ S via CSR (128 cols, S = pq[:,0:128] stride 256), float2/lane.
// ---------------------------------------------------------------------------
__global__ __launch_bounds__(256) void spmm_s_csr(
    const int* __restrict__ row_start, const int* __restrict__ ecol_s,
    const float* __restrict__ eval_s, const float* __restrict__ pq,
    float* __restrict__ as_, int n_nodes)
{
    int row = blockIdx.x * 4 + (threadIdx.x >> 6);
    if (row >= n_nodes) return;
    int lane = threadIdx.x & 63;
    int beg = row_start[row], end = row_start[row + 1];

    float2 a0 = {0,0}, a1 = {0,0}, a2 = {0,0}, a3 = {0,0};
    int j = beg;
    for (; j + 3 < end; j += 4) {
        int   c0 = ecol_s[j],     c1 = ecol_s[j + 1];
        int   c2 = ecol_s[j + 2], c3 = ecol_s[j + 3];
        float v0 = eval_s[j],     v1 = eval_s[j + 1];
        float v2 = eval_s[j + 2], v3 = eval_s[j + 3];
        float2 s0 = ((const float2*)(pq + (size_t)c0 * F2))[lane];
        float2 s1 = ((const float2*)(pq + (size_t)c1 * F2))[lane];
        float2 s2 = ((const float2*)(pq + (size_t)c2 * F2))[lane];
        float2 s3 = ((const float2*)(pq + (size_t)c3 * F2))[lane];
        a0.x += v0 * s0.x; a0.y += v0 * s0.y;
        a1.x += v1 * s1.x; a1.y += v1 * s1.y;
        a2.x += v2 * s2.x; a2.y += v2 * s2.y;
        a3.x += v3 * s3.x; a3.y += v3 * s3.y;
    }
    for (; j < end; ++j) {
        int c = ecol_s[j];
        float v = eval_s[j];
        float2 s = ((const float2*)(pq + (size_t)c * F2))[lane];
        a0.x += v * s.x; a0.y += v * s.y;
    }
    float2 r;
    r.x = a0.x + a1.x + a2.x + a3.x;
    r.y = a0.y + a1.y + a2.y + a3.y;
    ((float2*)(as_ + (size_t)row * KC))[lane] = r;
}

// ---------------------------------------------------------------------------
// K5: coarse_A = S^T @ AS (which=0), coarse_X = S^T @ Z (which=1).
// ---------------------------------------------------------------------------
__global__ __launch_bounds__(256) void coarse_kernel(
    const float* __restrict__ pq, const float* __restrict__ as_,
    float* __restrict__ out, int n_nodes)
{
    const int which = blockIdx.y;
    const int tid = threadIdx.x;
    const int f  = tid & 127;
    const int k0 = (tid >> 7) * 64;
    __shared__ float sS[8][128];
    float acc[64];
#pragma unroll
    for (int i = 0; i < 64; ++i) acc[i] = 0.f;
    const int stride = gridDim.x * 8;
    for (int n0 = blockIdx.x * 8; n0 < n_nodes; n0 += stride) {
        __syncthreads();
        for (int i = tid; i < 8 * 128; i += 256) {
            int rr = i >> 7, cc = i & 127;
            int n = n0 + rr;
            sS[rr][cc] = (n < n_nodes) ? pq[(size_t)n * F2 + cc] : 0.f;
        }
        __syncthreads();
        int rmax = (n_nodes - n0 < 8) ? (n_nodes - n0) : 8;
        for (int rr = 0; rr < rmax; ++rr) {
            int n = n0 + rr;
            float v = which ? pq[(size_t)n * F2 + KC + f]
                            : as_[(size_t)n * KC + f];
            const float4* s4 = (const float4*)(&sS[rr][k0]);
#pragma unroll
            for (int i = 0; i < 16; ++i) {
                float4 sv = s4[i];
                acc[4 * i + 0] += sv.x * v;
                acc[4 * i + 1] += sv.y * v;
                acc[4 * i + 2] += sv.z * v;
                acc[4 * i + 3] += sv.w * v;
            }
        }
    }
    float* o = out + (size_t)which * (KC * KC);
#pragma unroll
    for (int i = 0; i < 64; ++i)
        atomicAdd(&o[(size_t)(k0 + i) * KC + f], acc[i]);
}

// ---------------------------------------------------------------------------
// Fallback atomic SpMM path (used only if ws_size too small for CSR arrays)
// ---------------------------------------------------------------------------
__global__ __launch_bounds__(256) void spmm_dual_kernel(
    const int* __restrict__ erow, const int* __restrict__ ecol,
    const float* __restrict__ eval_, const float* __restrict__ xw,
    float* __restrict__ pq, int n_edges)
{
    int e = blockIdx.x * 4 + (threadIdx.x >> 6);
    if (e >= n_edges) return;
    int lane = threadIdx.x & 63;
    int r = erow[e], c = ecol[e];
    float v = eval_[e];
    const float4* src = (const float4*)(xw + (size_t)c * F2);
    float* dst = pq + (size_t)r * F2;
    float4 s = src[lane];
    int f = lane * 4;
    atomicAdd(&dst[f + 0], v * s.x);
    atomicAdd(&dst[f + 1], v * s.y);
    atomicAdd(&dst[f + 2], v * s.z);
    atomicAdd(&dst[f + 3], v * s.w);
}

__global__ __launch_bounds__(64) void softmax_relu_kernel(
    float* __restrict__ pq, int n_nodes)
{
    int n = blockIdx.x;
    if (n >= n_nodes) return;
    int lane = threadIdx.x;
    float* p = pq + (size_t)n * F2;
    float a0 = fmaxf(p[lane], 0.f);
    float a1 = fmaxf(p[lane + 64], 0.f);
    float m = fmaxf(a0, a1);
#pragma unroll
    for (int off = 32; off; off >>= 1) m = fmaxf(m, __shfl_xor(m, off));
    float e0 = __expf(a0 - m), e1 = __expf(a1 - m);
    float ssum = e0 + e1;
#pragma unroll
    for (int off = 32; off; off >>= 1) ssum += __shfl_xor(ssum, off);
    float inv = 1.f / ssum;
    p[lane]      = e0 * inv;
    p[lane + 64] = e1 * inv;
    p[lane + 128] = fmaxf(p[lane + 128], 0.f);
    p[lane + 192] = fmaxf(p[lane + 192], 0.f);
}

__global__ __launch_bounds__(256) void spmm_s_kernel(
    const int* __restrict__ erow, const int* __restrict__ ecol,
    const float* __restrict__ eval_, const float* __restrict__ pq,
    float* __restrict__ as_, int n_edges)
{
    int e = blockIdx.x * 4 + (threadIdx.x >> 6);
    if (e >= n_edges) return;
    int lane = threadIdx.x & 63;
    int r = erow[e], c = ecol[e];
    float v = eval_[e];
    const float2* src = (const float2*)(pq + (size_t)c * F2);
    float* dst = as_ + (size_t)r * KC;
    float2 s = src[lane];
    int f = lane * 2;
    atomicAdd(&dst[f + 0], v * s.x);
    atomicAdd(&dst[f + 1], v * s.y);
}

// ---------------------------------------------------------------------------
extern "C" void kernel_launch(void* const* d_in, const int* in_sizes, int n_in,
                              void* d_out, int out_size, void* d_ws, size_t ws_size,
                              hipStream_t stream)
{
    const float* x     = (const float*)d_in[0];
    const int*   erow  = (const int*)d_in[1];
    const int*   ecol  = (const int*)d_in[2];
    const float* eval_ = (const float*)d_in[3];
    const float* Wp    = (const float*)d_in[4];
    const float* We    = (const float*)d_in[5];
    float* out = (float*)d_out;

    const int n_nodes = in_sizes[0] / F_IN;
    const int n_edges = in_sizes[1];

    // Workspace layout:
    //   xw        [N*256] f32   (reused as AS [N*128] later)
    //   pq        [N*256] f32   (holds S|Z after spmm_dual_csr)
    //   row_start [N+1]   int
    //   cnt       [N]     int   (histogram, then reused as scatter cursor)
    //   ecol_s    [E]     int
    //   eval_s    [E]     f32
    float* xw  = (float*)d_ws;
    float* pq  = xw + (size_t)n_nodes * F2;
    int* row_start = (int*)(pq + (size_t)n_nodes * F2);
    int* cnt       = row_start + (n_nodes + 1);
    int* ecol_s    = cnt + n_nodes;
    float* eval_s  = (float*)(ecol_s + n_edges);
    float* as_ = xw;  // reuse: xw dead after spmm_dual_csr

    const size_t needed = ((size_t)(2 * n_nodes) * F2 + (size_t)(2 * n_nodes) + 1
                           + (size_t)(2 * n_edges)) * 4;

    hipMemsetAsync(d_out, 0, (size_t)out_size * sizeof(float), stream);
    gemm_xw_kernel<<<(n_nodes + 31) / 32, 256, 0, stream>>>(x, Wp, We, xw, n_nodes);

    if (ws_size >= needed) {
        // ---- CSR path ----
        hipMemsetAsync(cnt, 0, (size_t)n_nodes * sizeof(int), stream);
        hist_kernel<<<(n_edges + 255) / 256, 256, 0, stream>>>(erow, cnt, n_edges);
        scan_kernel<<<1, 1024, 0, stream>>>(cnt, row_start, n_nodes);
        hipMemsetAsync(cnt, 0, (size_t)n_nodes * sizeof(int), stream);
        scatter_kernel<<<(n_edges + 255) / 256, 256, 0, stream>>>(
            erow, ecol, eval_, row_start, cnt, ecol_s, eval_s, n_edges);

        spmm_dual_csr<<<(n_nodes + 3) / 4, 256, 0, stream>>>(
            row_start, ecol_s, eval_s, xw, pq, n_nodes);
        spmm_s_csr<<<(n_nodes + 3) / 4, 256, 0, stream>>>(
            row_start, ecol_s, eval_s, pq, as_, n_nodes);
    } else {
        // ---- fallback atomic path ----
        hipMemsetAsync(pq, 0, (size_t)n_nodes * F2 * sizeof(float), stream);
        spmm_dual_kernel<<<(n_edges + 3) / 4, 256, 0, stream>>>(
            erow, ecol, eval_, xw, pq, n_edges);
        softmax_relu_kernel<<<n_nodes, 64, 0, stream>>>(pq, n_nodes);
        hipMemsetAsync(as_, 0, (size_t)n_nodes * KC * sizeof(float), stream);
        spmm_s_kernel<<<(n_edges + 3) / 4, 256, 0, stream>>>(
            erow, ecol, eval_, pq, as_, n_edges);
    }

    coarse_kernel<<<dim3(128, 2), 256, 0, stream>>>(pq, as_, out, n_nodes);
}

// Round 3
// 662.248 us; speedup vs baseline: 10.4955x; 1.3858x over previous
//
#include <hip/hip_runtime.h>
#include <hip/hip_fp16.h>

constexpr int F_IN = 128;
constexpr int KC   = 128;   // K_CLUST == F_EMB == 128
constexpr int F2   = 256;   // K_CLUST + F_EMB

// ---------- fp16 pack/unpack helpers ----------
__device__ __forceinline__ float4 h8_to_f4(uint2 u) {
    union { unsigned int i; __half2 h; } a, b;
    a.i = u.x; b.i = u.y;
    float2 f0 = __half22float2(a.h);
    float2 f1 = __half22float2(b.h);
    return make_float4(f0.x, f0.y, f1.x, f1.y);
}
__device__ __forceinline__ unsigned int f2_to_h2u(float x, float y) {
    union { __half2 h; unsigned int i; } c;
    c.h = __floats2half2_rn(x, y);
    return c.i;
}
__device__ __forceinline__ float pe_val(unsigned int pe) {
    return __half2float(__ushort_as_half((unsigned short)(pe & 0xffffu)));
}

// ---------------------------------------------------------------------------
// K1: XW = x @ [W_pool | W_embed] -> fp16 [N,256]
// ---------------------------------------------------------------------------
__global__ __launch_bounds__(256) void gemm_xw_h(
    const float* __restrict__ x, const float* __restrict__ Wp,
    const float* __restrict__ We, __half* __restrict__ xwh, int n_nodes)
{
    constexpr int RPB = 32;
    __shared__ float xs[RPB][F_IN];
    const int r0 = blockIdx.x * RPB;
    const int tid = threadIdx.x;
    for (int i = tid; i < RPB * F_IN; i += 256) {
        int r = i >> 7, c = i & 127;
        int gr = r0 + r;
        xs[r][c] = (gr < n_nodes) ? x[(size_t)gr * F_IN + c] : 0.f;
    }
    __syncthreads();
    const int col = tid;
    const float* W = (col < KC) ? (Wp + col) : (We + (col - KC));
    float acc[RPB];
#pragma unroll
    for (int r = 0; r < RPB; ++r) acc[r] = 0.f;
    for (int k = 0; k < F_IN; ++k) {
        float w = W[(size_t)k * KC];
        const float* xk = &xs[0][k];
#pragma unroll
        for (int r = 0; r < RPB; ++r) acc[r] += xk[r * F_IN] * w;
    }
#pragma unroll
    for (int r = 0; r < RPB; ++r) {
        int gr = r0 + r;
        if (gr < n_nodes) xwh[(size_t)gr * F2 + col] = __float2half_rn(acc[r]);
    }
}

// ---------------------------------------------------------------------------
// CSR build: histogram -> exclusive scan -> scatter (packed col|half-val)
// ---------------------------------------------------------------------------
__global__ __launch_bounds__(256) void hist_kernel(
    const int* __restrict__ erow, int* __restrict__ cnt, int n_edges)
{
    int e = blockIdx.x * 256 + threadIdx.x;
    if (e < n_edges) atomicAdd(&cnt[erow[e]], 1);
}

__global__ __launch_bounds__(1024) void scan_kernel(
    const int* __restrict__ cnt, int* __restrict__ row_start, int n)
{
    __shared__ int wsum[16];
    __shared__ int sbase;
    const int tid = threadIdx.x;
    const int lane = tid & 63, wid = tid >> 6;
    if (tid == 0) sbase = 0;
    __syncthreads();
    for (int base = 0; base < n; base += 1024) {
        int i = base + tid;
        int v = (i < n) ? cnt[i] : 0;
        int incl = v;
#pragma unroll
        for (int off = 1; off < 64; off <<= 1) {
            int t = __shfl_up(incl, off);
            if (lane >= off) incl += t;
        }
        if (lane == 63) wsum[wid] = incl;
        __syncthreads();
        if (tid == 0) {
            int s = 0;
#pragma unroll
            for (int w = 0; w < 16; ++w) { int t = wsum[w]; wsum[w] = s; s += t; }
        }
        __syncthreads();
        if (i < n) row_start[i] = sbase + wsum[wid] + incl - v;
        __syncthreads();
        if (tid == 1023) sbase += wsum[15] + incl;
        __syncthreads();
    }
    if (tid == 0) row_start[n] = sbase;
}

__global__ __launch_bounds__(256) void scatter_pack_kernel(
    const int* __restrict__ erow, const int* __restrict__ ecol,
    const float* __restrict__ eval_, const int* __restrict__ row_start,
    int* __restrict__ cursor, unsigned int* __restrict__ epack, int n_edges)
{
    int e = blockIdx.x * 256 + threadIdx.x;
    if (e >= n_edges) return;
    int r = erow[e];
    int pos = row_start[r] + atomicAdd(&cursor[r], 1);
    union { __half h; unsigned short u; } hv;
    hv.h = __float2half_rn(eval_[e]);
    epack[pos] = ((unsigned int)ecol[e] << 16) | (unsigned int)hv.u;
}

// ---------------------------------------------------------------------------
// K2: CSR SpMM over 256 fp16 cols, one wave/row, fused relu+softmax, fp16 out.
// Lane l holds cols 4l..4l+3: lanes 0..31 = P (softmax), 32..63 = Q (relu).
// ---------------------------------------------------------------------------
__global__ __launch_bounds__(256) void spmm_dual_csr(
    const int* __restrict__ row_start, const unsigned int* __restrict__ epack,
    const __half* __restrict__ xwh, __half* __restrict__ pqh, int n_nodes)
{
    int row = blockIdx.x * 4 + (threadIdx.x >> 6);
    if (row >= n_nodes) return;
    int lane = threadIdx.x & 63;
    int beg = row_start[row], end = row_start[row + 1];

    float4 a0 = {0,0,0,0}, a1 = {0,0,0,0}, a2 = {0,0,0,0}, a3 = {0,0,0,0};
    int j = beg;
    for (; j + 3 < end; j += 4) {
        unsigned int p0 = epack[j],     p1 = epack[j + 1];
        unsigned int p2 = epack[j + 2], p3 = epack[j + 3];
        uint2 u0 = ((const uint2*)(xwh + (size_t)(p0 >> 16) * F2))[lane];
        uint2 u1 = ((const uint2*)(xwh + (size_t)(p1 >> 16) * F2))[lane];
        uint2 u2 = ((const uint2*)(xwh + (size_t)(p2 >> 16) * F2))[lane];
        uint2 u3 = ((const uint2*)(xwh + (size_t)(p3 >> 16) * F2))[lane];
        float v0 = pe_val(p0), v1 = pe_val(p1), v2 = pe_val(p2), v3 = pe_val(p3);
        float4 s0 = h8_to_f4(u0), s1 = h8_to_f4(u1);
        float4 s2 = h8_to_f4(u2), s3 = h8_to_f4(u3);
        a0.x += v0 * s0.x; a0.y += v0 * s0.y; a0.z += v0 * s0.z; a0.w += v0 * s0.w;
        a1.x += v1 * s1.x; a1.y += v1 * s1.y; a1.z += v1 * s1.z; a1.w += v1 * s1.w;
        a2.x += v2 * s2.x; a2.y += v2 * s2.y; a2.z += v2 * s2.z; a2.w += v2 * s2.w;
        a3.x += v3 * s3.x; a3.y += v3 * s3.y; a3.z += v3 * s3.z; a3.w += v3 * s3.w;
    }
    for (; j < end; ++j) {
        unsigned int p = epack[j];
        uint2 u = ((const uint2*)(xwh + (size_t)(p >> 16) * F2))[lane];
        float v = pe_val(p);
        float4 s = h8_to_f4(u);
        a0.x += v * s.x; a0.y += v * s.y; a0.z += v * s.z; a0.w += v * s.w;
    }
    float4 a;
    a.x = a0.x + a1.x + a2.x + a3.x;
    a.y = a0.y + a1.y + a2.y + a3.y;
    a.z = a0.z + a1.z + a2.z + a3.z;
    a.w = a0.w + a1.w + a2.w + a3.w;

    a.x = fmaxf(a.x, 0.f); a.y = fmaxf(a.y, 0.f);
    a.z = fmaxf(a.z, 0.f); a.w = fmaxf(a.w, 0.f);

    float m = fmaxf(fmaxf(a.x, a.y), fmaxf(a.z, a.w));
#pragma unroll
    for (int off = 16; off; off >>= 1) m = fmaxf(m, __shfl_xor(m, off));
    float ex = __expf(a.x - m), ey = __expf(a.y - m);
    float ez = __expf(a.z - m), ew = __expf(a.w - m);
    float ssum = ex + ey + ez + ew;
#pragma unroll
    for (int off = 16; off; off >>= 1) ssum += __shfl_xor(ssum, off);
    float inv = 1.f / ssum;

    bool isP = lane < 32;
    float wx = isP ? ex * inv : a.x;
    float wy = isP ? ey * inv : a.y;
    float wz = isP ? ez * inv : a.z;
    float ww = isP ? ew * inv : a.w;
    ((uint2*)(pqh + (size_t)row * F2))[lane] =
        make_uint2(f2_to_h2u(wx, wy), f2_to_h2u(wz, ww));
}

// ---------------------------------------------------------------------------
// K4: AS = A @ S (fp16 gather of S = pqh[:,0:128], stride 256), fp16 out.
// ---------------------------------------------------------------------------
__global__ __launch_bounds__(256) void spmm_s_csr(
    const int* __restrict__ row_start, const unsigned int* __restrict__ epack,
    const __half* __restrict__ pqh, __half* __restrict__ ash, int n_nodes)
{
    int row = blockIdx.x * 4 + (threadIdx.x >> 6);
    if (row >= n_nodes) return;
    int lane = threadIdx.x & 63;
    int beg = row_start[row], end = row_start[row + 1];

    float2 a0 = {0,0}, a1 = {0,0}, a2 = {0,0}, a3 = {0,0};
    int j = beg;
    for (; j + 3 < end; j += 4) {
        unsigned int p0 = epack[j],     p1 = epack[j + 1];
        unsigned int p2 = epack[j + 2], p3 = epack[j + 3];
        __half2 h0 = ((const __half2*)(pqh + (size_t)(p0 >> 16) * F2))[lane];
        __half2 h1 = ((const __half2*)(pqh + (size_t)(p1 >> 16) * F2))[lane];
        __half2 h2 = ((const __half2*)(pqh + (size_t)(p2 >> 16) * F2))[lane];
        __half2 h3 = ((const __half2*)(pqh + (size_t)(p3 >> 16) * F2))[lane];
        float v0 = pe_val(p0), v1 = pe_val(p1), v2 = pe_val(p2), v3 = pe_val(p3);
        float2 f0 = __half22float2(h0), f1 = __half22float2(h1);
        float2 f2 = __half22float2(h2), f3 = __half22float2(h3);
        a0.x += v0 * f0.x; a0.y += v0 * f0.y;
        a1.x += v1 * f1.x; a1.y += v1 * f1.y;
        a2.x += v2 * f2.x; a2.y += v2 * f2.y;
        a3.x += v3 * f3.x; a3.y += v3 * f3.y;
    }
    for (; j < end; ++j) {
        unsigned int p = epack[j];
        __half2 h = ((const __half2*)(pqh + (size_t)(p >> 16) * F2))[lane];
        float v = pe_val(p);
        float2 f = __half22float2(h);
        a0.x += v * f.x; a0.y += v * f.y;
    }
    float rx = a0.x + a1.x + a2.x + a3.x;
    float ry = a0.y + a1.y + a2.y + a3.y;
    union { __half2 h; unsigned int i; } o;
    o.h = __floats2half2_rn(rx, ry);
    ((unsigned int*)(ash + (size_t)row * KC))[lane] = o.i;
}

// ---------------------------------------------------------------------------
// K5: coarse_A = S^T @ AS (which=0), coarse_X = S^T @ Z (which=1). fp16 in.
// 1024 blocks for occupancy; rotated atomic flush.
// ---------------------------------------------------------------------------
__global__ __launch_bounds__(256) void coarse_h(
    const __half* __restrict__ pqh, const __half* __restrict__ ash,
    float* __restrict__ out, int n_nodes)
{
    const int which = blockIdx.y;
    const int tid = threadIdx.x;
    const int f  = tid & 127;
    const int k0 = (tid >> 7) * 64;
    __shared__ float sS[8][128];
    float acc[64];
#pragma unroll
    for (int i = 0; i < 64; ++i) acc[i] = 0.f;
    const int stride = gridDim.x * 8;
    for (int n0 = blockIdx.x * 8; n0 < n_nodes; n0 += stride) {
        __syncthreads();
        for (int i = tid; i < 512; i += 256) {   // 8 rows x 64 half2
            int rr = i >> 6, c2 = i & 63;
            int n = n0 + rr;
            float2 fv = {0.f, 0.f};
            if (n < n_nodes)
                fv = __half22float2(((const __half2*)(pqh + (size_t)n * F2))[c2]);
            sS[rr][2 * c2]     = fv.x;
            sS[rr][2 * c2 + 1] = fv.y;
        }
        __syncthreads();
        int rmax = (n_nodes - n0 < 8) ? (n_nodes - n0) : 8;
        for (int rr = 0; rr < rmax; ++rr) {
            int n = n0 + rr;
            float v = __half2float(which ? pqh[(size_t)n * F2 + KC + f]
                                         : ash[(size_t)n * KC + f]);
            const float4* s4 = (const float4*)(&sS[rr][k0]);
#pragma unroll
            for (int i = 0; i < 16; ++i) {
                float4 sv = s4[i];
                acc[4 * i + 0] += sv.x * v;
                acc[4 * i + 1] += sv.y * v;
                acc[4 * i + 2] += sv.z * v;
                acc[4 * i + 3] += sv.w * v;
            }
        }
    }
    float* o = out + (size_t)which * (KC * KC);
    int rot = blockIdx.x & 63;
#pragma unroll
    for (int ii = 0; ii < 64; ++ii) {
        int i = (ii + rot) & 63;
        atomicAdd(&o[(size_t)(k0 + i) * KC + f], acc[i]);
    }
}

// ---------------------------------------------------------------------------
// Fallback f32 atomic path (only if n_nodes > 65535 or ws too small)
// ---------------------------------------------------------------------------
__global__ __launch_bounds__(256) void gemm_xw_f(
    const float* __restrict__ x, const float* __restrict__ Wp,
    const float* __restrict__ We, float* __restrict__ xw, int n_nodes)
{
    constexpr int RPB = 32;
    __shared__ float xs[RPB][F_IN];
    const int r0 = blockIdx.x * RPB;
    const int tid = threadIdx.x;
    for (int i = tid; i < RPB * F_IN; i += 256) {
        int r = i >> 7, c = i & 127;
        int gr = r0 + r;
        xs[r][c] = (gr < n_nodes) ? x[(size_t)gr * F_IN + c] : 0.f;
    }
    __syncthreads();
    const int col = tid;
    const float* W = (col < KC) ? (Wp + col) : (We + (col - KC));
    float acc[RPB];
#pragma unroll
    for (int r = 0; r < RPB; ++r) acc[r] = 0.f;
    for (int k = 0; k < F_IN; ++k) {
        float w = W[(size_t)k * KC];
        const float* xk = &xs[0][k];
#pragma unroll
        for (int r = 0; r < RPB; ++r) acc[r] += xk[r * F_IN] * w;
    }
#pragma unroll
    for (int r = 0; r < RPB; ++r) {
        int gr = r0 + r;
        if (gr < n_nodes) xw[(size_t)gr * F2 + col] = acc[r];
    }
}

__global__ __launch_bounds__(256) void spmm_dual_kernel(
    const int* __restrict__ erow, const int* __restrict__ ecol,
    const float* __restrict__ eval_, const float* __restrict__ xw,
    float* __restrict__ pq, int n_edges)
{
    int e = blockIdx.x * 4 + (threadIdx.x >> 6);
    if (e >= n_edges) return;
    int lane = threadIdx.x & 63;
    int r = erow[e], c = ecol[e];
    float v = eval_[e];
    const float4* src = (const float4*)(xw + (size_t)c * F2);
    float* dst = pq + (size_t)r * F2;
    float4 s = src[lane];
    int f = lane * 4;
    atomicAdd(&dst[f + 0], v * s.x);
    atomicAdd(&dst[f + 1], v * s.y);
    atomicAdd(&dst[f + 2], v * s.z);
    atomicAdd(&dst[f + 3], v * s.w);
}

__global__ __launch_bounds__(64) void softmax_relu_kernel(
    float* __restrict__ pq, int n_nodes)
{
    int n = blockIdx.x;
    if (n >= n_nodes) return;
    int lane = threadIdx.x;
    float* p = pq + (size_t)n * F2;
    float a0 = fmaxf(p[lane], 0.f);
    float a1 = fmaxf(p[lane + 64], 0.f);
    float m = fmaxf(a0, a1);
#pragma unroll
    for (int off = 32; off; off >>= 1) m = fmaxf(m, __shfl_xor(m, off));
    float e0 = __expf(a0 - m), e1 = __expf(a1 - m);
    float ssum = e0 + e1;
#pragma unroll
    for (int off = 32; off; off >>= 1) ssum += __shfl_xor(ssum, off);
    float inv = 1.f / ssum;
    p[lane]      = e0 * inv;
    p[lane + 64] = e1 * inv;
    p[lane + 128] = fmaxf(p[lane + 128], 0.f);
    p[lane + 192] = fmaxf(p[lane + 192], 0.f);
}

__global__ __launch_bounds__(256) void spmm_s_kernel(
    const int* __restrict__ erow, const int* __restrict__ ecol,
    const float* __restrict__ eval_, const float* __restrict__ pq,
    float* __restrict__ as_, int n_edges)
{
    int e = blockIdx.x * 4 + (threadIdx.x >> 6);
    if (e >= n_edges) return;
    int lane = threadIdx.x & 63;
    int r = erow[e], c = ecol[e];
    float v = eval_[e];
    const float2* src = (const float2*)(pq + (size_t)c * F2);
    float* dst = as_ + (size_t)r * KC;
    float2 s = src[lane];
    int f = lane * 2;
    atomicAdd(&dst[f + 0], v * s.x);
    atomicAdd(&dst[f + 1], v * s.y);
}

__global__ __launch_bounds__(256) void coarse_f(
    const float* __restrict__ pq, const float* __restrict__ as_,
    float* __restrict__ out, int n_nodes)
{
    const int which = blockIdx.y;
    const int tid = threadIdx.x;
    const int f  = tid & 127;
    const int k0 = (tid >> 7) * 64;
    __shared__ float sS[8][128];
    float acc[64];
#pragma unroll
    for (int i = 0; i < 64; ++i) acc[i] = 0.f;
    const int stride = gridDim.x * 8;
    for (int n0 = blockIdx.x * 8; n0 < n_nodes; n0 += stride) {
        __syncthreads();
        for (int i = tid; i < 8 * 128; i += 256) {
            int rr = i >> 7, cc = i & 127;
            int n = n0 + rr;
            sS[rr][cc] = (n < n_nodes) ? pq[(size_t)n * F2 + cc] : 0.f;
        }
        __syncthreads();
        int rmax = (n_nodes - n0 < 8) ? (n_nodes - n0) : 8;
        for (int rr = 0; rr < rmax; ++rr) {
            int n = n0 + rr;
            float v = which ? pq[(size_t)n * F2 + KC + f]
                            : as_[(size_t)n * KC + f];
            const float4* s4 = (const float4*)(&sS[rr][k0]);
#pragma unroll
            for (int i = 0; i < 16; ++i) {
                float4 sv = s4[i];
                acc[4 * i + 0] += sv.x * v;
                acc[4 * i + 1] += sv.y * v;
                acc[4 * i + 2] += sv.z * v;
                acc[4 * i + 3] += sv.w * v;
            }
        }
    }
    float* o = out + (size_t)which * (KC * KC);
#pragma unroll
    for (int i = 0; i < 64; ++i)
        atomicAdd(&o[(size_t)(k0 + i) * KC + f], acc[i]);
}

// ---------------------------------------------------------------------------
extern "C" void kernel_launch(void* const* d_in, const int* in_sizes, int n_in,
                              void* d_out, int out_size, void* d_ws, size_t ws_size,
                              hipStream_t stream)
{
    const float* x     = (const float*)d_in[0];
    const int*   erow  = (const int*)d_in[1];
    const int*   ecol  = (const int*)d_in[2];
    const float* eval_ = (const float*)d_in[3];
    const float* Wp    = (const float*)d_in[4];
    const float* We    = (const float*)d_in[5];
    float* out = (float*)d_out;

    const int n_nodes = in_sizes[0] / F_IN;
    const int n_edges = in_sizes[1];

    // fp16 CSR layout:
    //   xwh  [N*256] h | pqh [N*256] h | ash [N*128] h
    //   row_start [N+1] i | cnt [N] i | epack [E] u32
    __half* xwh = (__half*)d_ws;
    __half* pqh = xwh + (size_t)n_nodes * F2;
    __half* ash = pqh + (size_t)n_nodes * F2;
    int* row_start = (int*)(ash + (size_t)n_nodes * KC);
    int* cnt       = row_start + (n_nodes + 1);
    unsigned int* epack = (unsigned int*)(cnt + n_nodes);

    const size_t needed_h = (size_t)n_nodes * (F2 * 2 * 2 + KC * 2)
                          + ((size_t)(2 * n_nodes) + 1) * 4 + (size_t)n_edges * 4;

    hipMemsetAsync(d_out, 0, (size_t)out_size * sizeof(float), stream);

    if (n_nodes <= 65535 && ws_size >= needed_h) {
        // ---- fast fp16 CSR path ----
        gemm_xw_h<<<(n_nodes + 31) / 32, 256, 0, stream>>>(x, Wp, We, xwh, n_nodes);
        hipMemsetAsync(cnt, 0, (size_t)n_nodes * sizeof(int), stream);
        hist_kernel<<<(n_edges + 255) / 256, 256, 0, stream>>>(erow, cnt, n_edges);
        scan_kernel<<<1, 1024, 0, stream>>>(cnt, row_start, n_nodes);
        hipMemsetAsync(cnt, 0, (size_t)n_nodes * sizeof(int), stream);
        scatter_pack_kernel<<<(n_edges + 255) / 256, 256, 0, stream>>>(
            erow, ecol, eval_, row_start, cnt, epack, n_edges);

        spmm_dual_csr<<<(n_nodes + 3) / 4, 256, 0, stream>>>(
            row_start, epack, xwh, pqh, n_nodes);
        spmm_s_csr<<<(n_nodes + 3) / 4, 256, 0, stream>>>(
            row_start, epack, pqh, ash, n_nodes);
        coarse_h<<<dim3(512, 2), 256, 0, stream>>>(pqh, ash, out, n_nodes);
    } else {
        // ---- f32 atomic fallback ----
        float* xw  = (float*)d_ws;
        float* pq  = xw + (size_t)n_nodes * F2;
        float* as_ = xw;
        gemm_xw_f<<<(n_nodes + 31) / 32, 256, 0, stream>>>(x, Wp, We, xw, n_nodes);
        hipMemsetAsync(pq, 0, (size_t)n_nodes * F2 * sizeof(float), stream);
        spmm_dual_kernel<<<(n_edges + 3) / 4, 256, 0, stream>>>(
            erow, ecol, eval_, xw, pq, n_edges);
        softmax_relu_kernel<<<n_nodes, 64, 0, stream>>>(pq, n_nodes);
        hipMemsetAsync(as_, 0, (size_t)n_nodes * KC * sizeof(float), stream);
        spmm_s_kernel<<<(n_edges + 3) / 4, 256, 0, stream>>>(
            erow, ecol, eval_, pq, as_, n_edges);
        coarse_f<<<dim3(128, 2), 256, 0, stream>>>(pq, as_, out, n_nodes);
    }
}

// Round 4
// 629.630 us; speedup vs baseline: 11.0392x; 1.0518x over previous
//
#include <hip/hip_runtime.h>
#include <hip/hip_fp16.h>

constexpr int F_IN = 128;
constexpr int KC   = 128;   // K_CLUST == F_EMB == 128
constexpr int F2   = 256;   // K_CLUST + F_EMB
constexpr int NB_COARSE = 192;   // partial tiles per output (fits in dead xwh)

// ---------- fp16 pack/unpack helpers ----------
__device__ __forceinline__ float4 h8_to_f4(uint2 u) {
    union { unsigned int i; __half2 h; } a, b;
    a.i = u.x; b.i = u.y;
    float2 f0 = __half22float2(a.h);
    float2 f1 = __half22float2(b.h);
    return make_float4(f0.x, f0.y, f1.x, f1.y);
}
__device__ __forceinline__ unsigned int f2_to_h2u(float x, float y) {
    union { __half2 h; unsigned int i; } c;
    c.h = __floats2half2_rn(x, y);
    return c.i;
}
__device__ __forceinline__ float pe_val(unsigned int pe) {
    return __half2float(__ushort_as_half((unsigned short)(pe & 0xffffu)));
}

// ---------------------------------------------------------------------------
// K1: XW = x @ [W_pool | W_embed] -> fp16 [N,256]
// ---------------------------------------------------------------------------
__global__ __launch_bounds__(256) void gemm_xw_h(
    const float* __restrict__ x, const float* __restrict__ Wp,
    const float* __restrict__ We, __half* __restrict__ xwh, int n_nodes)
{
    constexpr int RPB = 32;
    __shared__ float xs[RPB][F_IN];
    const int r0 = blockIdx.x * RPB;
    const int tid = threadIdx.x;
    for (int i = tid; i < RPB * F_IN; i += 256) {
        int r = i >> 7, c = i & 127;
        int gr = r0 + r;
        xs[r][c] = (gr < n_nodes) ? x[(size_t)gr * F_IN + c] : 0.f;
    }
    __syncthreads();
    const int col = tid;
    const float* W = (col < KC) ? (Wp + col) : (We + (col - KC));
    float acc[RPB];
#pragma unroll
    for (int r = 0; r < RPB; ++r) acc[r] = 0.f;
    for (int k = 0; k < F_IN; ++k) {
        float w = W[(size_t)k * KC];
        const float* xk = &xs[0][k];
#pragma unroll
        for (int r = 0; r < RPB; ++r) acc[r] += xk[r * F_IN] * w;
    }
#pragma unroll
    for (int r = 0; r < RPB; ++r) {
        int gr = r0 + r;
        if (gr < n_nodes) xwh[(size_t)gr * F2 + col] = __float2half_rn(acc[r]);
    }
}

// ---------------------------------------------------------------------------
// CSR build: histogram -> hierarchical exclusive scan -> scatter (packed)
// ---------------------------------------------------------------------------
__global__ __launch_bounds__(256) void hist_kernel(
    const int* __restrict__ erow, int* __restrict__ cnt, int n_edges)
{
    int e = blockIdx.x * 256 + threadIdx.x;
    if (e < n_edges) atomicAdd(&cnt[erow[e]], 1);
}

// chunk-local exclusive scan (1024 elements per block) + chunk totals
__global__ __launch_bounds__(1024) void scan_local(
    const int* __restrict__ cnt, int* __restrict__ row_start,
    int* __restrict__ chunk_sum, int n)
{
    __shared__ int wsum[16];
    const int tid = threadIdx.x;
    const int lane = tid & 63, wid = tid >> 6;
    int i = blockIdx.x * 1024 + tid;
    int v = (i < n) ? cnt[i] : 0;
    int incl = v;
#pragma unroll
    for (int off = 1; off < 64; off <<= 1) {
        int t = __shfl_up(incl, off);
        if (lane >= off) incl += t;
    }
    if (lane == 63) wsum[wid] = incl;
    __syncthreads();
    if (tid == 0) {
        int s = 0;
#pragma unroll
        for (int w = 0; w < 16; ++w) { int t = wsum[w]; wsum[w] = s; s += t; }
    }
    __syncthreads();
    if (i < n) row_start[i] = wsum[wid] + incl - v;
    if (tid == 1023) chunk_sum[blockIdx.x] = wsum[15] + incl;
}

// exclusive scan of chunk sums (single block, up to 1024 chunks)
__global__ __launch_bounds__(1024) void scan_chunks(
    const int* __restrict__ chunk_sum, int* __restrict__ chunk_base,
    int* __restrict__ row_start, int nchunks, int n)
{
    __shared__ int wsum[16];
    const int tid = threadIdx.x;
    const int lane = tid & 63, wid = tid >> 6;
    int v = (tid < nchunks) ? chunk_sum[tid] : 0;
    int incl = v;
#pragma unroll
    for (int off = 1; off < 64; off <<= 1) {
        int t = __shfl_up(incl, off);
        if (lane >= off) incl += t;
    }
    if (lane == 63) wsum[wid] = incl;
    __syncthreads();
    if (tid == 0) {
        int s = 0;
#pragma unroll
        for (int w = 0; w < 16; ++w) { int t = wsum[w]; wsum[w] = s; s += t; }
    }
    __syncthreads();
    int excl = wsum[wid] + incl - v;
    if (tid < nchunks) chunk_base[tid] = excl;
    if (tid == nchunks - 1) row_start[n] = excl + v;
}

__global__ __launch_bounds__(256) void scan_add(
    int* __restrict__ row_start, const int* __restrict__ chunk_base, int n)
{
    int i = blockIdx.x * 256 + threadIdx.x;
    if (i < n) row_start[i] += chunk_base[i >> 10];
}

__global__ __launch_bounds__(256) void scatter_pack_kernel(
    const int* __restrict__ erow, const int* __restrict__ ecol,
    const float* __restrict__ eval_, const int* __restrict__ row_start,
    int* __restrict__ cursor, unsigned int* __restrict__ epack, int n_edges)
{
    int e = blockIdx.x * 256 + threadIdx.x;
    if (e >= n_edges) return;
    int r = erow[e];
    int pos = row_start[r] + atomicAdd(&cursor[r], 1);
    union { __half h; unsigned short u; } hv;
    hv.h = __float2half_rn(eval_[e]);
    epack[pos] = ((unsigned int)ecol[e] << 16) | (unsigned int)hv.u;
}

// ---------------------------------------------------------------------------
// K2: CSR SpMM over 256 fp16 cols, one wave/row, fused relu+softmax, fp16 out.
// ---------------------------------------------------------------------------
__global__ __launch_bounds__(256) void spmm_dual_csr(
    const int* __restrict__ row_start, const unsigned int* __restrict__ epack,
    const __half* __restrict__ xwh, __half* __restrict__ pqh, int n_nodes)
{
    int row = blockIdx.x * 4 + (threadIdx.x >> 6);
    if (row >= n_nodes) return;
    int lane = threadIdx.x & 63;
    int beg = row_start[row], end = row_start[row + 1];

    float4 a0 = {0,0,0,0}, a1 = {0,0,0,0}, a2 = {0,0,0,0}, a3 = {0,0,0,0};
    int j = beg;
    for (; j + 3 < end; j += 4) {
        unsigned int p0 = epack[j],     p1 = epack[j + 1];
        unsigned int p2 = epack[j + 2], p3 = epack[j + 3];
        uint2 u0 = ((const uint2*)(xwh + (size_t)(p0 >> 16) * F2))[lane];
        uint2 u1 = ((const uint2*)(xwh + (size_t)(p1 >> 16) * F2))[lane];
        uint2 u2 = ((const uint2*)(xwh + (size_t)(p2 >> 16) * F2))[lane];
        uint2 u3 = ((const uint2*)(xwh + (size_t)(p3 >> 16) * F2))[lane];
        float v0 = pe_val(p0), v1 = pe_val(p1), v2 = pe_val(p2), v3 = pe_val(p3);
        float4 s0 = h8_to_f4(u0), s1 = h8_to_f4(u1);
        float4 s2 = h8_to_f4(u2), s3 = h8_to_f4(u3);
        a0.x += v0 * s0.x; a0.y += v0 * s0.y; a0.z += v0 * s0.z; a0.w += v0 * s0.w;
        a1.x += v1 * s1.x; a1.y += v1 * s1.y; a1.z += v1 * s1.z; a1.w += v1 * s1.w;
        a2.x += v2 * s2.x; a2.y += v2 * s2.y; a2.z += v2 * s2.z; a2.w += v2 * s2.w;
        a3.x += v3 * s3.x; a3.y += v3 * s3.y; a3.z += v3 * s3.z; a3.w += v3 * s3.w;
    }
    for (; j < end; ++j) {
        unsigned int p = epack[j];
        uint2 u = ((const uint2*)(xwh + (size_t)(p >> 16) * F2))[lane];
        float v = pe_val(p);
        float4 s = h8_to_f4(u);
        a0.x += v * s.x; a0.y += v * s.y; a0.z += v * s.z; a0.w += v * s.w;
    }
    float4 a;
    a.x = a0.x + a1.x + a2.x + a3.x;
    a.y = a0.y + a1.y + a2.y + a3.y;
    a.z = a0.z + a1.z + a2.z + a3.z;
    a.w = a0.w + a1.w + a2.w + a3.w;

    a.x = fmaxf(a.x, 0.f); a.y = fmaxf(a.y, 0.f);
    a.z = fmaxf(a.z, 0.f); a.w = fmaxf(a.w, 0.f);

    float m = fmaxf(fmaxf(a.x, a.y), fmaxf(a.z, a.w));
#pragma unroll
    for (int off = 16; off; off >>= 1) m = fmaxf(m, __shfl_xor(m, off));
    float ex = __expf(a.x - m), ey = __expf(a.y - m);
    float ez = __expf(a.z - m), ew = __expf(a.w - m);
    float ssum = ex + ey + ez + ew;
#pragma unroll
    for (int off = 16; off; off >>= 1) ssum += __shfl_xor(ssum, off);
    float inv = 1.f / ssum;

    bool isP = lane < 32;
    float wx = isP ? ex * inv : a.x;
    float wy = isP ? ey * inv : a.y;
    float wz = isP ? ez * inv : a.z;
    float ww = isP ? ew * inv : a.w;
    ((uint2*)(pqh + (size_t)row * F2))[lane] =
        make_uint2(f2_to_h2u(wx, wy), f2_to_h2u(wz, ww));
}

// ---------------------------------------------------------------------------
// K4: AS = A @ S (fp16 gather of S = pqh[:,0:128], stride 256), fp16 out.
// ---------------------------------------------------------------------------
__global__ __launch_bounds__(256) void spmm_s_csr(
    const int* __restrict__ row_start, const unsigned int* __restrict__ epack,
    const __half* __restrict__ pqh, __half* __restrict__ ash, int n_nodes)
{
    int row = blockIdx.x * 4 + (threadIdx.x >> 6);
    if (row >= n_nodes) return;
    int lane = threadIdx.x & 63;
    int beg = row_start[row], end = row_start[row + 1];

    float2 a0 = {0,0}, a1 = {0,0}, a2 = {0,0}, a3 = {0,0};
    int j = beg;
    for (; j + 3 < end; j += 4) {
        unsigned int p0 = epack[j],     p1 = epack[j + 1];
        unsigned int p2 = epack[j + 2], p3 = epack[j + 3];
        __half2 h0 = ((const __half2*)(pqh + (size_t)(p0 >> 16) * F2))[lane];
        __half2 h1 = ((const __half2*)(pqh + (size_t)(p1 >> 16) * F2))[lane];
        __half2 h2 = ((const __half2*)(pqh + (size_t)(p2 >> 16) * F2))[lane];
        __half2 h3 = ((const __half2*)(pqh + (size_t)(p3 >> 16) * F2))[lane];
        float v0 = pe_val(p0), v1 = pe_val(p1), v2 = pe_val(p2), v3 = pe_val(p3);
        float2 f0 = __half22float2(h0), f1 = __half22float2(h1);
        float2 f2 = __half22float2(h2), f3 = __half22float2(h3);
        a0.x += v0 * f0.x; a0.y += v0 * f0.y;
        a1.x += v1 * f1.x; a1.y += v1 * f1.y;
        a2.x += v2 * f2.x; a2.y += v2 * f2.y;
        a3.x += v3 * f3.x; a3.y += v3 * f3.y;
    }
    for (; j < end; ++j) {
        unsigned int p = epack[j];
        __half2 h = ((const __half2*)(pqh + (size_t)(p >> 16) * F2))[lane];
        float v = pe_val(p);
        float2 f = __half22float2(h);
        a0.x += v * f.x; a0.y += v * f.y;
    }
    float rx = a0.x + a1.x + a2.x + a3.x;
    float ry = a0.y + a1.y + a2.y + a3.y;
    union { __half2 h; unsigned int i; } o;
    o.h = __floats2half2_rn(rx, ry);
    ((unsigned int*)(ash + (size_t)row * KC))[lane] = o.i;
}

// ---------------------------------------------------------------------------
// K5a: coarse partials. which = blockIdx.y (0: S^T@AS, 1: S^T@Z).
// Each block accumulates a full 128x128 f32 tile in registers over its slice
// of nodes, then writes the tile with plain coalesced stores (NO atomics).
// ---------------------------------------------------------------------------
__global__ __launch_bounds__(256) void coarse_part(
    const __half* __restrict__ pqh, const __half* __restrict__ ash,
    float* __restrict__ part, int n_nodes)
{
    const int which = blockIdx.y;
    const int tid = threadIdx.x;
    const int f  = tid & 127;
    const int k0 = (tid >> 7) * 64;
    __shared__ float sS[8][128];
    float acc[64];
#pragma unroll
    for (int i = 0; i < 64; ++i) acc[i] = 0.f;
    const int stride = gridDim.x * 8;
    for (int n0 = blockIdx.x * 8; n0 < n_nodes; n0 += stride) {
        __syncthreads();
        for (int i = tid; i < 512; i += 256) {   // 8 rows x 64 half2
            int rr = i >> 6, c2 = i & 63;
            int n = n0 + rr;
            float2 fv = {0.f, 0.f};
            if (n < n_nodes)
                fv = __half22float2(((const __half2*)(pqh + (size_t)n * F2))[c2]);
            sS[rr][2 * c2]     = fv.x;
            sS[rr][2 * c2 + 1] = fv.y;
        }
        __syncthreads();
        int rmax = (n_nodes - n0 < 8) ? (n_nodes - n0) : 8;
        for (int rr = 0; rr < rmax; ++rr) {
            int n = n0 + rr;
            float v = __half2float(which ? pqh[(size_t)n * F2 + KC + f]
                                         : ash[(size_t)n * KC + f]);
            const float4* s4 = (const float4*)(&sS[rr][k0]);
#pragma unroll
            for (int i = 0; i < 16; ++i) {
                float4 sv = s4[i];
                acc[4 * i + 0] += sv.x * v;
                acc[4 * i + 1] += sv.y * v;
                acc[4 * i + 2] += sv.z * v;
                acc[4 * i + 3] += sv.w * v;
            }
        }
    }
    float* p = part + ((size_t)which * gridDim.x + blockIdx.x) * (KC * KC);
#pragma unroll
    for (int i = 0; i < 64; ++i)
        p[(size_t)(k0 + i) * KC + f] = acc[i];
}

// K5b: sum NB_COARSE partial tiles per output element -> d_out (full overwrite)
__global__ __launch_bounds__(256) void coarse_reduce(
    const float* __restrict__ part, float* __restrict__ out, int nb)
{
    int e = blockIdx.x * 256 + threadIdx.x;      // 0 .. 2*16384-1
    int which = e >> 14;
    int idx = e & 16383;
    const float* p = part + (size_t)which * nb * (KC * KC) + idx;
    float s = 0.f;
    for (int t = 0; t < nb; ++t) s += p[(size_t)t * (KC * KC)];
    out[e] = s;
}

// ---------------------------------------------------------------------------
// Fallback f32 atomic path (only if n_nodes too large or ws too small)
// ---------------------------------------------------------------------------
__global__ __launch_bounds__(256) void gemm_xw_f(
    const float* __restrict__ x, const float* __restrict__ Wp,
    const float* __restrict__ We, float* __restrict__ xw, int n_nodes)
{
    constexpr int RPB = 32;
    __shared__ float xs[RPB][F_IN];
    const int r0 = blockIdx.x * RPB;
    const int tid = threadIdx.x;
    for (int i = tid; i < RPB * F_IN; i += 256) {
        int r = i >> 7, c = i & 127;
        int gr = r0 + r;
        xs[r][c] = (gr < n_nodes) ? x[(size_t)gr * F_IN + c] : 0.f;
    }
    __syncthreads();
    const int col = tid;
    const float* W = (col < KC) ? (Wp + col) : (We + (col - KC));
    float acc[RPB];
#pragma unroll
    for (int r = 0; r < RPB; ++r) acc[r] = 0.f;
    for (int k = 0; k < F_IN; ++k) {
        float w = W[(size_t)k * KC];
        const float* xk = &xs[0][k];
#pragma unroll
        for (int r = 0; r < RPB; ++r) acc[r] += xk[r * F_IN] * w;
    }
#pragma unroll
    for (int r = 0; r < RPB; ++r) {
        int gr = r0 + r;
        if (gr < n_nodes) xw[(size_t)gr * F2 + col] = acc[r];
    }
}

__global__ __launch_bounds__(256) void spmm_dual_kernel(
    const int* __restrict__ erow, const int* __restrict__ ecol,
    const float* __restrict__ eval_, const float* __restrict__ xw,
    float* __restrict__ pq, int n_edges)
{
    int e = blockIdx.x * 4 + (threadIdx.x >> 6);
    if (e >= n_edges) return;
    int lane = threadIdx.x & 63;
    int r = erow[e], c = ecol[e];
    float v = eval_[e];
    const float4* src = (const float4*)(xw + (size_t)c * F2);
    float* dst = pq + (size_t)r * F2;
    float4 s = src[lane];
    int f = lane * 4;
    atomicAdd(&dst[f + 0], v * s.x);
    atomicAdd(&dst[f + 1], v * s.y);
    atomicAdd(&dst[f + 2], v * s.z);
    atomicAdd(&dst[f + 3], v * s.w);
}

__global__ __launch_bounds__(64) void softmax_relu_kernel(
    float* __restrict__ pq, int n_nodes)
{
    int n = blockIdx.x;
    if (n >= n_nodes) return;
    int lane = threadIdx.x;
    float* p = pq + (size_t)n * F2;
    float a0 = fmaxf(p[lane], 0.f);
    float a1 = fmaxf(p[lane + 64], 0.f);
    float m = fmaxf(a0, a1);
#pragma unroll
    for (int off = 32; off; off >>= 1) m = fmaxf(m, __shfl_xor(m, off));
    float e0 = __expf(a0 - m), e1 = __expf(a1 - m);
    float ssum = e0 + e1;
#pragma unroll
    for (int off = 32; off; off >>= 1) ssum += __shfl_xor(ssum, off);
    float inv = 1.f / ssum;
    p[lane]      = e0 * inv;
    p[lane + 64] = e1 * inv;
    p[lane + 128] = fmaxf(p[lane + 128], 0.f);
    p[lane + 192] = fmaxf(p[lane + 192], 0.f);
}

__global__ __launch_bounds__(256) void spmm_s_kernel(
    const int* __restrict__ erow, const int* __restrict__ ecol,
    const float* __restrict__ eval_, const float* __restrict__ pq,
    float* __restrict__ as_, int n_edges)
{
    int e = blockIdx.x * 4 + (threadIdx.x >> 6);
    if (e >= n_edges) return;
    int lane = threadIdx.x & 63;
    int r = erow[e], c = ecol[e];
    float v = eval_[e];
    const float2* src = (const float2*)(pq + (size_t)c * F2);
    float* dst = as_ + (size_t)r * KC;
    float2 s = src[lane];
    int f = lane * 2;
    atomicAdd(&dst[f + 0], v * s.x);
    atomicAdd(&dst[f + 1], v * s.y);
}

__global__ __launch_bounds__(256) void coarse_f(
    const float* __restrict__ pq, const float* __restrict__ as_,
    float* __restrict__ out, int n_nodes)
{
    const int which = blockIdx.y;
    const int tid = threadIdx.x;
    const int f  = tid & 127;
    const int k0 = (tid >> 7) * 64;
    __shared__ float sS[8][128];
    float acc[64];
#pragma unroll
    for (int i = 0; i < 64; ++i) acc[i] = 0.f;
    const int stride = gridDim.x * 8;
    for (int n0 = blockIdx.x * 8; n0 < n_nodes; n0 += stride) {
        __syncthreads();
        for (int i = tid; i < 8 * 128; i += 256) {
            int rr = i >> 7, cc = i & 127;
            int n = n0 + rr;
            sS[rr][cc] = (n < n_nodes) ? pq[(size_t)n * F2 + cc] : 0.f;
        }
        __syncthreads();
        int rmax = (n_nodes - n0 < 8) ? (n_nodes - n0) : 8;
        for (int rr = 0; rr < rmax; ++rr) {
            int n = n0 + rr;
            float v = which ? pq[(size_t)n * F2 + KC + f]
                            : as_[(size_t)n * KC + f];
            const float4* s4 = (const float4*)(&sS[rr][k0]);
#pragma unroll
            for (int i = 0; i < 16; ++i) {
                float4 sv = s4[i];
                acc[4 * i + 0] += sv.x * v;
                acc[4 * i + 1] += sv.y * v;
                acc[4 * i + 2] += sv.z * v;
                acc[4 * i + 3] += sv.w * v;
            }
        }
    }
    float* o = out + (size_t)which * (KC * KC);
#pragma unroll
    for (int i = 0; i < 64; ++i)
        atomicAdd(&o[(size_t)(k0 + i) * KC + f], acc[i]);
}

// ---------------------------------------------------------------------------
extern "C" void kernel_launch(void* const* d_in, const int* in_sizes, int n_in,
                              void* d_out, int out_size, void* d_ws, size_t ws_size,
                              hipStream_t stream)
{
    const float* x     = (const float*)d_in[0];
    const int*   erow  = (const int*)d_in[1];
    const int*   ecol  = (const int*)d_in[2];
    const float* eval_ = (const float*)d_in[3];
    const float* Wp    = (const float*)d_in[4];
    const float* We    = (const float*)d_in[5];
    float* out = (float*)d_out;

    const int n_nodes = in_sizes[0] / F_IN;
    const int n_edges = in_sizes[1];
    const int nchunks = (n_nodes + 1023) / 1024;

    // fp16 CSR layout:
    //   xwh  [N*256] h   (dead after spmm_dual -> reused as coarse partials)
    //   pqh  [N*256] h | ash [N*128] h
    //   row_start [N+1] i | cnt [N] i | epack [E] u32
    //   chunk_sum [1024] i | chunk_base [1024] i
    __half* xwh = (__half*)d_ws;
    __half* pqh = xwh + (size_t)n_nodes * F2;
    __half* ash = pqh + (size_t)n_nodes * F2;
    int* row_start = (int*)(ash + (size_t)n_nodes * KC);
    int* cnt       = row_start + (n_nodes + 1);
    unsigned int* epack = (unsigned int*)(cnt + n_nodes);
    int* chunk_sum  = (int*)(epack + n_edges);
    int* chunk_base = chunk_sum + 1024;
    float* part = (float*)xwh;   // 2*NB_COARSE*16384*4 = 24.6 MB <= xwh's 25.6 MB

    const size_t needed_h = (size_t)n_nodes * (F2 * 2 * 2 + KC * 2)
                          + ((size_t)(2 * n_nodes) + 1) * 4
                          + (size_t)n_edges * 4 + 2048 * 4;
    const bool part_fits = (size_t)2 * NB_COARSE * KC * KC * 4
                           <= (size_t)n_nodes * F2 * 2;

    if (n_nodes <= 65535 && nchunks <= 1024 && ws_size >= needed_h && part_fits) {
        // ---- fast fp16 CSR path ----
        gemm_xw_h<<<(n_nodes + 31) / 32, 256, 0, stream>>>(x, Wp, We, xwh, n_nodes);
        hipMemsetAsync(cnt, 0, (size_t)n_nodes * sizeof(int), stream);
        hist_kernel<<<(n_edges + 255) / 256, 256, 0, stream>>>(erow, cnt, n_edges);
        scan_local<<<nchunks, 1024, 0, stream>>>(cnt, row_start, chunk_sum, n_nodes);
        scan_chunks<<<1, 1024, 0, stream>>>(chunk_sum, chunk_base, row_start,
                                            nchunks, n_nodes);
        scan_add<<<(n_nodes + 255) / 256, 256, 0, stream>>>(row_start, chunk_base,
                                                            n_nodes);
        hipMemsetAsync(cnt, 0, (size_t)n_nodes * sizeof(int), stream);
        scatter_pack_kernel<<<(n_edges + 255) / 256, 256, 0, stream>>>(
            erow, ecol, eval_, row_start, cnt, epack, n_edges);

        spmm_dual_csr<<<(n_nodes + 3) / 4, 256, 0, stream>>>(
            row_start, epack, xwh, pqh, n_nodes);
        spmm_s_csr<<<(n_nodes + 3) / 4, 256, 0, stream>>>(
            row_start, epack, pqh, ash, n_nodes);

        coarse_part<<<dim3(NB_COARSE, 2), 256, 0, stream>>>(pqh, ash, part, n_nodes);
        coarse_reduce<<<(2 * KC * KC) / 256, 256, 0, stream>>>(part, out, NB_COARSE);
    } else {
        // ---- f32 atomic fallback ----
        float* xw  = (float*)d_ws;
        float* pq  = xw + (size_t)n_nodes * F2;
        float* as_ = xw;
        hipMemsetAsync(d_out, 0, (size_t)out_size * sizeof(float), stream);
        gemm_xw_f<<<(n_nodes + 31) / 32, 256, 0, stream>>>(x, Wp, We, xw, n_nodes);
        hipMemsetAsync(pq, 0, (size_t)n_nodes * F2 * sizeof(float), stream);
        spmm_dual_kernel<<<(n_edges + 3) / 4, 256, 0, stream>>>(
            erow, ecol, eval_, xw, pq, n_edges);
        softmax_relu_kernel<<<n_nodes, 64, 0, stream>>>(pq, n_nodes);
        hipMemsetAsync(as_, 0, (size_t)n_nodes * KC * sizeof(float), stream);
        spmm_s_kernel<<<(n_edges + 3) / 4, 256, 0, stream>>>(
            erow, ecol, eval_, pq, as_, n_edges);
        coarse_f<<<dim3(128, 2), 256, 0, stream>>>(pq, as_, out, n_nodes);
    }
}

// Round 5
// 496.663 us; speedup vs baseline: 13.9946x; 1.2677x over previous
//
#include <hip/hip_runtime.h>
#include <hip/hip_fp16.h>

constexpr int F_IN = 128;
constexpr int KC   = 128;   // K_CLUST == F_EMB == 128
constexpr int F2   = 256;   // K_CLUST + F_EMB
constexpr int NB_COARSE = 256;   // partial tiles per output (lives in ws tail)

typedef _Float16 f16x8 __attribute__((ext_vector_type(8)));
typedef float    f32x4 __attribute__((ext_vector_type(4)));

// ---------- fp16 pack/unpack helpers ----------
__device__ __forceinline__ float4 h8_to_f4(uint2 u) {
    union { unsigned int i; __half2 h; } a, b;
    a.i = u.x; b.i = u.y;
    float2 f0 = __half22float2(a.h);
    float2 f1 = __half22float2(b.h);
    return make_float4(f0.x, f0.y, f1.x, f1.y);
}
__device__ __forceinline__ unsigned int f2_to_h2u(float x, float y) {
    union { __half2 h; unsigned int i; } c;
    c.h = __floats2half2_rn(x, y);
    return c.i;
}
__device__ __forceinline__ float pe_val(unsigned int pe) {
    return __half2float(__ushort_as_half((unsigned short)(pe & 0xffffu)));
}

// ---------------------------------------------------------------------------
// W transpose: wt[col][k] = W[k][col], fp16. col 0..255 (Wp|We), k 0..127.
// ---------------------------------------------------------------------------
__global__ __launch_bounds__(128) void transpose_w(
    const float* __restrict__ Wp, const float* __restrict__ We,
    __half* __restrict__ wt)
{
    int col = blockIdx.x;      // 0..255
    int k   = threadIdx.x;     // 0..127
    float v = (col < KC) ? Wp[(size_t)k * KC + col]
                         : We[(size_t)k * KC + (col - KC)];
    wt[(size_t)col * F_IN + k] = __float2half_rn(v);
}

// ---------------------------------------------------------------------------
// K1: XW = x @ [W_pool | W_embed] -> fp16 [N,256], via MFMA 16x16x32_f16.
// Block: 256 thr (4 waves), M-tile 32 nodes, N=256 cols, K=128.
// A (x tile) staged fp16 in LDS, stride 136 halves (272B) to spread banks.
// B frags read from pre-transposed wt (contiguous 8 halves per lane).
// ---------------------------------------------------------------------------
__global__ __launch_bounds__(256) void gemm_xw_mfma(
    const float* __restrict__ x, const __half* __restrict__ wt,
    __half* __restrict__ xwh, int n_nodes)
{
    __shared__ _Float16 xs[32][136];
    const int r0 = blockIdx.x * 32;
    const int tid = threadIdx.x;

    // stage: thread t -> row r = t>>3, cols c0..c0+15
    {
        int r = tid >> 3, c0 = (tid & 7) * 16;
        int gr = r0 + r;
        if (gr < n_nodes) {
            const float4* src = (const float4*)(x + (size_t)gr * F_IN + c0);
#pragma unroll
            for (int i = 0; i < 4; ++i) {
                float4 f = src[i];
                xs[r][c0 + 4 * i + 0] = (_Float16)f.x;
                xs[r][c0 + 4 * i + 1] = (_Float16)f.y;
                xs[r][c0 + 4 * i + 2] = (_Float16)f.z;
                xs[r][c0 + 4 * i + 3] = (_Float16)f.w;
            }
        } else {
#pragma unroll
            for (int i = 0; i < 16; ++i) xs[r][c0 + i] = (_Float16)0.f;
        }
    }
    __syncthreads();

    const int w = tid >> 6, lane = tid & 63;
    const int lrow = lane & 15;          // A row / B col within tile
    const int lk   = (lane >> 4) * 8;    // k offset within 32-chunk

    // B frags: wave w owns col-blocks w*4 .. w*4+3
    f16x8 bfrag[4][4];
#pragma unroll
    for (int cb = 0; cb < 4; ++cb) {
        int gcol = (w * 4 + cb) * 16 + lrow;
        const f16x8* bp = (const f16x8*)(wt + (size_t)gcol * F_IN + lk);
#pragma unroll
        for (int kc = 0; kc < 4; ++kc) bfrag[cb][kc] = bp[kc * 4];
    }

    f32x4 acc[2][4];
#pragma unroll
    for (int rb = 0; rb < 2; ++rb)
#pragma unroll
        for (int cb = 0; cb < 4; ++cb) acc[rb][cb] = (f32x4){0.f, 0.f, 0.f, 0.f};

#pragma unroll
    for (int kc = 0; kc < 4; ++kc) {
        f16x8 a0 = *(const f16x8*)(&xs[lrow][kc * 32 + lk]);
        f16x8 a1 = *(const f16x8*)(&xs[16 + lrow][kc * 32 + lk]);
#pragma unroll
        for (int cb = 0; cb < 4; ++cb) {
            acc[0][cb] = __builtin_amdgcn_mfma_f32_16x16x32_f16(a0, bfrag[cb][kc], acc[0][cb], 0, 0, 0);
            acc[1][cb] = __builtin_amdgcn_mfma_f32_16x16x32_f16(a1, bfrag[cb][kc], acc[1][cb], 0, 0, 0);
        }
    }

    // C/D layout: col = lane&15, row = (lane>>4)*4 + reg  [m89-verified]
#pragma unroll
    for (int rb = 0; rb < 2; ++rb) {
#pragma unroll
        for (int cb = 0; cb < 4; ++cb) {
            int gcol = (w * 4 + cb) * 16 + lrow;
#pragma unroll
            for (int reg = 0; reg < 4; ++reg) {
                int grow = r0 + rb * 16 + (lane >> 4) * 4 + reg;
                if (grow < n_nodes)
                    xwh[(size_t)grow * F2 + gcol] = __float2half_rn(acc[rb][cb][reg]);
            }
        }
    }
}

// ---------------------------------------------------------------------------
// CSR build: histogram -> hierarchical exclusive scan -> scatter (packed)
// ---------------------------------------------------------------------------
__global__ __launch_bounds__(256) void hist_kernel(
    const int* __restrict__ erow, int* __restrict__ cnt, int n_edges)
{
    int e = blockIdx.x * 256 + threadIdx.x;
    if (e < n_edges) atomicAdd(&cnt[erow[e]], 1);
}

__global__ __launch_bounds__(1024) void scan_local(
    const int* __restrict__ cnt, int* __restrict__ row_start,
    int* __restrict__ chunk_sum, int n)
{
    __shared__ int wsum[16];
    const int tid = threadIdx.x;
    const int lane = tid & 63, wid = tid >> 6;
    int i = blockIdx.x * 1024 + tid;
    int v = (i < n) ? cnt[i] : 0;
    int incl = v;
#pragma unroll
    for (int off = 1; off < 64; off <<= 1) {
        int t = __shfl_up(incl, off);
        if (lane >= off) incl += t;
    }
    if (lane == 63) wsum[wid] = incl;
    __syncthreads();
    if (tid == 0) {
        int s = 0;
#pragma unroll
        for (int w = 0; w < 16; ++w) { int t = wsum[w]; wsum[w] = s; s += t; }
    }
    __syncthreads();
    if (i < n) row_start[i] = wsum[wid] + incl - v;
    if (tid == 1023) chunk_sum[blockIdx.x] = wsum[15] + incl;
}

__global__ __launch_bounds__(1024) void scan_chunks(
    const int* __restrict__ chunk_sum, int* __restrict__ chunk_base,
    int* __restrict__ row_start, int nchunks, int n)
{
    __shared__ int wsum[16];
    const int tid = threadIdx.x;
    const int lane = tid & 63, wid = tid >> 6;
    int v = (tid < nchunks) ? chunk_sum[tid] : 0;
    int incl = v;
#pragma unroll
    for (int off = 1; off < 64; off <<= 1) {
        int t = __shfl_up(incl, off);
        if (lane >= off) incl += t;
    }
    if (lane == 63) wsum[wid] = incl;
    __syncthreads();
    if (tid == 0) {
        int s = 0;
#pragma unroll
        for (int w = 0; w < 16; ++w) { int t = wsum[w]; wsum[w] = s; s += t; }
    }
    __syncthreads();
    int excl = wsum[wid] + incl - v;
    if (tid < nchunks) chunk_base[tid] = excl;
    if (tid == nchunks - 1) row_start[n] = excl + v;
}

__global__ __launch_bounds__(256) void scan_add(
    int* __restrict__ row_start, const int* __restrict__ chunk_base, int n)
{
    int i = blockIdx.x * 256 + threadIdx.x;
    if (i < n) row_start[i] += chunk_base[i >> 10];
}

__global__ __launch_bounds__(256) void scatter_pack_kernel(
    const int* __restrict__ erow, const int* __restrict__ ecol,
    const float* __restrict__ eval_, const int* __restrict__ row_start,
    int* __restrict__ cursor, unsigned int* __restrict__ epack, int n_edges)
{
    int e = blockIdx.x * 256 + threadIdx.x;
    if (e >= n_edges) return;
    int r = erow[e];
    int pos = row_start[r] + atomicAdd(&cursor[r], 1);
    union { __half h; unsigned short u; } hv;
    hv.h = __float2half_rn(eval_[e]);
    epack[pos] = ((unsigned int)ecol[e] << 16) | (unsigned int)hv.u;
}

// ---------------------------------------------------------------------------
// K2: CSR SpMM over 256 fp16 cols, one wave/row, fused relu+softmax, fp16 out.
// ---------------------------------------------------------------------------
__global__ __launch_bounds__(256) void spmm_dual_csr(
    const int* __restrict__ row_start, const unsigned int* __restrict__ epack,
    const __half* __restrict__ xwh, __half* __restrict__ pqh, int n_nodes)
{
    int row = blockIdx.x * 4 + (threadIdx.x >> 6);
    if (row >= n_nodes) return;
    int lane = threadIdx.x & 63;
    int beg = row_start[row], end = row_start[row + 1];

    float4 a0 = {0,0,0,0}, a1 = {0,0,0,0}, a2 = {0,0,0,0}, a3 = {0,0,0,0};
    int j = beg;
    for (; j + 3 < end; j += 4) {
        unsigned int p0 = epack[j],     p1 = epack[j + 1];
        unsigned int p2 = epack[j + 2], p3 = epack[j + 3];
        uint2 u0 = ((const uint2*)(xwh + (size_t)(p0 >> 16) * F2))[lane];
        uint2 u1 = ((const uint2*)(xwh + (size_t)(p1 >> 16) * F2))[lane];
        uint2 u2 = ((const uint2*)(xwh + (size_t)(p2 >> 16) * F2))[lane];
        uint2 u3 = ((const uint2*)(xwh + (size_t)(p3 >> 16) * F2))[lane];
        float v0 = pe_val(p0), v1 = pe_val(p1), v2 = pe_val(p2), v3 = pe_val(p3);
        float4 s0 = h8_to_f4(u0), s1 = h8_to_f4(u1);
        float4 s2 = h8_to_f4(u2), s3 = h8_to_f4(u3);
        a0.x += v0 * s0.x; a0.y += v0 * s0.y; a0.z += v0 * s0.z; a0.w += v0 * s0.w;
        a1.x += v1 * s1.x; a1.y += v1 * s1.y; a1.z += v1 * s1.z; a1.w += v1 * s1.w;
        a2.x += v2 * s2.x; a2.y += v2 * s2.y; a2.z += v2 * s2.z; a2.w += v2 * s2.w;
        a3.x += v3 * s3.x; a3.y += v3 * s3.y; a3.z += v3 * s3.z; a3.w += v3 * s3.w;
    }
    for (; j < end; ++j) {
        unsigned int p = epack[j];
        uint2 u = ((const uint2*)(xwh + (size_t)(p >> 16) * F2))[lane];
        float v = pe_val(p);
        float4 s = h8_to_f4(u);
        a0.x += v * s.x; a0.y += v * s.y; a0.z += v * s.z; a0.w += v * s.w;
    }
    float4 a;
    a.x = a0.x + a1.x + a2.x + a3.x;
    a.y = a0.y + a1.y + a2.y + a3.y;
    a.z = a0.z + a1.z + a2.z + a3.z;
    a.w = a0.w + a1.w + a2.w + a3.w;

    a.x = fmaxf(a.x, 0.f); a.y = fmaxf(a.y, 0.f);
    a.z = fmaxf(a.z, 0.f); a.w = fmaxf(a.w, 0.f);

    float m = fmaxf(fmaxf(a.x, a.y), fmaxf(a.z, a.w));
#pragma unroll
    for (int off = 16; off; off >>= 1) m = fmaxf(m, __shfl_xor(m, off));
    float ex = __expf(a.x - m), ey = __expf(a.y - m);
    float ez = __expf(a.z - m), ew = __expf(a.w - m);
    float ssum = ex + ey + ez + ew;
#pragma unroll
    for (int off = 16; off; off >>= 1) ssum += __shfl_xor(ssum, off);
    float inv = 1.f / ssum;

    bool isP = lane < 32;
    float wx = isP ? ex * inv : a.x;
    float wy = isP ? ey * inv : a.y;
    float wz = isP ? ez * inv : a.z;
    float ww = isP ? ew * inv : a.w;
    ((uint2*)(pqh + (size_t)row * F2))[lane] =
        make_uint2(f2_to_h2u(wx, wy), f2_to_h2u(wz, ww));
}

// ---------------------------------------------------------------------------
// K4: AS = A @ S (fp16 gather of S = pqh[:,0:128], stride 256), fp16 out.
// ---------------------------------------------------------------------------
__global__ __launch_bounds__(256) void spmm_s_csr(
    const int* __restrict__ row_start, const unsigned int* __restrict__ epack,
    const __half* __restrict__ pqh, __half* __restrict__ ash, int n_nodes)
{
    int row = blockIdx.x * 4 + (threadIdx.x >> 6);
    if (row >= n_nodes) return;
    int lane = threadIdx.x & 63;
    int beg = row_start[row], end = row_start[row + 1];

    float2 a0 = {0,0}, a1 = {0,0}, a2 = {0,0}, a3 = {0,0};
    int j = beg;
    for (; j + 3 < end; j += 4) {
        unsigned int p0 = epack[j],     p1 = epack[j + 1];
        unsigned int p2 = epack[j + 2], p3 = epack[j + 3];
        __half2 h0 = ((const __half2*)(pqh + (size_t)(p0 >> 16) * F2))[lane];
        __half2 h1 = ((const __half2*)(pqh + (size_t)(p1 >> 16) * F2))[lane];
        __half2 h2 = ((const __half2*)(pqh + (size_t)(p2 >> 16) * F2))[lane];
        __half2 h3 = ((const __half2*)(pqh + (size_t)(p3 >> 16) * F2))[lane];
        float v0 = pe_val(p0), v1 = pe_val(p1), v2 = pe_val(p2), v3 = pe_val(p3);
        float2 f0 = __half22float2(h0), f1 = __half22float2(h1);
        float2 f2 = __half22float2(h2), f3 = __half22float2(h3);
        a0.x += v0 * f0.x; a0.y += v0 * f0.y;
        a1.x += v1 * f1.x; a1.y += v1 * f1.y;
        a2.x += v2 * f2.x; a2.y += v2 * f2.y;
        a3.x += v3 * f3.x; a3.y += v3 * f3.y;
    }
    for (; j < end; ++j) {
        unsigned int p = epack[j];
        __half2 h = ((const __half2*)(pqh + (size_t)(p >> 16) * F2))[lane];
        float v = pe_val(p);
        float2 f = __half22float2(h);
        a0.x += v * f.x; a0.y += v * f.y;
    }
    float rx = a0.x + a1.x + a2.x + a3.x;
    float ry = a0.y + a1.y + a2.y + a3.y;
    union { __half2 h; unsigned int i; } o;
    o.h = __floats2half2_rn(rx, ry);
    ((unsigned int*)(ash + (size_t)row * KC))[lane] = o.i;
}

// ---------------------------------------------------------------------------
// K5a: coarse partials, 1024 threads/block for occupancy.
// which = blockIdx.y (0: S^T@AS, 1: S^T@Z). Thread owns 16 acc rows x 1 col.
// ---------------------------------------------------------------------------
__global__ __launch_bounds__(1024) void coarse_part(
    const __half* __restrict__ pqh, const __half* __restrict__ ash,
    float* __restrict__ part, int n_nodes)
{
    constexpr int ROWS = 16;
    const int which = blockIdx.y;
    const int tid = threadIdx.x;
    const int f  = tid & 127;           // output column
    const int k0 = (tid >> 7) * 16;     // output rows [k0, k0+16)
    __shared__ float sS[ROWS][128];
    float acc[16];
#pragma unroll
    for (int i = 0; i < 16; ++i) acc[i] = 0.f;
    const int stride = gridDim.x * ROWS;
    for (int n0 = blockIdx.x * ROWS; n0 < n_nodes; n0 += stride) {
        __syncthreads();
        {
            int rr = tid >> 6, c2 = tid & 63;   // 16 rows x 64 half2
            int n = n0 + rr;
            float2 fv = {0.f, 0.f};
            if (n < n_nodes)
                fv = __half22float2(((const __half2*)(pqh + (size_t)n * F2))[c2]);
            sS[rr][2 * c2]     = fv.x;
            sS[rr][2 * c2 + 1] = fv.y;
        }
        __syncthreads();
        int rmax = (n_nodes - n0 < ROWS) ? (n_nodes - n0) : ROWS;
        for (int rr = 0; rr < rmax; ++rr) {
            int n = n0 + rr;
            float v = __half2float(which ? pqh[(size_t)n * F2 + KC + f]
                                         : ash[(size_t)n * KC + f]);
            const float4* s4 = (const float4*)(&sS[rr][k0]);
#pragma unroll
            for (int i = 0; i < 4; ++i) {
                float4 sv = s4[i];
                acc[4 * i + 0] += sv.x * v;
                acc[4 * i + 1] += sv.y * v;
                acc[4 * i + 2] += sv.z * v;
                acc[4 * i + 3] += sv.w * v;
            }
        }
    }
    float* p = part + ((size_t)which * gridDim.x + blockIdx.x) * (KC * KC);
#pragma unroll
    for (int i = 0; i < 16; ++i)
        p[(size_t)(k0 + i) * KC + f] = acc[i];
}

// K5b: sum nb partial tiles per output element -> d_out (full overwrite)
__global__ __launch_bounds__(256) void coarse_reduce(
    const float* __restrict__ part, float* __restrict__ out, int nb)
{
    int e = blockIdx.x * 256 + threadIdx.x;      // 0 .. 2*16384-1
    int which = e >> 14;
    int idx = e & 16383;
    const float* p = part + (size_t)which * nb * (KC * KC) + idx;
    float s = 0.f;
    for (int t = 0; t < nb; ++t) s += p[(size_t)t * (KC * KC)];
    out[e] = s;
}

// ---------------------------------------------------------------------------
// Fallback f32 atomic path (only if n_nodes too large or ws too small)
// ---------------------------------------------------------------------------
__global__ __launch_bounds__(256) void gemm_xw_f(
    const float* __restrict__ x, const float* __restrict__ Wp,
    const float* __restrict__ We, float* __restrict__ xw, int n_nodes)
{
    constexpr int RPB = 32;
    __shared__ float xs[RPB][F_IN];
    const int r0 = blockIdx.x * RPB;
    const int tid = threadIdx.x;
    for (int i = tid; i < RPB * F_IN; i += 256) {
        int r = i >> 7, c = i & 127;
        int gr = r0 + r;
        xs[r][c] = (gr < n_nodes) ? x[(size_t)gr * F_IN + c] : 0.f;
    }
    __syncthreads();
    const int col = tid;
    const float* W = (col < KC) ? (Wp + col) : (We + (col - KC));
    float acc[RPB];
#pragma unroll
    for (int r = 0; r < RPB; ++r) acc[r] = 0.f;
    for (int k = 0; k < F_IN; ++k) {
        float w = W[(size_t)k * KC];
        const float* xk = &xs[0][k];
#pragma unroll
        for (int r = 0; r < RPB; ++r) acc[r] += xk[r * F_IN] * w;
    }
#pragma unroll
    for (int r = 0; r < RPB; ++r) {
        int gr = r0 + r;
        if (gr < n_nodes) xw[(size_t)gr * F2 + col] = acc[r];
    }
}

__global__ __launch_bounds__(256) void spmm_dual_kernel(
    const int* __restrict__ erow, const int* __restrict__ ecol,
    const float* __restrict__ eval_, const float* __restrict__ xw,
    float* __restrict__ pq, int n_edges)
{
    int e = blockIdx.x * 4 + (threadIdx.x >> 6);
    if (e >= n_edges) return;
    int lane = threadIdx.x & 63;
    int r = erow[e], c = ecol[e];
    float v = eval_[e];
    const float4* src = (const float4*)(xw + (size_t)c * F2);
    float* dst = pq + (size_t)r * F2;
    float4 s = src[lane];
    int f = lane * 4;
    atomicAdd(&dst[f + 0], v * s.x);
    atomicAdd(&dst[f + 1], v * s.y);
    atomicAdd(&dst[f + 2], v * s.z);
    atomicAdd(&dst[f + 3], v * s.w);
}

__global__ __launch_bounds__(64) void softmax_relu_kernel(
    float* __restrict__ pq, int n_nodes)
{
    int n = blockIdx.x;
    if (n >= n_nodes) return;
    int lane = threadIdx.x;
    float* p = pq + (size_t)n * F2;
    float a0 = fmaxf(p[lane], 0.f);
    float a1 = fmaxf(p[lane + 64], 0.f);
    float m = fmaxf(a0, a1);
#pragma unroll
    for (int off = 32; off; off >>= 1) m = fmaxf(m, __shfl_xor(m, off));
    float e0 = __expf(a0 - m), e1 = __expf(a1 - m);
    float ssum = e0 + e1;
#pragma unroll
    for (int off = 32; off; off >>= 1) ssum += __shfl_xor(ssum, off);
    float inv = 1.f / ssum;
    p[lane]      = e0 * inv;
    p[lane + 64] = e1 * inv;
    p[lane + 128] = fmaxf(p[lane + 128], 0.f);
    p[lane + 192] = fmaxf(p[lane + 192], 0.f);
}

__global__ __launch_bounds__(256) void spmm_s_kernel(
    const int* __restrict__ erow, const int* __restrict__ ecol,
    const float* __restrict__ eval_, const float* __restrict__ pq,
    float* __restrict__ as_, int n_edges)
{
    int e = blockIdx.x * 4 + (threadIdx.x >> 6);
    if (e >= n_edges) return;
    int lane = threadIdx.x & 63;
    int r = erow[e], c = ecol[e];
    float v = eval_[e];
    const float2* src = (const float2*)(pq + (size_t)c * F2);
    float* dst = as_ + (size_t)r * KC;
    float2 s = src[lane];
    int f = lane * 2;
    atomicAdd(&dst[f + 0], v * s.x);
    atomicAdd(&dst[f + 1], v * s.y);
}

__global__ __launch_bounds__(256) void coarse_f(
    const float* __restrict__ pq, const float* __restrict__ as_,
    float* __restrict__ out, int n_nodes)
{
    const int which = blockIdx.y;
    const int tid = threadIdx.x;
    const int f  = tid & 127;
    const int k0 = (tid >> 7) * 64;
    __shared__ float sS[8][128];
    float acc[64];
#pragma unroll
    for (int i = 0; i < 64; ++i) acc[i] = 0.f;
    const int stride = gridDim.x * 8;
    for (int n0 = blockIdx.x * 8; n0 < n_nodes; n0 += stride) {
        __syncthreads();
        for (int i = tid; i < 8 * 128; i += 256) {
            int rr = i >> 7, cc = i & 127;
            int n = n0 + rr;
            sS[rr][cc] = (n < n_nodes) ? pq[(size_t)n * F2 + cc] : 0.f;
        }
        __syncthreads();
        int rmax = (n_nodes - n0 < 8) ? (n_nodes - n0) : 8;
        for (int rr = 0; rr < rmax; ++rr) {
            int n = n0 + rr;
            float v = which ? pq[(size_t)n * F2 + KC + f]
                            : as_[(size_t)n * KC + f];
            const float4* s4 = (const float4*)(&sS[rr][k0]);
#pragma unroll
            for (int i = 0; i < 16; ++i) {
                float4 sv = s4[i];
                acc[4 * i + 0] += sv.x * v;
                acc[4 * i + 1] += sv.y * v;
                acc[4 * i + 2] += sv.z * v;
                acc[4 * i + 3] += sv.w * v;
            }
        }
    }
    float* o = out + (size_t)which * (KC * KC);
#pragma unroll
    for (int i = 0; i < 64; ++i)
        atomicAdd(&o[(size_t)(k0 + i) * KC + f], acc[i]);
}

// ---------------------------------------------------------------------------
extern "C" void kernel_launch(void* const* d_in, const int* in_sizes, int n_in,
                              void* d_out, int out_size, void* d_ws, size_t ws_size,
                              hipStream_t stream)
{
    const float* x     = (const float*)d_in[0];
    const int*   erow  = (const int*)d_in[1];
    const int*   ecol  = (const int*)d_in[2];
    const float* eval_ = (const float*)d_in[3];
    const float* Wp    = (const float*)d_in[4];
    const float* We    = (const float*)d_in[5];
    float* out = (float*)d_out;

    const int n_nodes = in_sizes[0] / F_IN;
    const int n_edges = in_sizes[1];
    const int nchunks = (n_nodes + 1023) / 1024;

    // fp16 CSR layout:
    //   xwh [N*256] h | pqh [N*256] h | ash [N*128] h
    //   row_start [N+1] i | cnt [N] i | epack [E] u32
    //   chunk_sum [1024] i | chunk_base [1024] i | wt [256*128] h
    //   part [2*NB_COARSE*16384] f32   (tail)
    __half* xwh = (__half*)d_ws;
    __half* pqh = xwh + (size_t)n_nodes * F2;
    __half* ash = pqh + (size_t)n_nodes * F2;
    int* row_start = (int*)(ash + (size_t)n_nodes * KC);
    int* cnt       = row_start + (n_nodes + 1);
    unsigned int* epack = (unsigned int*)(cnt + n_nodes);
    int* chunk_sum  = (int*)(epack + n_edges);
    int* chunk_base = chunk_sum + 1024;
    __half* wt      = (__half*)(chunk_base + 1024);
    // part: next 256B-aligned offset after wt
    size_t part_off = (((size_t)((char*)(wt + F2 * F_IN) - (char*)d_ws)) + 255) & ~(size_t)255;
    float* part = (float*)((char*)d_ws + part_off);

    const size_t needed_h = part_off + (size_t)2 * NB_COARSE * KC * KC * sizeof(float);

    if (n_nodes <= 65535 && nchunks <= 1024 && ws_size >= needed_h) {
        // ---- fast fp16 CSR + MFMA path ----
        transpose_w<<<F2, 128, 0, stream>>>(Wp, We, wt);
        gemm_xw_mfma<<<(n_nodes + 31) / 32, 256, 0, stream>>>(x, wt, xwh, n_nodes);

        hipMemsetAsync(cnt, 0, (size_t)n_nodes * sizeof(int), stream);
        hist_kernel<<<(n_edges + 255) / 256, 256, 0, stream>>>(erow, cnt, n_edges);
        scan_local<<<nchunks, 1024, 0, stream>>>(cnt, row_start, chunk_sum, n_nodes);
        scan_chunks<<<1, 1024, 0, stream>>>(chunk_sum, chunk_base, row_start,
                                            nchunks, n_nodes);
        scan_add<<<(n_nodes + 255) / 256, 256, 0, stream>>>(row_start, chunk_base,
                                                            n_nodes);
        hipMemsetAsync(cnt, 0, (size_t)n_nodes * sizeof(int), stream);
        scatter_pack_kernel<<<(n_edges + 255) / 256, 256, 0, stream>>>(
            erow, ecol, eval_, row_start, cnt, epack, n_edges);

        spmm_dual_csr<<<(n_nodes + 3) / 4, 256, 0, stream>>>(
            row_start, epack, xwh, pqh, n_nodes);
        spmm_s_csr<<<(n_nodes + 3) / 4, 256, 0, stream>>>(
            row_start, epack, pqh, ash, n_nodes);

        coarse_part<<<dim3(NB_COARSE, 2), 1024, 0, stream>>>(pqh, ash, part, n_nodes);
        coarse_reduce<<<(2 * KC * KC) / 256, 256, 0, stream>>>(part, out, NB_COARSE);
    } else {
        // ---- f32 atomic fallback ----
        float* xw  = (float*)d_ws;
        float* pq  = xw + (size_t)n_nodes * F2;
        float* as_ = xw;
        hipMemsetAsync(d_out, 0, (size_t)out_size * sizeof(float), stream);
        gemm_xw_f<<<(n_nodes + 31) / 32, 256, 0, stream>>>(x, Wp, We, xw, n_nodes);
        hipMemsetAsync(pq, 0, (size_t)n_nodes * F2 * sizeof(float), stream);
        spmm_dual_kernel<<<(n_edges + 3) / 4, 256, 0, stream>>>(
            erow, ecol, eval_, xw, pq, n_edges);
        softmax_relu_kernel<<<n_nodes, 64, 0, stream>>>(pq, n_nodes);
        hipMemsetAsync(as_, 0, (size_t)n_nodes * KC * sizeof(float), stream);
        spmm_s_kernel<<<(n_edges + 3) / 4, 256, 0, stream>>>(
            erow, ecol, eval_, pq, as_, n_edges);
        coarse_f<<<dim3(128, 2), 256, 0, stream>>>(pq, as_, out, n_nodes);
    }
}

// Round 6
// 441.705 us; speedup vs baseline: 15.7359x; 1.1244x over previous
//
#include <hip/hip_runtime.h>
#include <hip/hip_fp16.h>

constexpr int F_IN = 128;
constexpr int KC   = 128;   // K_CLUST == F_EMB == 128
constexpr int F2   = 256;   // K_CLUST + F_EMB
constexpr int NB_COARSE = 384;   // partial tiles per output
constexpr int CROWS = 16;        // node rows per coarse tile

typedef _Float16 f16x8 __attribute__((ext_vector_type(8)));
typedef float    f32x4 __attribute__((ext_vector_type(4)));
typedef float    f32x2 __attribute__((ext_vector_type(2)));

// ---------- fp16 helpers ----------
__device__ __forceinline__ float4 h8_to_f4(uint2 u) {
    union { unsigned int i; __half2 h; } a, b;
    a.i = u.x; b.i = u.y;
    float2 f0 = __half22float2(a.h);
    float2 f1 = __half22float2(b.h);
    return make_float4(f0.x, f0.y, f1.x, f1.y);
}
__device__ __forceinline__ unsigned int f2_to_h2u(float x, float y) {
    union { __half2 h; unsigned int i; } c;
    c.h = __floats2half2_rn(x, y);
    return c.i;
}
__device__ __forceinline__ float pe_val(unsigned int pe) {
    return __half2float(__ushort_as_half((unsigned short)(pe & 0xffffu)));
}

// ---------- fp8 e4m3fn helpers ----------
// encode f32 -> e4m3fn (RNE via half; flush |v|<2^-6 to signed zero; clamp to 448)
__device__ __forceinline__ unsigned char f32_to_fp8(float f) {
    union { __half h; unsigned short u; } c; c.h = __float2half_rn(f);
    unsigned short h = c.u;
    unsigned int s = (h >> 8) & 0x80u;
    int e5 = (h >> 10) & 0x1f;
    if (e5 < 9) return (unsigned char)s;
    unsigned int c7 = ((unsigned int)(e5 - 8) << 3) | ((h >> 7) & 7u);
    unsigned int rem = h & 0x7fu;
    c7 += (rem > 0x40u) || ((rem == 0x40u) && (c7 & 1u));
    if (c7 > 0x7eu) c7 = 0x7eu;
    return (unsigned char)(s | c7);
}
// decode 4x e4m3fn packed in a dword -> 4 floats
__device__ __forceinline__ float4 fp8x4_dec(unsigned int u) {
#if __has_builtin(__builtin_amdgcn_cvt_pk_f32_fp8)
    f32x2 lo = __builtin_amdgcn_cvt_pk_f32_fp8((int)u, false);
    f32x2 hi = __builtin_amdgcn_cvt_pk_f32_fp8((int)u, true);
    return make_float4(lo.x, lo.y, hi.x, hi.y);
#else
    unsigned int e01 = (u & 0xffu) | ((u & 0xff00u) << 8);
    unsigned int e23 = ((u >> 16) & 0xffu) | ((u & 0xff000000u) >> 8);
    unsigned int h01 = ((e01 & 0x00800080u) << 8) | (((e01 & 0x007f007fu) << 7) + 0x20002000u);
    unsigned int h23 = ((e23 & 0x00800080u) << 8) | (((e23 & 0x007f007fu) << 7) + 0x20002000u);
    union { unsigned int i; __half2 h; } t0, t1;
    t0.i = h01; t1.i = h23;
    float2 f0 = __half22float2(t0.h), f1 = __half22float2(t1.h);
    return make_float4(f0.x, f0.y, f1.x, f1.y);
#endif
}

__device__ __forceinline__ void h8_store(float* dst, uint4 u) {
    union { unsigned int i; __half2 h; } t;
    t.i = u.x; { float2 f = __half22float2(t.h); dst[0] = f.x; dst[1] = f.y; }
    t.i = u.y; { float2 f = __half22float2(t.h); dst[2] = f.x; dst[3] = f.y; }
    t.i = u.z; { float2 f = __half22float2(t.h); dst[4] = f.x; dst[5] = f.y; }
    t.i = u.w; { float2 f = __half22float2(t.h); dst[6] = f.x; dst[7] = f.y; }
}

// ---------------------------------------------------------------------------
// W transpose: wt[col][k] = W[k][col], fp16. col 0..255 (Wp|We), k 0..127.
// ---------------------------------------------------------------------------
__global__ __launch_bounds__(128) void transpose_w(
    const float* __restrict__ Wp, const float* __restrict__ We,
    __half* __restrict__ wt)
{
    int col = blockIdx.x;
    int k   = threadIdx.x;
    float v = (col < KC) ? Wp[(size_t)k * KC + col]
                         : We[(size_t)k * KC + (col - KC)];
    wt[(size_t)col * F_IN + k] = __float2half_rn(v);
}

// ---------------------------------------------------------------------------
// K1: XW = x @ [W_pool | W_embed] -> fp8 [N,256], via MFMA 16x16x32_f16.
// ---------------------------------------------------------------------------
__global__ __launch_bounds__(256) void gemm_xw_mfma(
    const float* __restrict__ x, const __half* __restrict__ wt,
    unsigned char* __restrict__ xw8, int n_nodes)
{
    __shared__ _Float16 xs[32][136];
    const int r0 = blockIdx.x * 32;
    const int tid = threadIdx.x;
    {
        int r = tid >> 3, c0 = (tid & 7) * 16;
        int gr = r0 + r;
        if (gr < n_nodes) {
            const float4* src = (const float4*)(x + (size_t)gr * F_IN + c0);
#pragma unroll
            for (int i = 0; i < 4; ++i) {
                float4 f = src[i];
                xs[r][c0 + 4 * i + 0] = (_Float16)f.x;
                xs[r][c0 + 4 * i + 1] = (_Float16)f.y;
                xs[r][c0 + 4 * i + 2] = (_Float16)f.z;
                xs[r][c0 + 4 * i + 3] = (_Float16)f.w;
            }
        } else {
#pragma unroll
            for (int i = 0; i < 16; ++i) xs[r][c0 + i] = (_Float16)0.f;
        }
    }
    __syncthreads();

    const int w = tid >> 6, lane = tid & 63;
    const int lrow = lane & 15;
    const int lk   = (lane >> 4) * 8;

    f16x8 bfrag[4][4];
#pragma unroll
    for (int cb = 0; cb < 4; ++cb) {
        int gcol = (w * 4 + cb) * 16 + lrow;
        const f16x8* bp = (const f16x8*)(wt + (size_t)gcol * F_IN + lk);
#pragma unroll
        for (int kc = 0; kc < 4; ++kc) bfrag[cb][kc] = bp[kc * 4];
    }

    f32x4 acc[2][4];
#pragma unroll
    for (int rb = 0; rb < 2; ++rb)
#pragma unroll
        for (int cb = 0; cb < 4; ++cb) acc[rb][cb] = (f32x4){0.f, 0.f, 0.f, 0.f};

#pragma unroll
    for (int kc = 0; kc < 4; ++kc) {
        f16x8 a0 = *(const f16x8*)(&xs[lrow][kc * 32 + lk]);
        f16x8 a1 = *(const f16x8*)(&xs[16 + lrow][kc * 32 + lk]);
#pragma unroll
        for (int cb = 0; cb < 4; ++cb) {
            acc[0][cb] = __builtin_amdgcn_mfma_f32_16x16x32_f16(a0, bfrag[cb][kc], acc[0][cb], 0, 0, 0);
            acc[1][cb] = __builtin_amdgcn_mfma_f32_16x16x32_f16(a1, bfrag[cb][kc], acc[1][cb], 0, 0, 0);
        }
    }

#pragma unroll
    for (int rb = 0; rb < 2; ++rb) {
#pragma unroll
        for (int cb = 0; cb < 4; ++cb) {
            int gcol = (w * 4 + cb) * 16 + lrow;
#pragma unroll
            for (int reg = 0; reg < 4; ++reg) {
                int grow = r0 + rb * 16 + (lane >> 4) * 4 + reg;
                if (grow < n_nodes)
                    xw8[(size_t)grow * F2 + gcol] = f32_to_fp8(acc[rb][cb][reg]);
            }
        }
    }
}

// ---------------------------------------------------------------------------
// CSR build
// ---------------------------------------------------------------------------
__global__ __launch_bounds__(256) void hist_kernel(
    const int* __restrict__ erow, int* __restrict__ cnt, int n_edges)
{
    int e = blockIdx.x * 256 + threadIdx.x;
    if (e < n_edges) atomicAdd(&cnt[erow[e]], 1);
}

// chunk-local exclusive scan (1024/block) + chunk totals; zeroes cnt in-place
__global__ __launch_bounds__(1024) void scan_local(
    int* __restrict__ cnt, int* __restrict__ row_start,
    int* __restrict__ chunk_sum, int n)
{
    __shared__ int wsum[16];
    const int tid = threadIdx.x;
    const int lane = tid & 63, wid = tid >> 6;
    int i = blockIdx.x * 1024 + tid;
    int v = (i < n) ? cnt[i] : 0;
    int incl = v;
#pragma unroll
    for (int off = 1; off < 64; off <<= 1) {
        int t = __shfl_up(incl, off);
        if (lane >= off) incl += t;
    }
    if (lane == 63) wsum[wid] = incl;
    __syncthreads();
    if (tid == 0) {
        int s = 0;
#pragma unroll
        for (int w = 0; w < 16; ++w) { int t = wsum[w]; wsum[w] = s; s += t; }
    }
    __syncthreads();
    if (i < n) { row_start[i] = wsum[wid] + incl - v; cnt[i] = 0; }
    if (tid == 1023) chunk_sum[blockIdx.x] = wsum[15] + incl;
}

__global__ __launch_bounds__(1024) void scan_chunks(
    const int* __restrict__ chunk_sum, int* __restrict__ chunk_base,
    int* __restrict__ row_start, int nchunks, int n)
{
    __shared__ int wsum[16];
    const int tid = threadIdx.x;
    const int lane = tid & 63, wid = tid >> 6;
    int v = (tid < nchunks) ? chunk_sum[tid] : 0;
    int incl = v;
#pragma unroll
    for (int off = 1; off < 64; off <<= 1) {
        int t = __shfl_up(incl, off);
        if (lane >= off) incl += t;
    }
    if (lane == 63) wsum[wid] = incl;
    __syncthreads();
    if (tid == 0) {
        int s = 0;
#pragma unroll
        for (int w = 0; w < 16; ++w) { int t = wsum[w]; wsum[w] = s; s += t; }
    }
    __syncthreads();
    int excl = wsum[wid] + incl - v;
    if (tid < nchunks) chunk_base[tid] = excl;
    if (tid == nchunks - 1) row_start[n] = excl + v;
}

__global__ __launch_bounds__(256) void scan_add(
    int* __restrict__ row_start, const int* __restrict__ chunk_base, int n)
{
    int i = blockIdx.x * 256 + threadIdx.x;
    if (i < n) row_start[i] += chunk_base[i >> 10];
}

__global__ __launch_bounds__(256) void scatter_pack_kernel(
    const int* __restrict__ erow, const int* __restrict__ ecol,
    const float* __restrict__ eval_, const int* __restrict__ row_start,
    int* __restrict__ cursor, unsigned int* __restrict__ epack, int n_edges)
{
    int e = blockIdx.x * 256 + threadIdx.x;
    if (e >= n_edges) return;
    int r = erow[e];
    int pos = row_start[r] + atomicAdd(&cursor[r], 1);
    union { __half h; unsigned short u; } hv;
    hv.h = __float2half_rn(eval_[e]);
    epack[pos] = ((unsigned int)ecol[e] << 16) | (unsigned int)hv.u;
}

// ---------------------------------------------------------------------------
// K2: CSR SpMM over 256 fp8 cols, one wave/row, fused relu+softmax, fp16 out.
// Lane l holds cols 4l..4l+3: lanes 0..31 = P (softmax), 32..63 = Q (relu).
// ---------------------------------------------------------------------------
__global__ __launch_bounds__(256) void spmm_dual_csr(
    const int* __restrict__ row_start, const unsigned int* __restrict__ epack,
    const unsigned char* __restrict__ xw8, __half* __restrict__ pqh, int n_nodes)
{
    int row = blockIdx.x * 4 + (threadIdx.x >> 6);
    if (row >= n_nodes) return;
    int lane = threadIdx.x & 63;
    int beg = row_start[row], end = row_start[row + 1];

    float4 a0 = {0,0,0,0}, a1 = {0,0,0,0}, a2 = {0,0,0,0}, a3 = {0,0,0,0};
    int j = beg;
    for (; j + 3 < end; j += 4) {
        unsigned int p0 = epack[j],     p1 = epack[j + 1];
        unsigned int p2 = epack[j + 2], p3 = epack[j + 3];
        unsigned int u0 = ((const unsigned int*)(xw8 + (size_t)(p0 >> 16) * F2))[lane];
        unsigned int u1 = ((const unsigned int*)(xw8 + (size_t)(p1 >> 16) * F2))[lane];
        unsigned int u2 = ((const unsigned int*)(xw8 + (size_t)(p2 >> 16) * F2))[lane];
        unsigned int u3 = ((const unsigned int*)(xw8 + (size_t)(p3 >> 16) * F2))[lane];
        float v0 = pe_val(p0), v1 = pe_val(p1), v2 = pe_val(p2), v3 = pe_val(p3);
        float4 s0 = fp8x4_dec(u0), s1 = fp8x4_dec(u1);
        float4 s2 = fp8x4_dec(u2), s3 = fp8x4_dec(u3);
        a0.x += v0 * s0.x; a0.y += v0 * s0.y; a0.z += v0 * s0.z; a0.w += v0 * s0.w;
        a1.x += v1 * s1.x; a1.y += v1 * s1.y; a1.z += v1 * s1.z; a1.w += v1 * s1.w;
        a2.x += v2 * s2.x; a2.y += v2 * s2.y; a2.z += v2 * s2.z; a2.w += v2 * s2.w;
        a3.x += v3 * s3.x; a3.y += v3 * s3.y; a3.z += v3 * s3.z; a3.w += v3 * s3.w;
    }
    for (; j < end; ++j) {
        unsigned int p = epack[j];
        unsigned int u = ((const unsigned int*)(xw8 + (size_t)(p >> 16) * F2))[lane];
        float v = pe_val(p);
        float4 s = fp8x4_dec(u);
        a0.x += v * s.x; a0.y += v * s.y; a0.z += v * s.z; a0.w += v * s.w;
    }
    float4 a;
    a.x = a0.x + a1.x + a2.x + a3.x;
    a.y = a0.y + a1.y + a2.y + a3.y;
    a.z = a0.z + a1.z + a2.z + a3.z;
    a.w = a0.w + a1.w + a2.w + a3.w;

    a.x = fmaxf(a.x, 0.f); a.y = fmaxf(a.y, 0.f);
    a.z = fmaxf(a.z, 0.f); a.w = fmaxf(a.w, 0.f);

    float m = fmaxf(fmaxf(a.x, a.y), fmaxf(a.z, a.w));
#pragma unroll
    for (int off = 16; off; off >>= 1) m = fmaxf(m, __shfl_xor(m, off));
    float ex = __expf(a.x - m), ey = __expf(a.y - m);
    float ez = __expf(a.z - m), ew = __expf(a.w - m);
    float ssum = ex + ey + ez + ew;
#pragma unroll
    for (int off = 16; off; off >>= 1) ssum += __shfl_xor(ssum, off);
    float inv = 1.f / ssum;

    bool isP = lane < 32;
    float wx = isP ? ex * inv : a.x;
    float wy = isP ? ey * inv : a.y;
    float wz = isP ? ez * inv : a.z;
    float ww = isP ? ew * inv : a.w;
    ((uint2*)(pqh + (size_t)row * F2))[lane] =
        make_uint2(f2_to_h2u(wx, wy), f2_to_h2u(wz, ww));
}

// ---------------------------------------------------------------------------
// K4: AS = A @ S (fp16 gather of S = pqh[:,0:128], stride 256), fp16 out.
// ---------------------------------------------------------------------------
__global__ __launch_bounds__(256) void spmm_s_csr(
    const int* __restrict__ row_start, const unsigned int* __restrict__ epack,
    const __half* __restrict__ pqh, __half* __restrict__ ash, int n_nodes)
{
    int row = blockIdx.x * 4 + (threadIdx.x >> 6);
    if (row >= n_nodes) return;
    int lane = threadIdx.x & 63;
    int beg = row_start[row], end = row_start[row + 1];

    float2 a0 = {0,0}, a1 = {0,0}, a2 = {0,0}, a3 = {0,0};
    int j = beg;
    for (; j + 3 < end; j += 4) {
        unsigned int p0 = epack[j],     p1 = epack[j + 1];
        unsigned int p2 = epack[j + 2], p3 = epack[j + 3];
        __half2 h0 = ((const __half2*)(pqh + (size_t)(p0 >> 16) * F2))[lane];
        __half2 h1 = ((const __half2*)(pqh + (size_t)(p1 >> 16) * F2))[lane];
        __half2 h2 = ((const __half2*)(pqh + (size_t)(p2 >> 16) * F2))[lane];
        __half2 h3 = ((const __half2*)(pqh + (size_t)(p3 >> 16) * F2))[lane];
        float v0 = pe_val(p0), v1 = pe_val(p1), v2 = pe_val(p2), v3 = pe_val(p3);
        float2 f0 = __half22float2(h0), f1 = __half22float2(h1);
        float2 f2 = __half22float2(h2), f3 = __half22float2(h3);
        a0.x += v0 * f0.x; a0.y += v0 * f0.y;
        a1.x += v1 * f1.x; a1.y += v1 * f1.y;
        a2.x += v2 * f2.x; a2.y += v2 * f2.y;
        a3.x += v3 * f3.x; a3.y += v3 * f3.y;
    }
    for (; j < end; ++j) {
        unsigned int p = epack[j];
        __half2 h = ((const __half2*)(pqh + (size_t)(p >> 16) * F2))[lane];
        float v = pe_val(p);
        float2 f = __half22float2(h);
        a0.x += v * f.x; a0.y += v * f.y;
    }
    float rx = a0.x + a1.x + a2.x + a3.x;
    float ry = a0.y + a1.y + a2.y + a3.y;
    union { __half2 h; unsigned int i; } o;
    o.h = __floats2half2_rn(rx, ry);
    ((unsigned int*)(ash + (size_t)row * KC))[lane] = o.i;
}

// ---------------------------------------------------------------------------
// K5a: coarse partials, 8x8 register outer-product per thread.
// which = blockIdx.y (0: S^T@AS, 1: S^T@Z). Both operands LDS-staged.
// Thread (tid): output rows k0..k0+7 (S cols), output cols f0..f0+7.
// ---------------------------------------------------------------------------
__global__ __launch_bounds__(256) void coarse_part(
    const __half* __restrict__ pqh, const __half* __restrict__ ash,
    float* __restrict__ part, int n_nodes)
{
    const int which = blockIdx.y;
    const int tid = threadIdx.x;
    const int k0 = (tid >> 4) * 8;
    const int f0 = (tid & 15) * 8;
    __shared__ float sS[CROWS][128];
    __shared__ float sV[CROWS][128];
    float acc[8][8];
#pragma unroll
    for (int i = 0; i < 8; ++i)
#pragma unroll
        for (int jj = 0; jj < 8; ++jj) acc[i][jj] = 0.f;

    const int stride = gridDim.x * CROWS;
    for (int n0 = blockIdx.x * CROWS; n0 < n_nodes; n0 += stride) {
        __syncthreads();
        {
            int rr = tid >> 4;           // 0..15
            int cc = (tid & 15) * 8;     // 0..120
            int n = n0 + rr;
            if (n < n_nodes) {
                uint4 us = *(const uint4*)(pqh + (size_t)n * F2 + cc);
                h8_store(&sS[rr][cc], us);
                uint4 uv = which
                    ? *(const uint4*)(pqh + (size_t)n * F2 + KC + cc)
                    : *(const uint4*)(ash + (size_t)n * KC + cc);
                h8_store(&sV[rr][cc], uv);
            } else {
#pragma unroll
                for (int i = 0; i < 8; ++i) { sS[rr][cc + i] = 0.f; sV[rr][cc + i] = 0.f; }
            }
        }
        __syncthreads();
#pragma unroll 4
        for (int rr = 0; rr < CROWS; ++rr) {
            const float4* sp = (const float4*)(&sS[rr][k0]);
            float4 s0 = sp[0], s1 = sp[1];
            const float4* vp = (const float4*)(&sV[rr][f0]);
            float4 v0 = vp[0], v1 = vp[1];
            float sv[8] = {s0.x, s0.y, s0.z, s0.w, s1.x, s1.y, s1.z, s1.w};
            float vv[8] = {v0.x, v0.y, v0.z, v0.w, v1.x, v1.y, v1.z, v1.w};
#pragma unroll
            for (int i = 0; i < 8; ++i)
#pragma unroll
                for (int jj = 0; jj < 8; ++jj) acc[i][jj] += sv[i] * vv[jj];
        }
    }
    float* p = part + ((size_t)which * gridDim.x + blockIdx.x) * (KC * KC);
#pragma unroll
    for (int i = 0; i < 8; ++i) {
        float4 o0 = {acc[i][0], acc[i][1], acc[i][2], acc[i][3]};
        float4 o1 = {acc[i][4], acc[i][5], acc[i][6], acc[i][7]};
        *(float4*)(&p[(size_t)(k0 + i) * KC + f0])     = o0;
        *(float4*)(&p[(size_t)(k0 + i) * KC + f0 + 4]) = o1;
    }
}

// K5b: sum nb partial tiles per output element -> d_out (full overwrite)
__global__ __launch_bounds__(256) void coarse_reduce(
    const float* __restrict__ part, float* __restrict__ out, int nb)
{
    int e = blockIdx.x * 256 + threadIdx.x;
    int which = e >> 14;
    int idx = e & 16383;
    const float* p = part + (size_t)which * nb * (KC * KC) + idx;
    float s = 0.f;
    for (int t = 0; t < nb; ++t) s += p[(size_t)t * (KC * KC)];
    out[e] = s;
}

// ---------------------------------------------------------------------------
// Fallback f32 atomic path (only if shapes/ws don't fit the fast path)
// ---------------------------------------------------------------------------
__global__ __launch_bounds__(256) void gemm_xw_f(
    const float* __restrict__ x, const float* __restrict__ Wp,
    const float* __restrict__ We, float* __restrict__ xw, int n_nodes)
{
    constexpr int RPB = 32;
    __shared__ float xs[RPB][F_IN];
    const int r0 = blockIdx.x * RPB;
    const int tid = threadIdx.x;
    for (int i = tid; i < RPB * F_IN; i += 256) {
        int r = i >> 7, c = i & 127;
        int gr = r0 + r;
        xs[r][c] = (gr < n_nodes) ? x[(size_t)gr * F_IN + c] : 0.f;
    }
    __syncthreads();
    const int col = tid;
    const float* W = (col < KC) ? (Wp + col) : (We + (col - KC));
    float acc[RPB];
#pragma unroll
    for (int r = 0; r < RPB; ++r) acc[r] = 0.f;
    for (int k = 0; k < F_IN; ++k) {
        float w = W[(size_t)k * KC];
        const float* xk = &xs[0][k];
#pragma unroll
        for (int r = 0; r < RPB; ++r) acc[r] += xk[r * F_IN] * w;
    }
#pragma unroll
    for (int r = 0; r < RPB; ++r) {
        int gr = r0 + r;
        if (gr < n_nodes) xw[(size_t)gr * F2 + col] = acc[r];
    }
}

__global__ __launch_bounds__(256) void spmm_dual_kernel(
    const int* __restrict__ erow, const int* __restrict__ ecol,
    const float* __restrict__ eval_, const float* __restrict__ xw,
    float* __restrict__ pq, int n_edges)
{
    int e = blockIdx.x * 4 + (threadIdx.x >> 6);
    if (e >= n_edges) return;
    int lane = threadIdx.x & 63;
    int r = erow[e], c = ecol[e];
    float v = eval_[e];
    const float4* src = (const float4*)(xw + (size_t)c * F2);
    float* dst = pq + (size_t)r * F2;
    float4 s = src[lane];
    int f = lane * 4;
    atomicAdd(&dst[f + 0], v * s.x);
    atomicAdd(&dst[f + 1], v * s.y);
    atomicAdd(&dst[f + 2], v * s.z);
    atomicAdd(&dst[f + 3], v * s.w);
}

__global__ __launch_bounds__(64) void softmax_relu_kernel(
    float* __restrict__ pq, int n_nodes)
{
    int n = blockIdx.x;
    if (n >= n_nodes) return;
    int lane = threadIdx.x;
    float* p = pq + (size_t)n * F2;
    float a0 = fmaxf(p[lane], 0.f);
    float a1 = fmaxf(p[lane + 64], 0.f);
    float m = fmaxf(a0, a1);
#pragma unroll
    for (int off = 32; off; off >>= 1) m = fmaxf(m, __shfl_xor(m, off));
    float e0 = __expf(a0 - m), e1 = __expf(a1 - m);
    float ssum = e0 + e1;
#pragma unroll
    for (int off = 32; off; off >>= 1) ssum += __shfl_xor(ssum, off);
    float inv = 1.f / ssum;
    p[lane]      = e0 * inv;
    p[lane + 64] = e1 * inv;
    p[lane + 128] = fmaxf(p[lane + 128], 0.f);
    p[lane + 192] = fmaxf(p[lane + 192], 0.f);
}

__global__ __launch_bounds__(256) void spmm_s_kernel(
    const int* __restrict__ erow, const int* __restrict__ ecol,
    const float* __restrict__ eval_, const float* __restrict__ pq,
    float* __restrict__ as_, int n_edges)
{
    int e = blockIdx.x * 4 + (threadIdx.x >> 6);
    if (e >= n_edges) return;
    int lane = threadIdx.x & 63;
    int r = erow[e], c = ecol[e];
    float v = eval_[e];
    const float2* src = (const float2*)(pq + (size_t)c * F2);
    float* dst = as_ + (size_t)r * KC;
    float2 s = src[lane];
    int f = lane * 2;
    atomicAdd(&dst[f + 0], v * s.x);
    atomicAdd(&dst[f + 1], v * s.y);
}

__global__ __launch_bounds__(256) void coarse_f(
    const float* __restrict__ pq, const float* __restrict__ as_,
    float* __restrict__ out, int n_nodes)
{
    const int which = blockIdx.y;
    const int tid = threadIdx.x;
    const int f  = tid & 127;
    const int k0 = (tid >> 7) * 64;
    __shared__ float sS[8][128];
    float acc[64];
#pragma unroll
    for (int i = 0; i < 64; ++i) acc[i] = 0.f;
    const int stride = gridDim.x * 8;
    for (int n0 = blockIdx.x * 8; n0 < n_nodes; n0 += stride) {
        __syncthreads();
        for (int i = tid; i < 8 * 128; i += 256) {
            int rr = i >> 7, cc = i & 127;
            int n = n0 + rr;
            sS[rr][cc] = (n < n_nodes) ? pq[(size_t)n * F2 + cc] : 0.f;
        }
        __syncthreads();
        int rmax = (n_nodes - n0 < 8) ? (n_nodes - n0) : 8;
        for (int rr = 0; rr < rmax; ++rr) {
            int n = n0 + rr;
            float v = which ? pq[(size_t)n * F2 + KC + f]
                            : as_[(size_t)n * KC + f];
            const float4* s4 = (const float4*)(&sS[rr][k0]);
#pragma unroll
            for (int i = 0; i < 16; ++i) {
                float4 sv = s4[i];
                acc[4 * i + 0] += sv.x * v;
                acc[4 * i + 1] += sv.y * v;
                acc[4 * i + 2] += sv.z * v;
                acc[4 * i + 3] += sv.w * v;
            }
        }
    }
    float* o = out + (size_t)which * (KC * KC);
#pragma unroll
    for (int i = 0; i < 64; ++i)
        atomicAdd(&o[(size_t)(k0 + i) * KC + f], acc[i]);
}

// ---------------------------------------------------------------------------
extern "C" void kernel_launch(void* const* d_in, const int* in_sizes, int n_in,
                              void* d_out, int out_size, void* d_ws, size_t ws_size,
                              hipStream_t stream)
{
    const float* x     = (const float*)d_in[0];
    const int*   erow  = (const int*)d_in[1];
    const int*   ecol  = (const int*)d_in[2];
    const float* eval_ = (const float*)d_in[3];
    const float* Wp    = (const float*)d_in[4];
    const float* We    = (const float*)d_in[5];
    float* out = (float*)d_out;

    const int n_nodes = in_sizes[0] / F_IN;
    const int n_edges = in_sizes[1];
    const int nchunks = (n_nodes + 1023) / 1024;

    // bump allocator, 256B-aligned regions
    char* base = (char*)d_ws;
    size_t off = 0;
    auto alloc = [&](size_t bytes) -> void* {
        off = (off + 255) & ~(size_t)255;
        void* p = base + off;
        off += bytes;
        return p;
    };
    unsigned char* xw8 = (unsigned char*)alloc((size_t)n_nodes * F2);
    __half* pqh        = (__half*)alloc((size_t)n_nodes * F2 * 2);
    __half* ash        = (__half*)alloc((size_t)n_nodes * KC * 2);
    int* row_start     = (int*)alloc(((size_t)n_nodes + 1) * 4);
    int* cnt           = (int*)alloc((size_t)n_nodes * 4);
    unsigned int* epack = (unsigned int*)alloc((size_t)n_edges * 4);
    int* chunk_sum     = (int*)alloc(1024 * 4);
    int* chunk_base    = (int*)alloc(1024 * 4);
    __half* wt         = (__half*)alloc((size_t)F2 * F_IN * 2);
    float* part        = (float*)alloc((size_t)2 * NB_COARSE * KC * KC * 4);
    const size_t needed_h = off;

    if (n_nodes <= 65535 && nchunks <= 1024 && ws_size >= needed_h) {
        // ---- fast fp8/fp16 CSR + MFMA path ----
        transpose_w<<<F2, 128, 0, stream>>>(Wp, We, wt);
        gemm_xw_mfma<<<(n_nodes + 31) / 32, 256, 0, stream>>>(x, wt, xw8, n_nodes);

        hipMemsetAsync(cnt, 0, (size_t)n_nodes * sizeof(int), stream);
        hist_kernel<<<(n_edges + 255) / 256, 256, 0, stream>>>(erow, cnt, n_edges);
        scan_local<<<nchunks, 1024, 0, stream>>>(cnt, row_start, chunk_sum, n_nodes);
        scan_chunks<<<1, 1024, 0, stream>>>(chunk_sum, chunk_base, row_start,
                                            nchunks, n_nodes);
        scan_add<<<(n_nodes + 255) / 256, 256, 0, stream>>>(row_start, chunk_base,
                                                            n_nodes);
        scatter_pack_kernel<<<(n_edges + 255) / 256, 256, 0, stream>>>(
            erow, ecol, eval_, row_start, cnt, epack, n_edges);

        spmm_dual_csr<<<(n_nodes + 3) / 4, 256, 0, stream>>>(
            row_start, epack, xw8, pqh, n_nodes);
        spmm_s_csr<<<(n_nodes + 3) / 4, 256, 0, stream>>>(
            row_start, epack, pqh, ash, n_nodes);

        coarse_part<<<dim3(NB_COARSE, 2), 256, 0, stream>>>(pqh, ash, part, n_nodes);
        coarse_reduce<<<(2 * KC * KC) / 256, 256, 0, stream>>>(part, out, NB_COARSE);
    } else {
        // ---- f32 atomic fallback ----
        float* xw  = (float*)d_ws;
        float* pq  = xw + (size_t)n_nodes * F2;
        float* as_ = xw;
        hipMemsetAsync(d_out, 0, (size_t)out_size * sizeof(float), stream);
        gemm_xw_f<<<(n_nodes + 31) / 32, 256, 0, stream>>>(x, Wp, We, xw, n_nodes);
        hipMemsetAsync(pq, 0, (size_t)n_nodes * F2 * sizeof(float), stream);
        spmm_dual_kernel<<<(n_edges + 3) / 4, 256, 0, stream>>>(
            erow, ecol, eval_, xw, pq, n_edges);
        softmax_relu_kernel<<<n_nodes, 64, 0, stream>>>(pq, n_nodes);
        hipMemsetAsync(as_, 0, (size_t)n_nodes * KC * sizeof(float), stream);
        spmm_s_kernel<<<(n_edges + 3) / 4, 256, 0, stream>>>(
            erow, ecol, eval_, pq, as_, n_edges);
        coarse_f<<<dim3(128, 2), 256, 0, stream>>>(pq, as_, out, n_nodes);
    }
}

// Round 7
// 323.651 us; speedup vs baseline: 21.4757x; 1.3648x over previous
//
#include <hip/hip_runtime.h>
#include <hip/hip_fp16.h>

constexpr int F_IN = 128;
constexpr int KC   = 128;   // K_CLUST == F_EMB == 128
constexpr int F2   = 256;   // K_CLUST + F_EMB
constexpr int NB_COARSE = 256;   // partial tiles per output
constexpr int CROWS = 16;        // node rows per coarse tile
constexpr int NBLK_SORT = 256;   // blocks in bin-count / bin-place passes
constexpr int BIN_SHIFT = 7;     // 128 rows per bin
constexpr int MAXBIN = 512;      // ceil(65536/128)

typedef _Float16 f16x8 __attribute__((ext_vector_type(8)));
typedef float    f32x4 __attribute__((ext_vector_type(4)));
typedef float    f32x2 __attribute__((ext_vector_type(2)));

// ---------- fp16 helpers ----------
__device__ __forceinline__ unsigned int f2_to_h2u(float x, float y) {
    union { __half2 h; unsigned int i; } c;
    c.h = __floats2half2_rn(x, y);
    return c.i;
}
__device__ __forceinline__ float pe_val(unsigned int pe) {
    return __half2float(__ushort_as_half((unsigned short)(pe & 0xffffu)));
}

// ---------- fp8 e4m3fn helpers ----------
__device__ __forceinline__ unsigned char f32_to_fp8(float f) {
    union { __half h; unsigned short u; } c; c.h = __float2half_rn(f);
    unsigned short h = c.u;
    unsigned int s = (h >> 8) & 0x80u;
    int e5 = (h >> 10) & 0x1f;
    if (e5 < 9) return (unsigned char)s;
    unsigned int c7 = ((unsigned int)(e5 - 8) << 3) | ((h >> 7) & 7u);
    unsigned int rem = h & 0x7fu;
    c7 += (rem > 0x40u) || ((rem == 0x40u) && (c7 & 1u));
    if (c7 > 0x7eu) c7 = 0x7eu;
    return (unsigned char)(s | c7);
}
__device__ __forceinline__ float4 fp8x4_dec(unsigned int u) {
#if __has_builtin(__builtin_amdgcn_cvt_pk_f32_fp8)
    f32x2 lo = __builtin_amdgcn_cvt_pk_f32_fp8((int)u, false);
    f32x2 hi = __builtin_amdgcn_cvt_pk_f32_fp8((int)u, true);
    return make_float4(lo.x, lo.y, hi.x, hi.y);
#else
    unsigned int e01 = (u & 0xffu) | ((u & 0xff00u) << 8);
    unsigned int e23 = ((u >> 16) & 0xffu) | ((u & 0xff000000u) >> 8);
    unsigned int h01 = ((e01 & 0x00800080u) << 8) | (((e01 & 0x007f007fu) << 7) + 0x20002000u);
    unsigned int h23 = ((e23 & 0x00800080u) << 8) | (((e23 & 0x007f007fu) << 7) + 0x20002000u);
    union { unsigned int i; __half2 h; } t0, t1;
    t0.i = h01; t1.i = h23;
    float2 f0 = __half22float2(t0.h), f1 = __half22float2(t1.h);
    return make_float4(f0.x, f0.y, f1.x, f1.y);
#endif
}

__device__ __forceinline__ void h8_store(float* dst, uint4 u) {
    union { unsigned int i; __half2 h; } t;
    t.i = u.x; { float2 f = __half22float2(t.h); dst[0] = f.x; dst[1] = f.y; }
    t.i = u.y; { float2 f = __half22float2(t.h); dst[2] = f.x; dst[3] = f.y; }
    t.i = u.z; { float2 f = __half22float2(t.h); dst[4] = f.x; dst[5] = f.y; }
    t.i = u.w; { float2 f = __half22float2(t.h); dst[6] = f.x; dst[7] = f.y; }
}

// ---------------------------------------------------------------------------
// W transpose: wt[col][k] = W[k][col], fp16.
// ---------------------------------------------------------------------------
__global__ __launch_bounds__(128) void transpose_w(
    const float* __restrict__ Wp, const float* __restrict__ We,
    __half* __restrict__ wt)
{
    int col = blockIdx.x;
    int k   = threadIdx.x;
    float v = (col < KC) ? Wp[(size_t)k * KC + col]
                         : We[(size_t)k * KC + (col - KC)];
    wt[(size_t)col * F_IN + k] = __float2half_rn(v);
}

// ---------------------------------------------------------------------------
// K1: XW = x @ [W_pool | W_embed] -> fp8 [N,256], via MFMA 16x16x32_f16.
// ---------------------------------------------------------------------------
__global__ __launch_bounds__(256) void gemm_xw_mfma(
    const float* __restrict__ x, const __half* __restrict__ wt,
    unsigned char* __restrict__ xw8, int n_nodes)
{
    __shared__ _Float16 xs[32][136];
    const int r0 = blockIdx.x * 32;
    const int tid = threadIdx.x;
    {
        int r = tid >> 3, c0 = (tid & 7) * 16;
        int gr = r0 + r;
        if (gr < n_nodes) {
            const float4* src = (const float4*)(x + (size_t)gr * F_IN + c0);
#pragma unroll
            for (int i = 0; i < 4; ++i) {
                float4 f = src[i];
                xs[r][c0 + 4 * i + 0] = (_Float16)f.x;
                xs[r][c0 + 4 * i + 1] = (_Float16)f.y;
                xs[r][c0 + 4 * i + 2] = (_Float16)f.z;
                xs[r][c0 + 4 * i + 3] = (_Float16)f.w;
            }
        } else {
#pragma unroll
            for (int i = 0; i < 16; ++i) xs[r][c0 + i] = (_Float16)0.f;
        }
    }
    __syncthreads();

    const int w = tid >> 6, lane = tid & 63;
    const int lrow = lane & 15;
    const int lk   = (lane >> 4) * 8;

    f16x8 bfrag[4][4];
#pragma unroll
    for (int cb = 0; cb < 4; ++cb) {
        int gcol = (w * 4 + cb) * 16 + lrow;
        const f16x8* bp = (const f16x8*)(wt + (size_t)gcol * F_IN + lk);
#pragma unroll
        for (int kc = 0; kc < 4; ++kc) bfrag[cb][kc] = bp[kc * 4];
    }

    f32x4 acc[2][4];
#pragma unroll
    for (int rb = 0; rb < 2; ++rb)
#pragma unroll
        for (int cb = 0; cb < 4; ++cb) acc[rb][cb] = (f32x4){0.f, 0.f, 0.f, 0.f};

#pragma unroll
    for (int kc = 0; kc < 4; ++kc) {
        f16x8 a0 = *(const f16x8*)(&xs[lrow][kc * 32 + lk]);
        f16x8 a1 = *(const f16x8*)(&xs[16 + lrow][kc * 32 + lk]);
#pragma unroll
        for (int cb = 0; cb < 4; ++cb) {
            acc[0][cb] = __builtin_amdgcn_mfma_f32_16x16x32_f16(a0, bfrag[cb][kc], acc[0][cb], 0, 0, 0);
            acc[1][cb] = __builtin_amdgcn_mfma_f32_16x16x32_f16(a1, bfrag[cb][kc], acc[1][cb], 0, 0, 0);
        }
    }

#pragma unroll
    for (int rb = 0; rb < 2; ++rb) {
#pragma unroll
        for (int cb = 0; cb < 4; ++cb) {
            int gcol = (w * 4 + cb) * 16 + lrow;
#pragma unroll
            for (int reg = 0; reg < 4; ++reg) {
                int grow = r0 + rb * 16 + (lane >> 4) * 4 + reg;
                if (grow < n_nodes)
                    xw8[(size_t)grow * F2 + gcol] = f32_to_fp8(acc[rb][cb][reg]);
            }
        }
    }
}

// ---------------------------------------------------------------------------
// Two-level counting sort (row bins of 128), no global cursors.
// ---------------------------------------------------------------------------
// Pass A: per-(block, bin) counts. Cmat[bin * NBLK_SORT + blk]
__global__ __launch_bounds__(256) void bin_count(
    const int* __restrict__ erow, int* __restrict__ Cmat,
    int n_edges, int nbin, int epb)
{
    __shared__ int bc[MAXBIN];
    const int tid = threadIdx.x, blk = blockIdx.x;
    for (int i = tid; i < nbin; i += 256) bc[i] = 0;
    __syncthreads();
    int e0 = blk * epb;
    int e1 = min(e0 + epb, n_edges);
    for (int e = e0 + tid; e < e1; e += 256)
        atomicAdd(&bc[erow[e] >> BIN_SHIFT], 1);
    __syncthreads();
    for (int i = tid; i < nbin; i += 256)
        Cmat[i * NBLK_SORT + blk] = bc[i];
}

// hierarchical exclusive scan (reused for the Cmat -> Coff scan)
__global__ __launch_bounds__(1024) void scan_local(
    int* __restrict__ cnt, int* __restrict__ row_start,
    int* __restrict__ chunk_sum, int n)
{
    __shared__ int wsum[16];
    const int tid = threadIdx.x;
    const int lane = tid & 63, wid = tid >> 6;
    int i = blockIdx.x * 1024 + tid;
    int v = (i < n) ? cnt[i] : 0;
    int incl = v;
#pragma unroll
    for (int off = 1; off < 64; off <<= 1) {
        int t = __shfl_up(incl, off);
        if (lane >= off) incl += t;
    }
    if (lane == 63) wsum[wid] = incl;
    __syncthreads();
    if (tid == 0) {
        int s = 0;
#pragma unroll
        for (int w = 0; w < 16; ++w) { int t = wsum[w]; wsum[w] = s; s += t; }
    }
    __syncthreads();
    if (i < n) row_start[i] = wsum[wid] + incl - v;
    if (tid == 1023) chunk_sum[blockIdx.x] = wsum[15] + incl;
}

__global__ __launch_bounds__(1024) void scan_chunks(
    const int* __restrict__ chunk_sum, int* __restrict__ chunk_base,
    int* __restrict__ row_start, int nchunks, int n)
{
    __shared__ int wsum[16];
    const int tid = threadIdx.x;
    const int lane = tid & 63, wid = tid >> 6;
    int v = (tid < nchunks) ? chunk_sum[tid] : 0;
    int incl = v;
#pragma unroll
    for (int off = 1; off < 64; off <<= 1) {
        int t = __shfl_up(incl, off);
        if (lane >= off) incl += t;
    }
    if (lane == 63) wsum[wid] = incl;
    __syncthreads();
    if (tid == 0) {
        int s = 0;
#pragma unroll
        for (int w = 0; w < 16; ++w) { int t = wsum[w]; wsum[w] = s; s += t; }
    }
    __syncthreads();
    int excl = wsum[wid] + incl - v;
    if (tid < nchunks) chunk_base[tid] = excl;
    if (tid == nchunks - 1) row_start[n] = excl + v;
}

__global__ __launch_bounds__(256) void scan_add(
    int* __restrict__ row_start, const int* __restrict__ chunk_base, int n)
{
    int i = blockIdx.x * 256 + threadIdx.x;
    if (i < n) row_start[i] += chunk_base[i >> 10];
}

// Pass C: place edges into bin-grouped buffers via LDS cursors.
__global__ __launch_bounds__(256) void bin_place(
    const int* __restrict__ erow, const int* __restrict__ ecol,
    const float* __restrict__ eval_, const int* __restrict__ Coff,
    unsigned int* __restrict__ ebin_cv, unsigned char* __restrict__ ebin_r8,
    int n_edges, int nbin, int epb)
{
    __shared__ int curs[MAXBIN];
    const int tid = threadIdx.x, blk = blockIdx.x;
    for (int i = tid; i < nbin; i += 256) curs[i] = Coff[i * NBLK_SORT + blk];
    __syncthreads();
    int e0 = blk * epb;
    int e1 = min(e0 + epb, n_edges);
    for (int e = e0 + tid; e < e1; e += 256) {
        int r = erow[e];
        int b = r >> BIN_SHIFT;
        int pos = atomicAdd(&curs[b], 1);
        union { __half h; unsigned short u; } hv;
        hv.h = __float2half_rn(eval_[e]);
        ebin_cv[pos] = ((unsigned int)ecol[e] << 16) | (unsigned int)hv.u;
        ebin_r8[pos] = (unsigned char)(r & ((1 << BIN_SHIFT) - 1));
    }
}

// Pass D: one block per bin. LDS row-hist -> local scan -> row_start; then
// final place into exact CSR slots (all scatter within bin's L2-hot window).
__global__ __launch_bounds__(256) void bin_final(
    const unsigned int* __restrict__ ebin_cv, const unsigned char* __restrict__ ebin_r8,
    const int* __restrict__ Coff, unsigned int* __restrict__ epack,
    int* __restrict__ row_start, int n_nodes, int nbin)
{
    constexpr int RPB = 1 << BIN_SHIFT;
    __shared__ int rcnt[RPB];
    __shared__ int rbase[RPB];
    const int bin = blockIdx.x, tid = threadIdx.x;
    const int beg = Coff[(size_t)bin * NBLK_SORT];
    const int end = Coff[(size_t)(bin + 1) * NBLK_SORT];  // bin==nbin-1 hits Coff[M]=E
    if (tid < RPB) rcnt[tid] = 0;
    __syncthreads();
    for (int j = beg + tid; j < end; j += 256)
        atomicAdd(&rcnt[ebin_r8[j]], 1);
    __syncthreads();
    if (tid == 0) {
        int s = 0;
#pragma unroll
        for (int i = 0; i < RPB; ++i) { rbase[i] = s; s += rcnt[i]; }
    }
    __syncthreads();
    int grow = bin * RPB + tid;
    if (tid < RPB && grow < n_nodes) row_start[grow] = beg + rbase[tid];
    if (bin == nbin - 1 && tid == 0) row_start[n_nodes] = end;
    if (tid < RPB) rcnt[tid] = 0;
    __syncthreads();
    for (int j = beg + tid; j < end; j += 256) {
        int r8 = ebin_r8[j];
        int rank = atomicAdd(&rcnt[r8], 1);
        epack[beg + rbase[r8] + rank] = ebin_cv[j];
    }
}

// ---------------------------------------------------------------------------
// K2: CSR SpMM over 256 fp8 cols, one wave/row, fused relu+softmax, fp16 out.
// ---------------------------------------------------------------------------
__global__ __launch_bounds__(256) void spmm_dual_csr(
    const int* __restrict__ row_start, const unsigned int* __restrict__ epack,
    const unsigned char* __restrict__ xw8, __half* __restrict__ pqh, int n_nodes)
{
    int row = blockIdx.x * 4 + (threadIdx.x >> 6);
    if (row >= n_nodes) return;
    int lane = threadIdx.x & 63;
    int beg = row_start[row], end = row_start[row + 1];

    float4 a0 = {0,0,0,0}, a1 = {0,0,0,0}, a2 = {0,0,0,0}, a3 = {0,0,0,0};
    int j = beg;
    for (; j + 3 < end; j += 4) {
        unsigned int p0 = epack[j],     p1 = epack[j + 1];
        unsigned int p2 = epack[j + 2], p3 = epack[j + 3];
        unsigned int u0 = ((const unsigned int*)(xw8 + (size_t)(p0 >> 16) * F2))[lane];
        unsigned int u1 = ((const unsigned int*)(xw8 + (size_t)(p1 >> 16) * F2))[lane];
        unsigned int u2 = ((const unsigned int*)(xw8 + (size_t)(p2 >> 16) * F2))[lane];
        unsigned int u3 = ((const unsigned int*)(xw8 + (size_t)(p3 >> 16) * F2))[lane];
        float v0 = pe_val(p0), v1 = pe_val(p1), v2 = pe_val(p2), v3 = pe_val(p3);
        float4 s0 = fp8x4_dec(u0), s1 = fp8x4_dec(u1);
        float4 s2 = fp8x4_dec(u2), s3 = fp8x4_dec(u3);
        a0.x += v0 * s0.x; a0.y += v0 * s0.y; a0.z += v0 * s0.z; a0.w += v0 * s0.w;
        a1.x += v1 * s1.x; a1.y += v1 * s1.y; a1.z += v1 * s1.z; a1.w += v1 * s1.w;
        a2.x += v2 * s2.x; a2.y += v2 * s2.y; a2.z += v2 * s2.z; a2.w += v2 * s2.w;
        a3.x += v3 * s3.x; a3.y += v3 * s3.y; a3.z += v3 * s3.z; a3.w += v3 * s3.w;
    }
    for (; j < end; ++j) {
        unsigned int p = epack[j];
        unsigned int u = ((const unsigned int*)(xw8 + (size_t)(p >> 16) * F2))[lane];
        float v = pe_val(p);
        float4 s = fp8x4_dec(u);
        a0.x += v * s.x; a0.y += v * s.y; a0.z += v * s.z; a0.w += v * s.w;
    }
    float4 a;
    a.x = a0.x + a1.x + a2.x + a3.x;
    a.y = a0.y + a1.y + a2.y + a3.y;
    a.z = a0.z + a1.z + a2.z + a3.z;
    a.w = a0.w + a1.w + a2.w + a3.w;

    a.x = fmaxf(a.x, 0.f); a.y = fmaxf(a.y, 0.f);
    a.z = fmaxf(a.z, 0.f); a.w = fmaxf(a.w, 0.f);

    float m = fmaxf(fmaxf(a.x, a.y), fmaxf(a.z, a.w));
#pragma unroll
    for (int off = 16; off; off >>= 1) m = fmaxf(m, __shfl_xor(m, off));
    float ex = __expf(a.x - m), ey = __expf(a.y - m);
    float ez = __expf(a.z - m), ew = __expf(a.w - m);
    float ssum = ex + ey + ez + ew;
#pragma unroll
    for (int off = 16; off; off >>= 1) ssum += __shfl_xor(ssum, off);
    float inv = 1.f / ssum;

    bool isP = lane < 32;
    float wx = isP ? ex * inv : a.x;
    float wy = isP ? ey * inv : a.y;
    float wz = isP ? ez * inv : a.z;
    float ww = isP ? ew * inv : a.w;
    ((uint2*)(pqh + (size_t)row * F2))[lane] =
        make_uint2(f2_to_h2u(wx, wy), f2_to_h2u(wz, ww));
}

// ---------------------------------------------------------------------------
// K4: AS = A @ S (fp16 gather of S = pqh[:,0:128], stride 256), fp16 out.
// ---------------------------------------------------------------------------
__global__ __launch_bounds__(256) void spmm_s_csr(
    const int* __restrict__ row_start, const unsigned int* __restrict__ epack,
    const __half* __restrict__ pqh, __half* __restrict__ ash, int n_nodes)
{
    int row = blockIdx.x * 4 + (threadIdx.x >> 6);
    if (row >= n_nodes) return;
    int lane = threadIdx.x & 63;
    int beg = row_start[row], end = row_start[row + 1];

    float2 a0 = {0,0}, a1 = {0,0}, a2 = {0,0}, a3 = {0,0};
    int j = beg;
    for (; j + 3 < end; j += 4) {
        unsigned int p0 = epack[j],     p1 = epack[j + 1];
        unsigned int p2 = epack[j + 2], p3 = epack[j + 3];
        __half2 h0 = ((const __half2*)(pqh + (size_t)(p0 >> 16) * F2))[lane];
        __half2 h1 = ((const __half2*)(pqh + (size_t)(p1 >> 16) * F2))[lane];
        __half2 h2 = ((const __half2*)(pqh + (size_t)(p2 >> 16) * F2))[lane];
        __half2 h3 = ((const __half2*)(pqh + (size_t)(p3 >> 16) * F2))[lane];
        float v0 = pe_val(p0), v1 = pe_val(p1), v2 = pe_val(p2), v3 = pe_val(p3);
        float2 f0 = __half22float2(h0), f1 = __half22float2(h1);
        float2 f2 = __half22float2(h2), f3 = __half22float2(h3);
        a0.x += v0 * f0.x; a0.y += v0 * f0.y;
        a1.x += v1 * f1.x; a1.y += v1 * f1.y;
        a2.x += v2 * f2.x; a2.y += v2 * f2.y;
        a3.x += v3 * f3.x; a3.y += v3 * f3.y;
    }
    for (; j < end; ++j) {
        unsigned int p = epack[j];
        __half2 h = ((const __half2*)(pqh + (size_t)(p >> 16) * F2))[lane];
        float v = pe_val(p);
        float2 f = __half22float2(h);
        a0.x += v * f.x; a0.y += v * f.y;
    }
    float rx = a0.x + a1.x + a2.x + a3.x;
    float ry = a0.y + a1.y + a2.y + a3.y;
    union { __half2 h; unsigned int i; } o;
    o.h = __floats2half2_rn(rx, ry);
    ((unsigned int*)(ash + (size_t)row * KC))[lane] = o.i;
}

// ---------------------------------------------------------------------------
// K5a: coarse partials, 8x8 register outer-product per thread.
// ---------------------------------------------------------------------------
__global__ __launch_bounds__(256) void coarse_part(
    const __half* __restrict__ pqh, const __half* __restrict__ ash,
    float* __restrict__ part, int n_nodes)
{
    const int which = blockIdx.y;
    const int tid = threadIdx.x;
    const int k0 = (tid >> 4) * 8;
    const int f0 = (tid & 15) * 8;
    __shared__ float sS[CROWS][128];
    __shared__ float sV[CROWS][128];
    float acc[8][8];
#pragma unroll
    for (int i = 0; i < 8; ++i)
#pragma unroll
        for (int jj = 0; jj < 8; ++jj) acc[i][jj] = 0.f;

    const int stride = gridDim.x * CROWS;
    for (int n0 = blockIdx.x * CROWS; n0 < n_nodes; n0 += stride) {
        __syncthreads();
        {
            int rr = tid >> 4;
            int cc = (tid & 15) * 8;
            int n = n0 + rr;
            if (n < n_nodes) {
                uint4 us = *(const uint4*)(pqh + (size_t)n * F2 + cc);
                h8_store(&sS[rr][cc], us);
                uint4 uv = which
                    ? *(const uint4*)(pqh + (size_t)n * F2 + KC + cc)
                    : *(const uint4*)(ash + (size_t)n * KC + cc);
                h8_store(&sV[rr][cc], uv);
            } else {
#pragma unroll
                for (int i = 0; i < 8; ++i) { sS[rr][cc + i] = 0.f; sV[rr][cc + i] = 0.f; }
            }
        }
        __syncthreads();
#pragma unroll 4
        for (int rr = 0; rr < CROWS; ++rr) {
            const float4* sp = (const float4*)(&sS[rr][k0]);
            float4 s0 = sp[0], s1 = sp[1];
            const float4* vp = (const float4*)(&sV[rr][f0]);
            float4 v0 = vp[0], v1 = vp[1];
            float sv[8] = {s0.x, s0.y, s0.z, s0.w, s1.x, s1.y, s1.z, s1.w};
            float vv[8] = {v0.x, v0.y, v0.z, v0.w, v1.x, v1.y, v1.z, v1.w};
#pragma unroll
            for (int i = 0; i < 8; ++i)
#pragma unroll
                for (int jj = 0; jj < 8; ++jj) acc[i][jj] += sv[i] * vv[jj];
        }
    }
    float* p = part + ((size_t)which * gridDim.x + blockIdx.x) * (KC * KC);
#pragma unroll
    for (int i = 0; i < 8; ++i) {
        float4 o0 = {acc[i][0], acc[i][1], acc[i][2], acc[i][3]};
        float4 o1 = {acc[i][4], acc[i][5], acc[i][6], acc[i][7]};
        *(float4*)(&p[(size_t)(k0 + i) * KC + f0])     = o0;
        *(float4*)(&p[(size_t)(k0 + i) * KC + f0 + 4]) = o1;
    }
}

// K5b: sum nb partial tiles per output element -> d_out (full overwrite)
__global__ __launch_bounds__(256) void coarse_reduce(
    const float* __restrict__ part, float* __restrict__ out, int nb)
{
    int e = blockIdx.x * 256 + threadIdx.x;
    int which = e >> 14;
    int idx = e & 16383;
    const float* p = part + (size_t)which * nb * (KC * KC) + idx;
    float s = 0.f;
    for (int t = 0; t < nb; ++t) s += p[(size_t)t * (KC * KC)];
    out[e] = s;
}

// ---------------------------------------------------------------------------
// Fallback f32 atomic path
// ---------------------------------------------------------------------------
__global__ __launch_bounds__(256) void gemm_xw_f(
    const float* __restrict__ x, const float* __restrict__ Wp,
    const float* __restrict__ We, float* __restrict__ xw, int n_nodes)
{
    constexpr int RPB = 32;
    __shared__ float xs[RPB][F_IN];
    const int r0 = blockIdx.x * RPB;
    const int tid = threadIdx.x;
    for (int i = tid; i < RPB * F_IN; i += 256) {
        int r = i >> 7, c = i & 127;
        int gr = r0 + r;
        xs[r][c] = (gr < n_nodes) ? x[(size_t)gr * F_IN + c] : 0.f;
    }
    __syncthreads();
    const int col = tid;
    const float* W = (col < KC) ? (Wp + col) : (We + (col - KC));
    float acc[RPB];
#pragma unroll
    for (int r = 0; r < RPB; ++r) acc[r] = 0.f;
    for (int k = 0; k < F_IN; ++k) {
        float w = W[(size_t)k * KC];
        const float* xk = &xs[0][k];
#pragma unroll
        for (int r = 0; r < RPB; ++r) acc[r] += xk[r * F_IN] * w;
    }
#pragma unroll
    for (int r = 0; r < RPB; ++r) {
        int gr = r0 + r;
        if (gr < n_nodes) xw[(size_t)gr * F2 + col] = acc[r];
    }
}

__global__ __launch_bounds__(256) void spmm_dual_kernel(
    const int* __restrict__ erow, const int* __restrict__ ecol,
    const float* __restrict__ eval_, const float* __restrict__ xw,
    float* __restrict__ pq, int n_edges)
{
    int e = blockIdx.x * 4 + (threadIdx.x >> 6);
    if (e >= n_edges) return;
    int lane = threadIdx.x & 63;
    int r = erow[e], c = ecol[e];
    float v = eval_[e];
    const float4* src = (const float4*)(xw + (size_t)c * F2);
    float* dst = pq + (size_t)r * F2;
    float4 s = src[lane];
    int f = lane * 4;
    atomicAdd(&dst[f + 0], v * s.x);
    atomicAdd(&dst[f + 1], v * s.y);
    atomicAdd(&dst[f + 2], v * s.z);
    atomicAdd(&dst[f + 3], v * s.w);
}

__global__ __launch_bounds__(64) void softmax_relu_kernel(
    float* __restrict__ pq, int n_nodes)
{
    int n = blockIdx.x;
    if (n >= n_nodes) return;
    int lane = threadIdx.x;
    float* p = pq + (size_t)n * F2;
    float a0 = fmaxf(p[lane], 0.f);
    float a1 = fmaxf(p[lane + 64], 0.f);
    float m = fmaxf(a0, a1);
#pragma unroll
    for (int off = 32; off; off >>= 1) m = fmaxf(m, __shfl_xor(m, off));
    float e0 = __expf(a0 - m), e1 = __expf(a1 - m);
    float ssum = e0 + e1;
#pragma unroll
    for (int off = 32; off; off >>= 1) ssum += __shfl_xor(ssum, off);
    float inv = 1.f / ssum;
    p[lane]      = e0 * inv;
    p[lane + 64] = e1 * inv;
    p[lane + 128] = fmaxf(p[lane + 128], 0.f);
    p[lane + 192] = fmaxf(p[lane + 192], 0.f);
}

__global__ __launch_bounds__(256) void spmm_s_kernel(
    const int* __restrict__ erow, const int* __restrict__ ecol,
    const float* __restrict__ eval_, const float* __restrict__ pq,
    float* __restrict__ as_, int n_edges)
{
    int e = blockIdx.x * 4 + (threadIdx.x >> 6);
    if (e >= n_edges) return;
    int lane = threadIdx.x & 63;
    int r = erow[e], c = ecol[e];
    float v = eval_[e];
    const float2* src = (const float2*)(pq + (size_t)c * F2);
    float* dst = as_ + (size_t)r * KC;
    float2 s = src[lane];
    int f = lane * 2;
    atomicAdd(&dst[f + 0], v * s.x);
    atomicAdd(&dst[f + 1], v * s.y);
}

__global__ __launch_bounds__(256) void coarse_f(
    const float* __restrict__ pq, const float* __restrict__ as_,
    float* __restrict__ out, int n_nodes)
{
    const int which = blockIdx.y;
    const int tid = threadIdx.x;
    const int f  = tid & 127;
    const int k0 = (tid >> 7) * 64;
    __shared__ float sS[8][128];
    float acc[64];
#pragma unroll
    for (int i = 0; i < 64; ++i) acc[i] = 0.f;
    const int stride = gridDim.x * 8;
    for (int n0 = blockIdx.x * 8; n0 < n_nodes; n0 += stride) {
        __syncthreads();
        for (int i = tid; i < 8 * 128; i += 256) {
            int rr = i >> 7, cc = i & 127;
            int n = n0 + rr;
            sS[rr][cc] = (n < n_nodes) ? pq[(size_t)n * F2 + cc] : 0.f;
        }
        __syncthreads();
        int rmax = (n_nodes - n0 < 8) ? (n_nodes - n0) : 8;
        for (int rr = 0; rr < rmax; ++rr) {
            int n = n0 + rr;
            float v = which ? pq[(size_t)n * F2 + KC + f]
                            : as_[(size_t)n * KC + f];
            const float4* s4 = (const float4*)(&sS[rr][k0]);
#pragma unroll
            for (int i = 0; i < 16; ++i) {
                float4 sv = s4[i];
                acc[4 * i + 0] += sv.x * v;
                acc[4 * i + 1] += sv.y * v;
                acc[4 * i + 2] += sv.z * v;
                acc[4 * i + 3] += sv.w * v;
            }
        }
    }
    float* o = out + (size_t)which * (KC * KC);
#pragma unroll
    for (int i = 0; i < 64; ++i)
        atomicAdd(&o[(size_t)(k0 + i) * KC + f], acc[i]);
}

// ---------------------------------------------------------------------------
extern "C" void kernel_launch(void* const* d_in, const int* in_sizes, int n_in,
                              void* d_out, int out_size, void* d_ws, size_t ws_size,
                              hipStream_t stream)
{
    const float* x     = (const float*)d_in[0];
    const int*   erow  = (const int*)d_in[1];
    const int*   ecol  = (const int*)d_in[2];
    const float* eval_ = (const float*)d_in[3];
    const float* Wp    = (const float*)d_in[4];
    const float* We    = (const float*)d_in[5];
    float* out = (float*)d_out;

    const int n_nodes = in_sizes[0] / F_IN;
    const int n_edges = in_sizes[1];
    const int nbin = (n_nodes + (1 << BIN_SHIFT) - 1) >> BIN_SHIFT;
    const int M = nbin * NBLK_SORT;                 // Cmat elements
    const int mchunks = (M + 1023) / 1024;
    const int epb = (n_edges + NBLK_SORT - 1) / NBLK_SORT;

    // bump allocator, 256B-aligned regions
    char* base = (char*)d_ws;
    size_t off = 0;
    auto alloc = [&](size_t bytes) -> void* {
        off = (off + 255) & ~(size_t)255;
        void* p = base + off;
        off += bytes;
        return p;
    };
    unsigned char* xw8  = (unsigned char*)alloc((size_t)n_nodes * F2);
    __half* pqh         = (__half*)alloc((size_t)n_nodes * F2 * 2);
    __half* ash         = (__half*)alloc((size_t)n_nodes * KC * 2);
    int* row_start      = (int*)alloc(((size_t)n_nodes + 1) * 4);
    unsigned int* epack = (unsigned int*)alloc((size_t)n_edges * 4);
    unsigned int* ebin_cv = (unsigned int*)alloc((size_t)n_edges * 4);
    unsigned char* ebin_r8 = (unsigned char*)alloc((size_t)n_edges);
    int* Cmat           = (int*)alloc((size_t)M * 4);
    int* Coff           = (int*)alloc(((size_t)M + 1) * 4);
    int* chunk_sum      = (int*)alloc(1024 * 4);
    int* chunk_base     = (int*)alloc(1024 * 4);
    __half* wt          = (__half*)alloc((size_t)F2 * F_IN * 2);
    float* part         = (float*)alloc((size_t)2 * NB_COARSE * KC * KC * 4);
    const size_t needed_h = off;

    if (n_nodes <= 65535 && nbin <= MAXBIN && mchunks <= 1024 && ws_size >= needed_h) {
        // ---- fast fp8/fp16 counting-sort + MFMA path ----
        transpose_w<<<F2, 128, 0, stream>>>(Wp, We, wt);
        gemm_xw_mfma<<<(n_nodes + 31) / 32, 256, 0, stream>>>(x, wt, xw8, n_nodes);

        bin_count<<<NBLK_SORT, 256, 0, stream>>>(erow, Cmat, n_edges, nbin, epb);
        scan_local<<<mchunks, 1024, 0, stream>>>(Cmat, Coff, chunk_sum, M);
        scan_chunks<<<1, 1024, 0, stream>>>(chunk_sum, chunk_base, Coff, mchunks, M);
        scan_add<<<(M + 255) / 256, 256, 0, stream>>>(Coff, chunk_base, M);
        bin_place<<<NBLK_SORT, 256, 0, stream>>>(erow, ecol, eval_, Coff,
                                                 ebin_cv, ebin_r8, n_edges, nbin, epb);
        bin_final<<<nbin, 256, 0, stream>>>(ebin_cv, ebin_r8, Coff, epack,
                                            row_start, n_nodes, nbin);

        spmm_dual_csr<<<(n_nodes + 3) / 4, 256, 0, stream>>>(
            row_start, epack, xw8, pqh, n_nodes);
        spmm_s_csr<<<(n_nodes + 3) / 4, 256, 0, stream>>>(
            row_start, epack, pqh, ash, n_nodes);

        coarse_part<<<dim3(NB_COARSE, 2), 256, 0, stream>>>(pqh, ash, part, n_nodes);
        coarse_reduce<<<(2 * KC * KC) / 256, 256, 0, stream>>>(part, out, NB_COARSE);
    } else {
        // ---- f32 atomic fallback ----
        float* xw  = (float*)d_ws;
        float* pq  = xw + (size_t)n_nodes * F2;
        float* as_ = xw;
        hipMemsetAsync(d_out, 0, (size_t)out_size * sizeof(float), stream);
        gemm_xw_f<<<(n_nodes + 31) / 32, 256, 0, stream>>>(x, Wp, We, xw, n_nodes);
        hipMemsetAsync(pq, 0, (size_t)n_nodes * F2 * sizeof(float), stream);
        spmm_dual_kernel<<<(n_edges + 3) / 4, 256, 0, stream>>>(
            erow, ecol, eval_, xw, pq, n_edges);
        softmax_relu_kernel<<<n_nodes, 64, 0, stream>>>(pq, n_nodes);
        hipMemsetAsync(as_, 0, (size_t)n_nodes * KC * sizeof(float), stream);
        spmm_s_kernel<<<(n_edges + 3) / 4, 256, 0, stream>>>(
            erow, ecol, eval_, pq, as_, n_edges);
        coarse_f<<<dim3(128, 2), 256, 0, stream>>>(pq, as_, out, n_nodes);
    }
}

// Round 8
// 263.815 us; speedup vs baseline: 26.3466x; 1.2268x over previous
//
#include <hip/hip_runtime.h>
#include <hip/hip_fp16.h>

constexpr int F_IN = 128;
constexpr int KC   = 128;   // K_CLUST == F_EMB == 128
constexpr int F2   = 256;   // K_CLUST + F_EMB
constexpr int NB_COARSE = 256;   // partial tiles per output
constexpr int NSPLIT = 8;        // t-axis split in coarse reduce stage 1
constexpr int CROWS = 16;        // node rows per coarse tile
constexpr int NBLK_SORT = 256;   // blocks in bin-count / bin-place passes
constexpr int BIN_SHIFT = 7;     // 128 rows per bin
constexpr int MAXBIN = 512;      // ceil(65536/128)

typedef _Float16 f16x8 __attribute__((ext_vector_type(8)));
typedef float    f32x4 __attribute__((ext_vector_type(4)));
typedef float    f32x2 __attribute__((ext_vector_type(2)));

// ---------- fp16 helpers ----------
__device__ __forceinline__ unsigned int f2_to_h2u(float x, float y) {
    union { __half2 h; unsigned int i; } c;
    c.h = __floats2half2_rn(x, y);
    return c.i;
}
__device__ __forceinline__ float pe_val(unsigned int pe) {
    return __half2float(__ushort_as_half((unsigned short)(pe & 0xffffu)));
}

// ---------- fp8 e4m3fn helpers ----------
__device__ __forceinline__ unsigned char f32_to_fp8(float f) {
    union { __half h; unsigned short u; } c; c.h = __float2half_rn(f);
    unsigned short h = c.u;
    unsigned int s = (h >> 8) & 0x80u;
    int e5 = (h >> 10) & 0x1f;
    if (e5 < 9) return (unsigned char)s;
    unsigned int c7 = ((unsigned int)(e5 - 8) << 3) | ((h >> 7) & 7u);
    unsigned int rem = h & 0x7fu;
    c7 += (rem > 0x40u) || ((rem == 0x40u) && (c7 & 1u));
    if (c7 > 0x7eu) c7 = 0x7eu;
    return (unsigned char)(s | c7);
}
__device__ __forceinline__ float4 fp8x4_dec(unsigned int u) {
#if __has_builtin(__builtin_amdgcn_cvt_pk_f32_fp8)
    f32x2 lo = __builtin_amdgcn_cvt_pk_f32_fp8((int)u, false);
    f32x2 hi = __builtin_amdgcn_cvt_pk_f32_fp8((int)u, true);
    return make_float4(lo.x, lo.y, hi.x, hi.y);
#else
    unsigned int e01 = (u & 0xffu) | ((u & 0xff00u) << 8);
    unsigned int e23 = ((u >> 16) & 0xffu) | ((u & 0xff000000u) >> 8);
    unsigned int h01 = ((e01 & 0x00800080u) << 8) | (((e01 & 0x007f007fu) << 7) + 0x20002000u);
    unsigned int h23 = ((e23 & 0x00800080u) << 8) | (((e23 & 0x007f007fu) << 7) + 0x20002000u);
    union { unsigned int i; __half2 h; } t0, t1;
    t0.i = h01; t1.i = h23;
    float2 f0 = __half22float2(t0.h), f1 = __half22float2(t1.h);
    return make_float4(f0.x, f0.y, f1.x, f1.y);
#endif
}
__device__ __forceinline__ float2 fp8x2_dec(unsigned int u) {
#if __has_builtin(__builtin_amdgcn_cvt_pk_f32_fp8)
    f32x2 lo = __builtin_amdgcn_cvt_pk_f32_fp8((int)u, false);
    return make_float2(lo.x, lo.y);
#else
    unsigned int e01 = (u & 0xffu) | ((u & 0xff00u) << 8);
    unsigned int h01 = ((e01 & 0x00800080u) << 8) | (((e01 & 0x007f007fu) << 7) + 0x20002000u);
    union { unsigned int i; __half2 h; } t0;
    t0.i = h01;
    float2 f0 = __half22float2(t0.h);
    return f0;
#endif
}

__device__ __forceinline__ void h8_store(float* dst, uint4 u) {
    union { unsigned int i; __half2 h; } t;
    t.i = u.x; { float2 f = __half22float2(t.h); dst[0] = f.x; dst[1] = f.y; }
    t.i = u.y; { float2 f = __half22float2(t.h); dst[2] = f.x; dst[3] = f.y; }
    t.i = u.z; { float2 f = __half22float2(t.h); dst[4] = f.x; dst[5] = f.y; }
    t.i = u.w; { float2 f = __half22float2(t.h); dst[6] = f.x; dst[7] = f.y; }
}

// ---------------------------------------------------------------------------
// W transpose: wt[col][k] = W[k][col], fp16.
// ---------------------------------------------------------------------------
__global__ __launch_bounds__(128) void transpose_w(
    const float* __restrict__ Wp, const float* __restrict__ We,
    __half* __restrict__ wt)
{
    int col = blockIdx.x;
    int k   = threadIdx.x;
    float v = (col < KC) ? Wp[(size_t)k * KC + col]
                         : We[(size_t)k * KC + (col - KC)];
    wt[(size_t)col * F_IN + k] = __float2half_rn(v);
}

// ---------------------------------------------------------------------------
// K1: XW = x @ [W_pool | W_embed] -> fp8 [N,256], via MFMA 16x16x32_f16.
// ---------------------------------------------------------------------------
__global__ __launch_bounds__(256) void gemm_xw_mfma(
    const float* __restrict__ x, const __half* __restrict__ wt,
    unsigned char* __restrict__ xw8, int n_nodes)
{
    __shared__ _Float16 xs[32][136];
    const int r0 = blockIdx.x * 32;
    const int tid = threadIdx.x;
    {
        int r = tid >> 3, c0 = (tid & 7) * 16;
        int gr = r0 + r;
        if (gr < n_nodes) {
            const float4* src = (const float4*)(x + (size_t)gr * F_IN + c0);
#pragma unroll
            for (int i = 0; i < 4; ++i) {
                float4 f = src[i];
                xs[r][c0 + 4 * i + 0] = (_Float16)f.x;
                xs[r][c0 + 4 * i + 1] = (_Float16)f.y;
                xs[r][c0 + 4 * i + 2] = (_Float16)f.z;
                xs[r][c0 + 4 * i + 3] = (_Float16)f.w;
            }
        } else {
#pragma unroll
            for (int i = 0; i < 16; ++i) xs[r][c0 + i] = (_Float16)0.f;
        }
    }
    __syncthreads();

    const int w = tid >> 6, lane = tid & 63;
    const int lrow = lane & 15;
    const int lk   = (lane >> 4) * 8;

    f16x8 bfrag[4][4];
#pragma unroll
    for (int cb = 0; cb < 4; ++cb) {
        int gcol = (w * 4 + cb) * 16 + lrow;
        const f16x8* bp = (const f16x8*)(wt + (size_t)gcol * F_IN + lk);
#pragma unroll
        for (int kc = 0; kc < 4; ++kc) bfrag[cb][kc] = bp[kc * 4];
    }

    f32x4 acc[2][4];
#pragma unroll
    for (int rb = 0; rb < 2; ++rb)
#pragma unroll
        for (int cb = 0; cb < 4; ++cb) acc[rb][cb] = (f32x4){0.f, 0.f, 0.f, 0.f};

#pragma unroll
    for (int kc = 0; kc < 4; ++kc) {
        f16x8 a0 = *(const f16x8*)(&xs[lrow][kc * 32 + lk]);
        f16x8 a1 = *(const f16x8*)(&xs[16 + lrow][kc * 32 + lk]);
#pragma unroll
        for (int cb = 0; cb < 4; ++cb) {
            acc[0][cb] = __builtin_amdgcn_mfma_f32_16x16x32_f16(a0, bfrag[cb][kc], acc[0][cb], 0, 0, 0);
            acc[1][cb] = __builtin_amdgcn_mfma_f32_16x16x32_f16(a1, bfrag[cb][kc], acc[1][cb], 0, 0, 0);
        }
    }

#pragma unroll
    for (int rb = 0; rb < 2; ++rb) {
#pragma unroll
        for (int cb = 0; cb < 4; ++cb) {
            int gcol = (w * 4 + cb) * 16 + lrow;
#pragma unroll
            for (int reg = 0; reg < 4; ++reg) {
                int grow = r0 + rb * 16 + (lane >> 4) * 4 + reg;
                if (grow < n_nodes)
                    xw8[(size_t)grow * F2 + gcol] = f32_to_fp8(acc[rb][cb][reg]);
            }
        }
    }
}

// ---------------------------------------------------------------------------
// Two-level counting sort (row bins of 128), no global cursors.
// ---------------------------------------------------------------------------
__global__ __launch_bounds__(256) void bin_count(
    const int* __restrict__ erow, int* __restrict__ Cmat,
    int n_edges, int nbin, int epb)
{
    __shared__ int bc[MAXBIN];
    const int tid = threadIdx.x, blk = blockIdx.x;
    for (int i = tid; i < nbin; i += 256) bc[i] = 0;
    __syncthreads();
    int e0 = blk * epb;
    int e1 = min(e0 + epb, n_edges);
    for (int e = e0 + tid; e < e1; e += 256)
        atomicAdd(&bc[erow[e] >> BIN_SHIFT], 1);
    __syncthreads();
    for (int i = tid; i < nbin; i += 256)
        Cmat[i * NBLK_SORT + blk] = bc[i];
}

__global__ __launch_bounds__(1024) void scan_local(
    int* __restrict__ cnt, int* __restrict__ row_start,
    int* __restrict__ chunk_sum, int n)
{
    __shared__ int wsum[16];
    const int tid = threadIdx.x;
    const int lane = tid & 63, wid = tid >> 6;
    int i = blockIdx.x * 1024 + tid;
    int v = (i < n) ? cnt[i] : 0;
    int incl = v;
#pragma unroll
    for (int off = 1; off < 64; off <<= 1) {
        int t = __shfl_up(incl, off);
        if (lane >= off) incl += t;
    }
    if (lane == 63) wsum[wid] = incl;
    __syncthreads();
    if (tid == 0) {
        int s = 0;
#pragma unroll
        for (int w = 0; w < 16; ++w) { int t = wsum[w]; wsum[w] = s; s += t; }
    }
    __syncthreads();
    if (i < n) row_start[i] = wsum[wid] + incl - v;
    if (tid == 1023) chunk_sum[blockIdx.x] = wsum[15] + incl;
}

__global__ __launch_bounds__(1024) void scan_chunks(
    const int* __restrict__ chunk_sum, int* __restrict__ chunk_base,
    int* __restrict__ row_start, int nchunks, int n)
{
    __shared__ int wsum[16];
    const int tid = threadIdx.x;
    const int lane = tid & 63, wid = tid >> 6;
    int v = (tid < nchunks) ? chunk_sum[tid] : 0;
    int incl = v;
#pragma unroll
    for (int off = 1; off < 64; off <<= 1) {
        int t = __shfl_up(incl, off);
        if (lane >= off) incl += t;
    }
    if (lane == 63) wsum[wid] = incl;
    __syncthreads();
    if (tid == 0) {
        int s = 0;
#pragma unroll
        for (int w = 0; w < 16; ++w) { int t = wsum[w]; wsum[w] = s; s += t; }
    }
    __syncthreads();
    int excl = wsum[wid] + incl - v;
    if (tid < nchunks) chunk_base[tid] = excl;
    if (tid == nchunks - 1) row_start[n] = excl + v;
}

__global__ __launch_bounds__(256) void scan_add(
    int* __restrict__ row_start, const int* __restrict__ chunk_base, int n)
{
    int i = blockIdx.x * 256 + threadIdx.x;
    if (i < n) row_start[i] += chunk_base[i >> 10];
}

__global__ __launch_bounds__(256) void bin_place(
    const int* __restrict__ erow, const int* __restrict__ ecol,
    const float* __restrict__ eval_, const int* __restrict__ Coff,
    unsigned int* __restrict__ ebin_cv, unsigned char* __restrict__ ebin_r8,
    int n_edges, int nbin, int epb)
{
    __shared__ int curs[MAXBIN];
    const int tid = threadIdx.x, blk = blockIdx.x;
    for (int i = tid; i < nbin; i += 256) curs[i] = Coff[i * NBLK_SORT + blk];
    __syncthreads();
    int e0 = blk * epb;
    int e1 = min(e0 + epb, n_edges);
    for (int e = e0 + tid; e < e1; e += 256) {
        int r = erow[e];
        int b = r >> BIN_SHIFT;
        int pos = atomicAdd(&curs[b], 1);
        union { __half h; unsigned short u; } hv;
        hv.h = __float2half_rn(eval_[e]);
        ebin_cv[pos] = ((unsigned int)ecol[e] << 16) | (unsigned int)hv.u;
        ebin_r8[pos] = (unsigned char)(r & ((1 << BIN_SHIFT) - 1));
    }
}

__global__ __launch_bounds__(256) void bin_final(
    const unsigned int* __restrict__ ebin_cv, const unsigned char* __restrict__ ebin_r8,
    const int* __restrict__ Coff, unsigned int* __restrict__ epack,
    int* __restrict__ row_start, int n_nodes, int nbin)
{
    constexpr int RPB = 1 << BIN_SHIFT;
    __shared__ int rcnt[RPB];
    __shared__ int rbase[RPB];
    const int bin = blockIdx.x, tid = threadIdx.x;
    const int beg = Coff[(size_t)bin * NBLK_SORT];
    const int end = Coff[(size_t)(bin + 1) * NBLK_SORT];
    if (tid < RPB) rcnt[tid] = 0;
    __syncthreads();
    for (int j = beg + tid; j < end; j += 256)
        atomicAdd(&rcnt[ebin_r8[j]], 1);
    __syncthreads();
    if (tid == 0) {
        int s = 0;
#pragma unroll
        for (int i = 0; i < RPB; ++i) { rbase[i] = s; s += rcnt[i]; }
    }
    __syncthreads();
    int grow = bin * RPB + tid;
    if (tid < RPB && grow < n_nodes) row_start[grow] = beg + rbase[tid];
    if (bin == nbin - 1 && tid == 0) row_start[n_nodes] = end;
    if (tid < RPB) rcnt[tid] = 0;
    __syncthreads();
    for (int j = beg + tid; j < end; j += 256) {
        int r8 = ebin_r8[j];
        int rank = atomicAdd(&rcnt[r8], 1);
        epack[beg + rbase[r8] + rank] = ebin_cv[j];
    }
}

// ---------------------------------------------------------------------------
// K2: CSR SpMM over 256 fp8 cols, one wave/row, fused relu+softmax.
// Outputs: pqh fp16 [N,256] (S|Z) and s8 fp8 [N,128] = fp8(256*S).
// ---------------------------------------------------------------------------
__global__ __launch_bounds__(256) void spmm_dual_csr(
    const int* __restrict__ row_start, const unsigned int* __restrict__ epack,
    const unsigned char* __restrict__ xw8, __half* __restrict__ pqh,
    unsigned char* __restrict__ s8, int n_nodes)
{
    int row = blockIdx.x * 4 + (threadIdx.x >> 6);
    if (row >= n_nodes) return;
    int lane = threadIdx.x & 63;
    int beg = row_start[row], end = row_start[row + 1];

    float4 a0 = {0,0,0,0}, a1 = {0,0,0,0}, a2 = {0,0,0,0}, a3 = {0,0,0,0};
    int j = beg;
    for (; j + 3 < end; j += 4) {
        unsigned int p0 = epack[j],     p1 = epack[j + 1];
        unsigned int p2 = epack[j + 2], p3 = epack[j + 3];
        unsigned int u0 = ((const unsigned int*)(xw8 + (size_t)(p0 >> 16) * F2))[lane];
        unsigned int u1 = ((const unsigned int*)(xw8 + (size_t)(p1 >> 16) * F2))[lane];
        unsigned int u2 = ((const unsigned int*)(xw8 + (size_t)(p2 >> 16) * F2))[lane];
        unsigned int u3 = ((const unsigned int*)(xw8 + (size_t)(p3 >> 16) * F2))[lane];
        float v0 = pe_val(p0), v1 = pe_val(p1), v2 = pe_val(p2), v3 = pe_val(p3);
        float4 s0 = fp8x4_dec(u0), s1 = fp8x4_dec(u1);
        float4 s2 = fp8x4_dec(u2), s3 = fp8x4_dec(u3);
        a0.x += v0 * s0.x; a0.y += v0 * s0.y; a0.z += v0 * s0.z; a0.w += v0 * s0.w;
        a1.x += v1 * s1.x; a1.y += v1 * s1.y; a1.z += v1 * s1.z; a1.w += v1 * s1.w;
        a2.x += v2 * s2.x; a2.y += v2 * s2.y; a2.z += v2 * s2.z; a2.w += v2 * s2.w;
        a3.x += v3 * s3.x; a3.y += v3 * s3.y; a3.z += v3 * s3.z; a3.w += v3 * s3.w;
    }
    for (; j < end; ++j) {
        unsigned int p = epack[j];
        unsigned int u = ((const unsigned int*)(xw8 + (size_t)(p >> 16) * F2))[lane];
        float v = pe_val(p);
        float4 s = fp8x4_dec(u);
        a0.x += v * s.x; a0.y += v * s.y; a0.z += v * s.z; a0.w += v * s.w;
    }
    float4 a;
    a.x = a0.x + a1.x + a2.x + a3.x;
    a.y = a0.y + a1.y + a2.y + a3.y;
    a.z = a0.z + a1.z + a2.z + a3.z;
    a.w = a0.w + a1.w + a2.w + a3.w;

    a.x = fmaxf(a.x, 0.f); a.y = fmaxf(a.y, 0.f);
    a.z = fmaxf(a.z, 0.f); a.w = fmaxf(a.w, 0.f);

    float m = fmaxf(fmaxf(a.x, a.y), fmaxf(a.z, a.w));
#pragma unroll
    for (int off = 16; off; off >>= 1) m = fmaxf(m, __shfl_xor(m, off));
    float ex = __expf(a.x - m), ey = __expf(a.y - m);
    float ez = __expf(a.z - m), ew = __expf(a.w - m);
    float ssum = ex + ey + ez + ew;
#pragma unroll
    for (int off = 16; off; off >>= 1) ssum += __shfl_xor(ssum, off);
    float inv = 1.f / ssum;

    bool isP = lane < 32;
    float wx = isP ? ex * inv : a.x;
    float wy = isP ? ey * inv : a.y;
    float wz = isP ? ez * inv : a.z;
    float ww = isP ? ew * inv : a.w;
    ((uint2*)(pqh + (size_t)row * F2))[lane] =
        make_uint2(f2_to_h2u(wx, wy), f2_to_h2u(wz, ww));
    if (isP) {
        // s8 = fp8(256*S): scale keeps mean S (~1/128) out of e4m3 flush zone
        unsigned int pk = (unsigned int)f32_to_fp8(wx * 256.f)
                        | ((unsigned int)f32_to_fp8(wy * 256.f) << 8)
                        | ((unsigned int)f32_to_fp8(wz * 256.f) << 16)
                        | ((unsigned int)f32_to_fp8(ww * 256.f) << 24);
        ((unsigned int*)(s8 + (size_t)row * KC))[lane] = pk;
    }
}

// ---------------------------------------------------------------------------
// K4: AS = A @ S via fp8 gather of s8 (=256*S); 1/256 folded into edge val.
// Lane l handles cols 2l, 2l+1. fp16 out.
// ---------------------------------------------------------------------------
__global__ __launch_bounds__(256) void spmm_s_csr(
    const int* __restrict__ row_start, const unsigned int* __restrict__ epack,
    const unsigned char* __restrict__ s8, __half* __restrict__ ash, int n_nodes)
{
    int row = blockIdx.x * 4 + (threadIdx.x >> 6);
    if (row >= n_nodes) return;
    int lane = threadIdx.x & 63;
    int beg = row_start[row], end = row_start[row + 1];

    float2 a0 = {0,0}, a1 = {0,0}, a2 = {0,0}, a3 = {0,0};
    int j = beg;
    for (; j + 3 < end; j += 4) {
        unsigned int p0 = epack[j],     p1 = epack[j + 1];
        unsigned int p2 = epack[j + 2], p3 = epack[j + 3];
        unsigned int u0 = ((const unsigned short*)(s8 + (size_t)(p0 >> 16) * KC))[lane];
        unsigned int u1 = ((const unsigned short*)(s8 + (size_t)(p1 >> 16) * KC))[lane];
        unsigned int u2 = ((const unsigned short*)(s8 + (size_t)(p2 >> 16) * KC))[lane];
        unsigned int u3 = ((const unsigned short*)(s8 + (size_t)(p3 >> 16) * KC))[lane];
        float v0 = pe_val(p0) * (1.f / 256.f), v1 = pe_val(p1) * (1.f / 256.f);
        float v2 = pe_val(p2) * (1.f / 256.f), v3 = pe_val(p3) * (1.f / 256.f);
        float2 f0 = fp8x2_dec(u0), f1 = fp8x2_dec(u1);
        float2 f2 = fp8x2_dec(u2), f3 = fp8x2_dec(u3);
        a0.x += v0 * f0.x; a0.y += v0 * f0.y;
        a1.x += v1 * f1.x; a1.y += v1 * f1.y;
        a2.x += v2 * f2.x; a2.y += v2 * f2.y;
        a3.x += v3 * f3.x; a3.y += v3 * f3.y;
    }
    for (; j < end; ++j) {
        unsigned int p = epack[j];
        unsigned int u = ((const unsigned short*)(s8 + (size_t)(p >> 16) * KC))[lane];
        float v = pe_val(p) * (1.f / 256.f);
        float2 f = fp8x2_dec(u);
        a0.x += v * f.x; a0.y += v * f.y;
    }
    float rx = a0.x + a1.x + a2.x + a3.x;
    float ry = a0.y + a1.y + a2.y + a3.y;
    union { __half2 h; unsigned int i; } o;
    o.h = __floats2half2_rn(rx, ry);
    ((unsigned int*)(ash + (size_t)row * KC))[lane] = o.i;
}

// ---------------------------------------------------------------------------
// K5a: coarse partials, 8x8 register outer-product per thread.
// ---------------------------------------------------------------------------
__global__ __launch_bounds__(256) void coarse_part(
    const __half* __restrict__ pqh, const __half* __restrict__ ash,
    float* __restrict__ part, int n_nodes)
{
    const int which = blockIdx.y;
    const int tid = threadIdx.x;
    const int k0 = (tid >> 4) * 8;
    const int f0 = (tid & 15) * 8;
    __shared__ float sS[CROWS][128];
    __shared__ float sV[CROWS][128];
    float acc[8][8];
#pragma unroll
    for (int i = 0; i < 8; ++i)
#pragma unroll
        for (int jj = 0; jj < 8; ++jj) acc[i][jj] = 0.f;

    const int stride = gridDim.x * CROWS;
    for (int n0 = blockIdx.x * CROWS; n0 < n_nodes; n0 += stride) {
        __syncthreads();
        {
            int rr = tid >> 4;
            int cc = (tid & 15) * 8;
            int n = n0 + rr;
            if (n < n_nodes) {
                uint4 us = *(const uint4*)(pqh + (size_t)n * F2 + cc);
                h8_store(&sS[rr][cc], us);
                uint4 uv = which
                    ? *(const uint4*)(pqh + (size_t)n * F2 + KC + cc)
                    : *(const uint4*)(ash + (size_t)n * KC + cc);
                h8_store(&sV[rr][cc], uv);
            } else {
#pragma unroll
                for (int i = 0; i < 8; ++i) { sS[rr][cc + i] = 0.f; sV[rr][cc + i] = 0.f; }
            }
        }
        __syncthreads();
#pragma unroll 4
        for (int rr = 0; rr < CROWS; ++rr) {
            const float4* sp = (const float4*)(&sS[rr][k0]);
            float4 s0 = sp[0], s1 = sp[1];
            const float4* vp = (const float4*)(&sV[rr][f0]);
            float4 v0 = vp[0], v1 = vp[1];
            float sv[8] = {s0.x, s0.y, s0.z, s0.w, s1.x, s1.y, s1.z, s1.w};
            float vv[8] = {v0.x, v0.y, v0.z, v0.w, v1.x, v1.y, v1.z, v1.w};
#pragma unroll
            for (int i = 0; i < 8; ++i)
#pragma unroll
                for (int jj = 0; jj < 8; ++jj) acc[i][jj] += sv[i] * vv[jj];
        }
    }
    float* p = part + ((size_t)which * gridDim.x + blockIdx.x) * (KC * KC);
#pragma unroll
    for (int i = 0; i < 8; ++i) {
        float4 o0 = {acc[i][0], acc[i][1], acc[i][2], acc[i][3]};
        float4 o1 = {acc[i][4], acc[i][5], acc[i][6], acc[i][7]};
        *(float4*)(&p[(size_t)(k0 + i) * KC + f0])     = o0;
        *(float4*)(&p[(size_t)(k0 + i) * KC + f0 + 4]) = o1;
    }
}

// K5b stage 1: part2[s][e] = sum of this split's tiles (grid: 128 x NSPLIT)
__global__ __launch_bounds__(256) void coarse_reduce1(
    const float* __restrict__ part, float* __restrict__ part2, int nb)
{
    int e = blockIdx.x * 256 + threadIdx.x;      // 0 .. 2*16384-1
    int s = blockIdx.y;
    int which = e >> 14;
    int idx = e & 16383;
    int tpb = nb / NSPLIT;
    const float* p = part + ((size_t)which * nb + (size_t)s * tpb) * (KC * KC) + idx;
    float sum = 0.f;
    for (int t = 0; t < tpb; ++t) sum += p[(size_t)t * (KC * KC)];
    part2[(size_t)s * (2 * KC * KC) + e] = sum;
}

// K5b stage 2: out[e] = sum over NSPLIT partials (full overwrite of d_out)
__global__ __launch_bounds__(256) void coarse_reduce2(
    const float* __restrict__ part2, float* __restrict__ out)
{
    int e = blockIdx.x * 256 + threadIdx.x;
    float s = 0.f;
#pragma unroll
    for (int i = 0; i < NSPLIT; ++i) s += part2[(size_t)i * (2 * KC * KC) + e];
    out[e] = s;
}

// ---------------------------------------------------------------------------
// Fallback f32 atomic path
// ---------------------------------------------------------------------------
__global__ __launch_bounds__(256) void gemm_xw_f(
    const float* __restrict__ x, const float* __restrict__ Wp,
    const float* __restrict__ We, float* __restrict__ xw, int n_nodes)
{
    constexpr int RPB = 32;
    __shared__ float xs[RPB][F_IN];
    const int r0 = blockIdx.x * RPB;
    const int tid = threadIdx.x;
    for (int i = tid; i < RPB * F_IN; i += 256) {
        int r = i >> 7, c = i & 127;
        int gr = r0 + r;
        xs[r][c] = (gr < n_nodes) ? x[(size_t)gr * F_IN + c] : 0.f;
    }
    __syncthreads();
    const int col = tid;
    const float* W = (col < KC) ? (Wp + col) : (We + (col - KC));
    float acc[RPB];
#pragma unroll
    for (int r = 0; r < RPB; ++r) acc[r] = 0.f;
    for (int k = 0; k < F_IN; ++k) {
        float w = W[(size_t)k * KC];
        const float* xk = &xs[0][k];
#pragma unroll
        for (int r = 0; r < RPB; ++r) acc[r] += xk[r * F_IN] * w;
    }
#pragma unroll
    for (int r = 0; r < RPB; ++r) {
        int gr = r0 + r;
        if (gr < n_nodes) xw[(size_t)gr * F2 + col] = acc[r];
    }
}

__global__ __launch_bounds__(256) void spmm_dual_kernel(
    const int* __restrict__ erow, const int* __restrict__ ecol,
    const float* __restrict__ eval_, const float* __restrict__ xw,
    float* __restrict__ pq, int n_edges)
{
    int e = blockIdx.x * 4 + (threadIdx.x >> 6);
    if (e >= n_edges) return;
    int lane = threadIdx.x & 63;
    int r = erow[e], c = ecol[e];
    float v = eval_[e];
    const float4* src = (const float4*)(xw + (size_t)c * F2);
    float* dst = pq + (size_t)r * F2;
    float4 s = src[lane];
    int f = lane * 4;
    atomicAdd(&dst[f + 0], v * s.x);
    atomicAdd(&dst[f + 1], v * s.y);
    atomicAdd(&dst[f + 2], v * s.z);
    atomicAdd(&dst[f + 3], v * s.w);
}

__global__ __launch_bounds__(64) void softmax_relu_kernel(
    float* __restrict__ pq, int n_nodes)
{
    int n = blockIdx.x;
    if (n >= n_nodes) return;
    int lane = threadIdx.x;
    float* p = pq + (size_t)n * F2;
    float a0 = fmaxf(p[lane], 0.f);
    float a1 = fmaxf(p[lane + 64], 0.f);
    float m = fmaxf(a0, a1);
#pragma unroll
    for (int off = 32; off; off >>= 1) m = fmaxf(m, __shfl_xor(m, off));
    float e0 = __expf(a0 - m), e1 = __expf(a1 - m);
    float ssum = e0 + e1;
#pragma unroll
    for (int off = 32; off; off >>= 1) ssum += __shfl_xor(ssum, off);
    float inv = 1.f / ssum;
    p[lane]      = e0 * inv;
    p[lane + 64] = e1 * inv;
    p[lane + 128] = fmaxf(p[lane + 128], 0.f);
    p[lane + 192] = fmaxf(p[lane + 192], 0.f);
}

__global__ __launch_bounds__(256) void spmm_s_kernel(
    const int* __restrict__ erow, const int* __restrict__ ecol,
    const float* __restrict__ eval_, const float* __restrict__ pq,
    float* __restrict__ as_, int n_edges)
{
    int e = blockIdx.x * 4 + (threadIdx.x >> 6);
    if (e >= n_edges) return;
    int lane = threadIdx.x & 63;
    int r = erow[e], c = ecol[e];
    float v = eval_[e];
    const float2* src = (const float2*)(pq + (size_t)c * F2);
    float* dst = as_ + (size_t)r * KC;
    float2 s = src[lane];
    int f = lane * 2;
    atomicAdd(&dst[f + 0], v * s.x);
    atomicAdd(&dst[f + 1], v * s.y);
}

__global__ __launch_bounds__(256) void coarse_f(
    const float* __restrict__ pq, const float* __restrict__ as_,
    float* __restrict__ out, int n_nodes)
{
    const int which = blockIdx.y;
    const int tid = threadIdx.x;
    const int f  = tid & 127;
    const int k0 = (tid >> 7) * 64;
    __shared__ float sS[8][128];
    float acc[64];
#pragma unroll
    for (int i = 0; i < 64; ++i) acc[i] = 0.f;
    const int stride = gridDim.x * 8;
    for (int n0 = blockIdx.x * 8; n0 < n_nodes; n0 += stride) {
        __syncthreads();
        for (int i = tid; i < 8 * 128; i += 256) {
            int rr = i >> 7, cc = i & 127;
            int n = n0 + rr;
            sS[rr][cc] = (n < n_nodes) ? pq[(size_t)n * F2 + cc] : 0.f;
        }
        __syncthreads();
        int rmax = (n_nodes - n0 < 8) ? (n_nodes - n0) : 8;
        for (int rr = 0; rr < rmax; ++rr) {
            int n = n0 + rr;
            float v = which ? pq[(size_t)n * F2 + KC + f]
                            : as_[(size_t)n * KC + f];
            const float4* s4 = (const float4*)(&sS[rr][k0]);
#pragma unroll
            for (int i = 0; i < 16; ++i) {
                float4 sv = s4[i];
                acc[4 * i + 0] += sv.x * v;
                acc[4 * i + 1] += sv.y * v;
                acc[4 * i + 2] += sv.z * v;
                acc[4 * i + 3] += sv.w * v;
            }
        }
    }
    float* o = out + (size_t)which * (KC * KC);
#pragma unroll
    for (int i = 0; i < 64; ++i)
        atomicAdd(&o[(size_t)(k0 + i) * KC + f], acc[i]);
}

// ---------------------------------------------------------------------------
extern "C" void kernel_launch(void* const* d_in, const int* in_sizes, int n_in,
                              void* d_out, int out_size, void* d_ws, size_t ws_size,
                              hipStream_t stream)
{
    const float* x     = (const float*)d_in[0];
    const int*   erow  = (const int*)d_in[1];
    const int*   ecol  = (const int*)d_in[2];
    const float* eval_ = (const float*)d_in[3];
    const float* Wp    = (const float*)d_in[4];
    const float* We    = (const float*)d_in[5];
    float* out = (float*)d_out;

    const int n_nodes = in_sizes[0] / F_IN;
    const int n_edges = in_sizes[1];
    const int nbin = (n_nodes + (1 << BIN_SHIFT) - 1) >> BIN_SHIFT;
    const int M = nbin * NBLK_SORT;
    const int mchunks = (M + 1023) / 1024;
    const int epb = (n_edges + NBLK_SORT - 1) / NBLK_SORT;

    char* base = (char*)d_ws;
    size_t off = 0;
    auto alloc = [&](size_t bytes) -> void* {
        off = (off + 255) & ~(size_t)255;
        void* p = base + off;
        off += bytes;
        return p;
    };
    unsigned char* xw8  = (unsigned char*)alloc((size_t)n_nodes * F2);
    __half* pqh         = (__half*)alloc((size_t)n_nodes * F2 * 2);
    __half* ash         = (__half*)alloc((size_t)n_nodes * KC * 2);
    unsigned char* s8   = (unsigned char*)alloc((size_t)n_nodes * KC);
    int* row_start      = (int*)alloc(((size_t)n_nodes + 1) * 4);
    unsigned int* epack = (unsigned int*)alloc((size_t)n_edges * 4);
    unsigned int* ebin_cv = (unsigned int*)alloc((size_t)n_edges * 4);
    unsigned char* ebin_r8 = (unsigned char*)alloc((size_t)n_edges);
    int* Cmat           = (int*)alloc((size_t)M * 4);
    int* Coff           = (int*)alloc(((size_t)M + 1) * 4);
    int* chunk_sum      = (int*)alloc(1024 * 4);
    int* chunk_base     = (int*)alloc(1024 * 4);
    __half* wt          = (__half*)alloc((size_t)F2 * F_IN * 2);
    float* part         = (float*)alloc((size_t)2 * NB_COARSE * KC * KC * 4);
    float* part2        = (float*)alloc((size_t)NSPLIT * 2 * KC * KC * 4);
    const size_t needed_h = off;

    if (n_nodes <= 65535 && nbin <= MAXBIN && mchunks <= 1024 && ws_size >= needed_h) {
        // ---- fast fp8/fp16 counting-sort + MFMA path ----
        transpose_w<<<F2, 128, 0, stream>>>(Wp, We, wt);
        gemm_xw_mfma<<<(n_nodes + 31) / 32, 256, 0, stream>>>(x, wt, xw8, n_nodes);

        bin_count<<<NBLK_SORT, 256, 0, stream>>>(erow, Cmat, n_edges, nbin, epb);
        scan_local<<<mchunks, 1024, 0, stream>>>(Cmat, Coff, chunk_sum, M);
        scan_chunks<<<1, 1024, 0, stream>>>(chunk_sum, chunk_base, Coff, mchunks, M);
        scan_add<<<(M + 255) / 256, 256, 0, stream>>>(Coff, chunk_base, M);
        bin_place<<<NBLK_SORT, 256, 0, stream>>>(erow, ecol, eval_, Coff,
                                                 ebin_cv, ebin_r8, n_edges, nbin, epb);
        bin_final<<<nbin, 256, 0, stream>>>(ebin_cv, ebin_r8, Coff, epack,
                                            row_start, n_nodes, nbin);

        spmm_dual_csr<<<(n_nodes + 3) / 4, 256, 0, stream>>>(
            row_start, epack, xw8, pqh, s8, n_nodes);
        spmm_s_csr<<<(n_nodes + 3) / 4, 256, 0, stream>>>(
            row_start, epack, s8, ash, n_nodes);

        coarse_part<<<dim3(NB_COARSE, 2), 256, 0, stream>>>(pqh, ash, part, n_nodes);
        coarse_reduce1<<<dim3((2 * KC * KC) / 256, NSPLIT), 256, 0, stream>>>(
            part, part2, NB_COARSE);
        coarse_reduce2<<<(2 * KC * KC) / 256, 256, 0, stream>>>(part2, out);
    } else {
        // ---- f32 atomic fallback ----
        float* xw  = (float*)d_ws;
        float* pq  = xw + (size_t)n_nodes * F2;
        float* as_ = xw;
        hipMemsetAsync(d_out, 0, (size_t)out_size * sizeof(float), stream);
        gemm_xw_f<<<(n_nodes + 31) / 32, 256, 0, stream>>>(x, Wp, We, xw, n_nodes);
        hipMemsetAsync(pq, 0, (size_t)n_nodes * F2 * sizeof(float), stream);
        spmm_dual_kernel<<<(n_edges + 3) / 4, 256, 0, stream>>>(
            erow, ecol, eval_, xw, pq, n_edges);
        softmax_relu_kernel<<<n_nodes, 64, 0, stream>>>(pq, n_nodes);
        hipMemsetAsync(as_, 0, (size_t)n_nodes * KC * sizeof(float), stream);
        spmm_s_kernel<<<(n_edges + 3) / 4, 256, 0, stream>>>(
            erow, ecol, eval_, pq, as_, n_edges);
        coarse_f<<<dim3(128, 2), 256, 0, stream>>>(pq, as_, out, n_nodes);
    }
}

// Round 9
// 233.744 us; speedup vs baseline: 29.7361x; 1.1286x over previous
//
#include <hip/hip_runtime.h>
#include <hip/hip_fp16.h>

constexpr int F_IN = 128;
constexpr int KC   = 128;   // K_CLUST == F_EMB == 128
constexpr int F2   = 256;   // K_CLUST + F_EMB
constexpr int NB_COARSE = 256;   // partial tiles per output
constexpr int NSPLIT = 8;        // t-axis split in coarse reduce stage 1
constexpr int NBLK_SORT = 256;   // blocks in bin-count / bin-place passes
constexpr int BIN_SHIFT = 7;     // 128 rows per bin
constexpr int MAXBIN = 512;      // ceil(65536/128)
constexpr int LR = 40;           // LDS row stride (fp16 units); 80B = 5*16B

typedef _Float16 f16x8 __attribute__((ext_vector_type(8)));
typedef float    f32x4 __attribute__((ext_vector_type(4)));
typedef float    f32x2 __attribute__((ext_vector_type(2)));

// ---------- fp16 helpers ----------
__device__ __forceinline__ unsigned int f2_to_h2u(float x, float y) {
    union { __half2 h; unsigned int i; } c;
    c.h = __floats2half2_rn(x, y);
    return c.i;
}
__device__ __forceinline__ float pe_val(unsigned int pe) {
    return __half2float(__ushort_as_half((unsigned short)(pe & 0xffffu)));
}

// ---------- fp8 e4m3fn helpers ----------
__device__ __forceinline__ unsigned char f32_to_fp8(float f) {
    union { __half h; unsigned short u; } c; c.h = __float2half_rn(f);
    unsigned short h = c.u;
    unsigned int s = (h >> 8) & 0x80u;
    int e5 = (h >> 10) & 0x1f;
    if (e5 < 9) return (unsigned char)s;
    unsigned int c7 = ((unsigned int)(e5 - 8) << 3) | ((h >> 7) & 7u);
    unsigned int rem = h & 0x7fu;
    c7 += (rem > 0x40u) || ((rem == 0x40u) && (c7 & 1u));
    if (c7 > 0x7eu) c7 = 0x7eu;
    return (unsigned char)(s | c7);
}
__device__ __forceinline__ float4 fp8x4_dec(unsigned int u) {
#if __has_builtin(__builtin_amdgcn_cvt_pk_f32_fp8)
    f32x2 lo = __builtin_amdgcn_cvt_pk_f32_fp8((int)u, false);
    f32x2 hi = __builtin_amdgcn_cvt_pk_f32_fp8((int)u, true);
    return make_float4(lo.x, lo.y, hi.x, hi.y);
#else
    unsigned int e01 = (u & 0xffu) | ((u & 0xff00u) << 8);
    unsigned int e23 = ((u >> 16) & 0xffu) | ((u & 0xff000000u) >> 8);
    unsigned int h01 = ((e01 & 0x00800080u) << 8) | (((e01 & 0x007f007fu) << 7) + 0x20002000u);
    unsigned int h23 = ((e23 & 0x00800080u) << 8) | (((e23 & 0x007f007fu) << 7) + 0x20002000u);
    union { unsigned int i; __half2 h; } t0, t1;
    t0.i = h01; t1.i = h23;
    float2 f0 = __half22float2(t0.h), f1 = __half22float2(t1.h);
    return make_float4(f0.x, f0.y, f1.x, f1.y);
#endif
}
__device__ __forceinline__ float2 fp8x2_dec(unsigned int u) {
#if __has_builtin(__builtin_amdgcn_cvt_pk_f32_fp8)
    f32x2 lo = __builtin_amdgcn_cvt_pk_f32_fp8((int)u, false);
    return make_float2(lo.x, lo.y);
#else
    unsigned int e01 = (u & 0xffu) | ((u & 0xff00u) << 8);
    unsigned int h01 = ((e01 & 0x00800080u) << 8) | (((e01 & 0x007f007fu) << 7) + 0x20002000u);
    union { unsigned int i; __half2 h; } t0;
    t0.i = h01;
    float2 f0 = __half22float2(t0.h);
    return f0;
#endif
}

// scatter-transpose 16 fp16 (from two uint4) into column nl of LDS tile
__device__ __forceinline__ void store_t16(unsigned short* dst, int c0, int nl,
                                          uint4 u0, uint4 u1) {
    unsigned int w[8] = {u0.x, u0.y, u0.z, u0.w, u1.x, u1.y, u1.z, u1.w};
#pragma unroll
    for (int i = 0; i < 8; ++i) {
        dst[(c0 + 2 * i) * LR + nl]     = (unsigned short)(w[i] & 0xffffu);
        dst[(c0 + 2 * i + 1) * LR + nl] = (unsigned short)(w[i] >> 16);
    }
}

// ---------------------------------------------------------------------------
// W transpose: wt[col][k] = W[k][col], fp16.
// ---------------------------------------------------------------------------
__global__ __launch_bounds__(128) void transpose_w(
    const float* __restrict__ Wp, const float* __restrict__ We,
    __half* __restrict__ wt)
{
    int col = blockIdx.x;
    int k   = threadIdx.x;
    float v = (col < KC) ? Wp[(size_t)k * KC + col]
                         : We[(size_t)k * KC + (col - KC)];
    wt[(size_t)col * F_IN + k] = __float2half_rn(v);
}

// ---------------------------------------------------------------------------
// K1: XW = x @ [W_pool | W_embed] -> fp8 [N,256], via MFMA 16x16x32_f16.
// ---------------------------------------------------------------------------
__global__ __launch_bounds__(256) void gemm_xw_mfma(
    const float* __restrict__ x, const __half* __restrict__ wt,
    unsigned char* __restrict__ xw8, int n_nodes)
{
    __shared__ _Float16 xs[32][136];
    const int r0 = blockIdx.x * 32;
    const int tid = threadIdx.x;
    {
        int r = tid >> 3, c0 = (tid & 7) * 16;
        int gr = r0 + r;
        if (gr < n_nodes) {
            const float4* src = (const float4*)(x + (size_t)gr * F_IN + c0);
#pragma unroll
            for (int i = 0; i < 4; ++i) {
                float4 f = src[i];
                xs[r][c0 + 4 * i + 0] = (_Float16)f.x;
                xs[r][c0 + 4 * i + 1] = (_Float16)f.y;
                xs[r][c0 + 4 * i + 2] = (_Float16)f.z;
                xs[r][c0 + 4 * i + 3] = (_Float16)f.w;
            }
        } else {
#pragma unroll
            for (int i = 0; i < 16; ++i) xs[r][c0 + i] = (_Float16)0.f;
        }
    }
    __syncthreads();

    const int w = tid >> 6, lane = tid & 63;
    const int lrow = lane & 15;
    const int lk   = (lane >> 4) * 8;

    f16x8 bfrag[4][4];
#pragma unroll
    for (int cb = 0; cb < 4; ++cb) {
        int gcol = (w * 4 + cb) * 16 + lrow;
        const f16x8* bp = (const f16x8*)(wt + (size_t)gcol * F_IN + lk);
#pragma unroll
        for (int kc = 0; kc < 4; ++kc) bfrag[cb][kc] = bp[kc * 4];
    }

    f32x4 acc[2][4];
#pragma unroll
    for (int rb = 0; rb < 2; ++rb)
#pragma unroll
        for (int cb = 0; cb < 4; ++cb) acc[rb][cb] = (f32x4){0.f, 0.f, 0.f, 0.f};

#pragma unroll
    for (int kc = 0; kc < 4; ++kc) {
        f16x8 a0 = *(const f16x8*)(&xs[lrow][kc * 32 + lk]);
        f16x8 a1 = *(const f16x8*)(&xs[16 + lrow][kc * 32 + lk]);
#pragma unroll
        for (int cb = 0; cb < 4; ++cb) {
            acc[0][cb] = __builtin_amdgcn_mfma_f32_16x16x32_f16(a0, bfrag[cb][kc], acc[0][cb], 0, 0, 0);
            acc[1][cb] = __builtin_amdgcn_mfma_f32_16x16x32_f16(a1, bfrag[cb][kc], acc[1][cb], 0, 0, 0);
        }
    }

#pragma unroll
    for (int rb = 0; rb < 2; ++rb) {
#pragma unroll
        for (int cb = 0; cb < 4; ++cb) {
            int gcol = (w * 4 + cb) * 16 + lrow;
#pragma unroll
            for (int reg = 0; reg < 4; ++reg) {
                int grow = r0 + rb * 16 + (lane >> 4) * 4 + reg;
                if (grow < n_nodes)
                    xw8[(size_t)grow * F2 + gcol] = f32_to_fp8(acc[rb][cb][reg]);
            }
        }
    }
}

// ---------------------------------------------------------------------------
// Two-level counting sort (row bins of 128), no global cursors.
// ---------------------------------------------------------------------------
__global__ __launch_bounds__(256) void bin_count(
    const int* __restrict__ erow, int* __restrict__ Cmat,
    int n_edges, int nbin, int epb)
{
    __shared__ int bc[MAXBIN];
    const int tid = threadIdx.x, blk = blockIdx.x;
    for (int i = tid; i < nbin; i += 256) bc[i] = 0;
    __syncthreads();
    int e0 = blk * epb;
    int e1 = min(e0 + epb, n_edges);
    for (int e = e0 + tid; e < e1; e += 256)
        atomicAdd(&bc[erow[e] >> BIN_SHIFT], 1);
    __syncthreads();
    for (int i = tid; i < nbin; i += 256)
        Cmat[i * NBLK_SORT + blk] = bc[i];
}

__global__ __launch_bounds__(1024) void scan_local(
    int* __restrict__ cnt, int* __restrict__ row_start,
    int* __restrict__ chunk_sum, int n)
{
    __shared__ int wsum[16];
    const int tid = threadIdx.x;
    const int lane = tid & 63, wid = tid >> 6;
    int i = blockIdx.x * 1024 + tid;
    int v = (i < n) ? cnt[i] : 0;
    int incl = v;
#pragma unroll
    for (int off = 1; off < 64; off <<= 1) {
        int t = __shfl_up(incl, off);
        if (lane >= off) incl += t;
    }
    if (lane == 63) wsum[wid] = incl;
    __syncthreads();
    if (tid == 0) {
        int s = 0;
#pragma unroll
        for (int w = 0; w < 16; ++w) { int t = wsum[w]; wsum[w] = s; s += t; }
    }
    __syncthreads();
    if (i < n) row_start[i] = wsum[wid] + incl - v;
    if (tid == 1023) chunk_sum[blockIdx.x] = wsum[15] + incl;
}

__global__ __launch_bounds__(1024) void scan_chunks(
    const int* __restrict__ chunk_sum, int* __restrict__ chunk_base,
    int* __restrict__ row_start, int nchunks, int n)
{
    __shared__ int wsum[16];
    const int tid = threadIdx.x;
    const int lane = tid & 63, wid = tid >> 6;
    int v = (tid < nchunks) ? chunk_sum[tid] : 0;
    int incl = v;
#pragma unroll
    for (int off = 1; off < 64; off <<= 1) {
        int t = __shfl_up(incl, off);
        if (lane >= off) incl += t;
    }
    if (lane == 63) wsum[wid] = incl;
    __syncthreads();
    if (tid == 0) {
        int s = 0;
#pragma unroll
        for (int w = 0; w < 16; ++w) { int t = wsum[w]; wsum[w] = s; s += t; }
    }
    __syncthreads();
    int excl = wsum[wid] + incl - v;
    if (tid < nchunks) chunk_base[tid] = excl;
    if (tid == nchunks - 1) row_start[n] = excl + v;
}

__global__ __launch_bounds__(256) void scan_add(
    int* __restrict__ row_start, const int* __restrict__ chunk_base, int n)
{
    int i = blockIdx.x * 256 + threadIdx.x;
    if (i < n) row_start[i] += chunk_base[i >> 10];
}

__global__ __launch_bounds__(256) void bin_place(
    const int* __restrict__ erow, const int* __restrict__ ecol,
    const float* __restrict__ eval_, const int* __restrict__ Coff,
    unsigned int* __restrict__ ebin_cv, unsigned char* __restrict__ ebin_r8,
    int n_edges, int nbin, int epb)
{
    __shared__ int curs[MAXBIN];
    const int tid = threadIdx.x, blk = blockIdx.x;
    for (int i = tid; i < nbin; i += 256) curs[i] = Coff[i * NBLK_SORT + blk];
    __syncthreads();
    int e0 = blk * epb;
    int e1 = min(e0 + epb, n_edges);
    for (int e = e0 + tid; e < e1; e += 256) {
        int r = erow[e];
        int b = r >> BIN_SHIFT;
        int pos = atomicAdd(&curs[b], 1);
        union { __half h; unsigned short u; } hv;
        hv.h = __float2half_rn(eval_[e]);
        ebin_cv[pos] = ((unsigned int)ecol[e] << 16) | (unsigned int)hv.u;
        ebin_r8[pos] = (unsigned char)(r & ((1 << BIN_SHIFT) - 1));
    }
}

__global__ __launch_bounds__(256) void bin_final(
    const unsigned int* __restrict__ ebin_cv, const unsigned char* __restrict__ ebin_r8,
    const int* __restrict__ Coff, unsigned int* __restrict__ epack,
    int* __restrict__ row_start, int n_nodes, int nbin)
{
    constexpr int RPB = 1 << BIN_SHIFT;
    __shared__ int rcnt[RPB];
    __shared__ int rbase[RPB];
    const int bin = blockIdx.x, tid = threadIdx.x;
    const int beg = Coff[(size_t)bin * NBLK_SORT];
    const int end = Coff[(size_t)(bin + 1) * NBLK_SORT];
    if (tid < RPB) rcnt[tid] = 0;
    __syncthreads();
    for (int j = beg + tid; j < end; j += 256)
        atomicAdd(&rcnt[ebin_r8[j]], 1);
    __syncthreads();
    if (tid == 0) {
        int s = 0;
#pragma unroll
        for (int i = 0; i < RPB; ++i) { rbase[i] = s; s += rcnt[i]; }
    }
    __syncthreads();
    int grow = bin * RPB + tid;
    if (tid < RPB && grow < n_nodes) row_start[grow] = beg + rbase[tid];
    if (bin == nbin - 1 && tid == 0) row_start[n_nodes] = end;
    if (tid < RPB) rcnt[tid] = 0;
    __syncthreads();
    for (int j = beg + tid; j < end; j += 256) {
        int r8 = ebin_r8[j];
        int rank = atomicAdd(&rcnt[r8], 1);
        epack[beg + rbase[r8] + rank] = ebin_cv[j];
    }
}

// ---------------------------------------------------------------------------
// K2: CSR SpMM over 256 fp8 cols, one wave/row, fused relu+softmax.
// Outputs: pqh fp16 [N,256] (S|Z) and s8 fp8 [N,128] = fp8(256*S).
// ---------------------------------------------------------------------------
__global__ __launch_bounds__(256) void spmm_dual_csr(
    const int* __restrict__ row_start, const unsigned int* __restrict__ epack,
    const unsigned char* __restrict__ xw8, __half* __restrict__ pqh,
    unsigned char* __restrict__ s8, int n_nodes)
{
    int row = blockIdx.x * 4 + (threadIdx.x >> 6);
    if (row >= n_nodes) return;
    int lane = threadIdx.x & 63;
    int beg = row_start[row], end = row_start[row + 1];

    float4 a0 = {0,0,0,0}, a1 = {0,0,0,0}, a2 = {0,0,0,0}, a3 = {0,0,0,0};
    int j = beg;
    for (; j + 3 < end; j += 4) {
        unsigned int p0 = epack[j],     p1 = epack[j + 1];
        unsigned int p2 = epack[j + 2], p3 = epack[j + 3];
        unsigned int u0 = ((const unsigned int*)(xw8 + (size_t)(p0 >> 16) * F2))[lane];
        unsigned int u1 = ((const unsigned int*)(xw8 + (size_t)(p1 >> 16) * F2))[lane];
        unsigned int u2 = ((const unsigned int*)(xw8 + (size_t)(p2 >> 16) * F2))[lane];
        unsigned int u3 = ((const unsigned int*)(xw8 + (size_t)(p3 >> 16) * F2))[lane];
        float v0 = pe_val(p0), v1 = pe_val(p1), v2 = pe_val(p2), v3 = pe_val(p3);
        float4 s0 = fp8x4_dec(u0), s1 = fp8x4_dec(u1);
        float4 s2 = fp8x4_dec(u2), s3 = fp8x4_dec(u3);
        a0.x += v0 * s0.x; a0.y += v0 * s0.y; a0.z += v0 * s0.z; a0.w += v0 * s0.w;
        a1.x += v1 * s1.x; a1.y += v1 * s1.y; a1.z += v1 * s1.z; a1.w += v1 * s1.w;
        a2.x += v2 * s2.x; a2.y += v2 * s2.y; a2.z += v2 * s2.z; a2.w += v2 * s2.w;
        a3.x += v3 * s3.x; a3.y += v3 * s3.y; a3.z += v3 * s3.z; a3.w += v3 * s3.w;
    }
    for (; j < end; ++j) {
        unsigned int p = epack[j];
        unsigned int u = ((const unsigned int*)(xw8 + (size_t)(p >> 16) * F2))[lane];
        float v = pe_val(p);
        float4 s = fp8x4_dec(u);
        a0.x += v * s.x; a0.y += v * s.y; a0.z += v * s.z; a0.w += v * s.w;
    }
    float4 a;
    a.x = a0.x + a1.x + a2.x + a3.x;
    a.y = a0.y + a1.y + a2.y + a3.y;
    a.z = a0.z + a1.z + a2.z + a3.z;
    a.w = a0.w + a1.w + a2.w + a3.w;

    a.x = fmaxf(a.x, 0.f); a.y = fmaxf(a.y, 0.f);
    a.z = fmaxf(a.z, 0.f); a.w = fmaxf(a.w, 0.f);

    float m = fmaxf(fmaxf(a.x, a.y), fmaxf(a.z, a.w));
#pragma unroll
    for (int off = 16; off; off >>= 1) m = fmaxf(m, __shfl_xor(m, off));
    float ex = __expf(a.x - m), ey = __expf(a.y - m);
    float ez = __expf(a.z - m), ew = __expf(a.w - m);
    float ssum = ex + ey + ez + ew;
#pragma unroll
    for (int off = 16; off; off >>= 1) ssum += __shfl_xor(ssum, off);
    float inv = 1.f / ssum;

    bool isP = lane < 32;
    float wx = isP ? ex * inv : a.x;
    float wy = isP ? ey * inv : a.y;
    float wz = isP ? ez * inv : a.z;
    float ww = isP ? ew * inv : a.w;
    ((uint2*)(pqh + (size_t)row * F2))[lane] =
        make_uint2(f2_to_h2u(wx, wy), f2_to_h2u(wz, ww));
    if (isP) {
        unsigned int pk = (unsigned int)f32_to_fp8(wx * 256.f)
                        | ((unsigned int)f32_to_fp8(wy * 256.f) << 8)
                        | ((unsigned int)f32_to_fp8(wz * 256.f) << 16)
                        | ((unsigned int)f32_to_fp8(ww * 256.f) << 24);
        ((unsigned int*)(s8 + (size_t)row * KC))[lane] = pk;
    }
}

// ---------------------------------------------------------------------------
// K4: AS = A @ S via fp8 gather of s8 (=256*S); 1/256 folded into edge val.
// ---------------------------------------------------------------------------
__global__ __launch_bounds__(256) void spmm_s_csr(
    const int* __restrict__ row_start, const unsigned int* __restrict__ epack,
    const unsigned char* __restrict__ s8, __half* __restrict__ ash, int n_nodes)
{
    int row = blockIdx.x * 4 + (threadIdx.x >> 6);
    if (row >= n_nodes) return;
    int lane = threadIdx.x & 63;
    int beg = row_start[row], end = row_start[row + 1];

    float2 a0 = {0,0}, a1 = {0,0}, a2 = {0,0}, a3 = {0,0};
    int j = beg;
    for (; j + 3 < end; j += 4) {
        unsigned int p0 = epack[j],     p1 = epack[j + 1];
        unsigned int p2 = epack[j + 2], p3 = epack[j + 3];
        unsigned int u0 = ((const unsigned short*)(s8 + (size_t)(p0 >> 16) * KC))[lane];
        unsigned int u1 = ((const unsigned short*)(s8 + (size_t)(p1 >> 16) * KC))[lane];
        unsigned int u2 = ((const unsigned short*)(s8 + (size_t)(p2 >> 16) * KC))[lane];
        unsigned int u3 = ((const unsigned short*)(s8 + (size_t)(p3 >> 16) * KC))[lane];
        float v0 = pe_val(p0) * (1.f / 256.f), v1 = pe_val(p1) * (1.f / 256.f);
        float v2 = pe_val(p2) * (1.f / 256.f), v3 = pe_val(p3) * (1.f / 256.f);
        float2 f0 = fp8x2_dec(u0), f1 = fp8x2_dec(u1);
        float2 f2 = fp8x2_dec(u2), f3 = fp8x2_dec(u3);
        a0.x += v0 * f0.x; a0.y += v0 * f0.y;
        a1.x += v1 * f1.x; a1.y += v1 * f1.y;
        a2.x += v2 * f2.x; a2.y += v2 * f2.y;
        a3.x += v3 * f3.x; a3.y += v3 * f3.y;
    }
    for (; j < end; ++j) {
        unsigned int p = epack[j];
        unsigned int u = ((const unsigned short*)(s8 + (size_t)(p >> 16) * KC))[lane];
        float v = pe_val(p) * (1.f / 256.f);
        float2 f = fp8x2_dec(u);
        a0.x += v * f.x; a0.y += v * f.y;
    }
    float rx = a0.x + a1.x + a2.x + a3.x;
    float ry = a0.y + a1.y + a2.y + a3.y;
    union { __half2 h; unsigned int i; } o;
    o.h = __floats2half2_rn(rx, ry);
    ((unsigned int*)(ash + (size_t)row * KC))[lane] = o.i;
}

// ---------------------------------------------------------------------------
// K5a: coarse partials via MFMA. which = blockIdx.y (0: S^T@AS, 1: S^T@Z).
// Per 32-node step: stage S,V tiles TRANSPOSED in LDS ([128][LR] fp16, 80B
// rows -> fragments are single ds_read_b128), then 64 mfma_16x16x32_f16
// (4 waves x 2 m-blocks x 8 f-blocks, K=32 = whole tile).
// ---------------------------------------------------------------------------
__global__ __launch_bounds__(256) void coarse_part_mfma(
    const __half* __restrict__ pqh, const __half* __restrict__ ash,
    float* __restrict__ part, int n_nodes)
{
    __shared__ _Float16 sSt[128 * LR];   // S^T: [cluster m][node k]
    __shared__ _Float16 sVt[128 * LR];   // V^T: [feat f][node k]
    const int which = blockIdx.y;
    const int tid = threadIdx.x;
    const int w = tid >> 6, lane = tid & 63;
    const int nl = tid & 31;            // staging: node within tile
    const int c0 = (tid >> 5) * 16;     // staging: col group
    const int fr = lane & 15;
    const int fk = (lane >> 4) * 8;

    f32x4 acc[2][8];
#pragma unroll
    for (int b = 0; b < 2; ++b)
#pragma unroll
        for (int fb = 0; fb < 8; ++fb) acc[b][fb] = (f32x4){0.f, 0.f, 0.f, 0.f};

    const int stride = gridDim.x * 32;
    for (int n0 = blockIdx.x * 32; n0 < n_nodes; n0 += stride) {
        __syncthreads();
        int n = n0 + nl;
        if (n < n_nodes) {
            uint4 u0 = *(const uint4*)(pqh + (size_t)n * F2 + c0);
            uint4 u1 = *(const uint4*)(pqh + (size_t)n * F2 + c0 + 8);
            store_t16((unsigned short*)sSt, c0, nl, u0, u1);
            uint4 v0, v1;
            if (which) {
                v0 = *(const uint4*)(pqh + (size_t)n * F2 + KC + c0);
                v1 = *(const uint4*)(pqh + (size_t)n * F2 + KC + c0 + 8);
            } else {
                v0 = *(const uint4*)(ash + (size_t)n * KC + c0);
                v1 = *(const uint4*)(ash + (size_t)n * KC + c0 + 8);
            }
            store_t16((unsigned short*)sVt, c0, nl, v0, v1);
        } else {
#pragma unroll
            for (int i = 0; i < 16; ++i) {
                sSt[(c0 + i) * LR + nl] = (_Float16)0.f;
                sVt[(c0 + i) * LR + nl] = (_Float16)0.f;
            }
        }
        __syncthreads();

        f16x8 a0 = *(const f16x8*)(&sSt[((2 * w + 0) * 16 + fr) * LR + fk]);
        f16x8 a1 = *(const f16x8*)(&sSt[((2 * w + 1) * 16 + fr) * LR + fk]);
#pragma unroll
        for (int fb = 0; fb < 8; ++fb) {
            f16x8 bf = *(const f16x8*)(&sVt[(fb * 16 + fr) * LR + fk]);
            acc[0][fb] = __builtin_amdgcn_mfma_f32_16x16x32_f16(a0, bf, acc[0][fb], 0, 0, 0);
            acc[1][fb] = __builtin_amdgcn_mfma_f32_16x16x32_f16(a1, bf, acc[1][fb], 0, 0, 0);
        }
    }

    float* p = part + ((size_t)which * gridDim.x + blockIdx.x) * (KC * KC);
    // C/D layout: col = lane&15, row = (lane>>4)*4 + reg
#pragma unroll
    for (int b = 0; b < 2; ++b) {
        int mbase = (2 * w + b) * 16 + (lane >> 4) * 4;
#pragma unroll
        for (int fb = 0; fb < 8; ++fb) {
            int f = fb * 16 + fr;
#pragma unroll
            for (int reg = 0; reg < 4; ++reg)
                p[(size_t)(mbase + reg) * KC + f] = acc[b][fb][reg];
        }
    }
}

// K5b stage 1: part2[s][e] = sum of this split's tiles (grid: 128 x NSPLIT)
__global__ __launch_bounds__(256) void coarse_reduce1(
    const float* __restrict__ part, float* __restrict__ part2, int nb)
{
    int e = blockIdx.x * 256 + threadIdx.x;
    int s = blockIdx.y;
    int which = e >> 14;
    int idx = e & 16383;
    int tpb = nb / NSPLIT;
    const float* p = part + ((size_t)which * nb + (size_t)s * tpb) * (KC * KC) + idx;
    float sum = 0.f;
    for (int t = 0; t < tpb; ++t) sum += p[(size_t)t * (KC * KC)];
    part2[(size_t)s * (2 * KC * KC) + e] = sum;
}

// K5b stage 2: out[e] = sum over NSPLIT partials (full overwrite of d_out)
__global__ __launch_bounds__(256) void coarse_reduce2(
    const float* __restrict__ part2, float* __restrict__ out)
{
    int e = blockIdx.x * 256 + threadIdx.x;
    float s = 0.f;
#pragma unroll
    for (int i = 0; i < NSPLIT; ++i) s += part2[(size_t)i * (2 * KC * KC) + e];
    out[e] = s;
}

// ---------------------------------------------------------------------------
// Fallback f32 atomic path
// ---------------------------------------------------------------------------
__global__ __launch_bounds__(256) void gemm_xw_f(
    const float* __restrict__ x, const float* __restrict__ Wp,
    const float* __restrict__ We, float* __restrict__ xw, int n_nodes)
{
    constexpr int RPB = 32;
    __shared__ float xs[RPB][F_IN];
    const int r0 = blockIdx.x * RPB;
    const int tid = threadIdx.x;
    for (int i = tid; i < RPB * F_IN; i += 256) {
        int r = i >> 7, c = i & 127;
        int gr = r0 + r;
        xs[r][c] = (gr < n_nodes) ? x[(size_t)gr * F_IN + c] : 0.f;
    }
    __syncthreads();
    const int col = tid;
    const float* W = (col < KC) ? (Wp + col) : (We + (col - KC));
    float acc[RPB];
#pragma unroll
    for (int r = 0; r < RPB; ++r) acc[r] = 0.f;
    for (int k = 0; k < F_IN; ++k) {
        float w = W[(size_t)k * KC];
        const float* xk = &xs[0][k];
#pragma unroll
        for (int r = 0; r < RPB; ++r) acc[r] += xk[r * F_IN] * w;
    }
#pragma unroll
    for (int r = 0; r < RPB; ++r) {
        int gr = r0 + r;
        if (gr < n_nodes) xw[(size_t)gr * F2 + col] = acc[r];
    }
}

__global__ __launch_bounds__(256) void spmm_dual_kernel(
    const int* __restrict__ erow, const int* __restrict__ ecol,
    const float* __restrict__ eval_, const float* __restrict__ xw,
    float* __restrict__ pq, int n_edges)
{
    int e = blockIdx.x * 4 + (threadIdx.x >> 6);
    if (e >= n_edges) return;
    int lane = threadIdx.x & 63;
    int r = erow[e], c = ecol[e];
    float v = eval_[e];
    const float4* src = (const float4*)(xw + (size_t)c * F2);
    float* dst = pq + (size_t)r * F2;
    float4 s = src[lane];
    int f = lane * 4;
    atomicAdd(&dst[f + 0], v * s.x);
    atomicAdd(&dst[f + 1], v * s.y);
    atomicAdd(&dst[f + 2], v * s.z);
    atomicAdd(&dst[f + 3], v * s.w);
}

__global__ __launch_bounds__(64) void softmax_relu_kernel(
    float* __restrict__ pq, int n_nodes)
{
    int n = blockIdx.x;
    if (n >= n_nodes) return;
    int lane = threadIdx.x;
    float* p = pq + (size_t)n * F2;
    float a0 = fmaxf(p[lane], 0.f);
    float a1 = fmaxf(p[lane + 64], 0.f);
    float m = fmaxf(a0, a1);
#pragma unroll
    for (int off = 32; off; off >>= 1) m = fmaxf(m, __shfl_xor(m, off));
    float e0 = __expf(a0 - m), e1 = __expf(a1 - m);
    float ssum = e0 + e1;
#pragma unroll
    for (int off = 32; off; off >>= 1) ssum += __shfl_xor(ssum, off);
    float inv = 1.f / ssum;
    p[lane]      = e0 * inv;
    p[lane + 64] = e1 * inv;
    p[lane + 128] = fmaxf(p[lane + 128], 0.f);
    p[lane + 192] = fmaxf(p[lane + 192], 0.f);
}

__global__ __launch_bounds__(256) void spmm_s_kernel(
    const int* __restrict__ erow, const int* __restrict__ ecol,
    const float* __restrict__ eval_, const float* __restrict__ pq,
    float* __restrict__ as_, int n_edges)
{
    int e = blockIdx.x * 4 + (threadIdx.x >> 6);
    if (e >= n_edges) return;
    int lane = threadIdx.x & 63;
    int r = erow[e], c = ecol[e];
    float v = eval_[e];
    const float2* src = (const float2*)(pq + (size_t)c * F2);
    float* dst = as_ + (size_t)r * KC;
    float2 s = src[lane];
    int f = lane * 2;
    atomicAdd(&dst[f + 0], v * s.x);
    atomicAdd(&dst[f + 1], v * s.y);
}

__global__ __launch_bounds__(256) void coarse_f(
    const float* __restrict__ pq, const float* __restrict__ as_,
    float* __restrict__ out, int n_nodes)
{
    const int which = blockIdx.y;
    const int tid = threadIdx.x;
    const int f  = tid & 127;
    const int k0 = (tid >> 7) * 64;
    __shared__ float sS[8][128];
    float acc[64];
#pragma unroll
    for (int i = 0; i < 64; ++i) acc[i] = 0.f;
    const int stride = gridDim.x * 8;
    for (int n0 = blockIdx.x * 8; n0 < n_nodes; n0 += stride) {
        __syncthreads();
        for (int i = tid; i < 8 * 128; i += 256) {
            int rr = i >> 7, cc = i & 127;
            int n = n0 + rr;
            sS[rr][cc] = (n < n_nodes) ? pq[(size_t)n * F2 + cc] : 0.f;
        }
        __syncthreads();
        int rmax = (n_nodes - n0 < 8) ? (n_nodes - n0) : 8;
        for (int rr = 0; rr < rmax; ++rr) {
            int n = n0 + rr;
            float v = which ? pq[(size_t)n * F2 + KC + f]
                            : as_[(size_t)n * KC + f];
            const float4* s4 = (const float4*)(&sS[rr][k0]);
#pragma unroll
            for (int i = 0; i < 16; ++i) {
                float4 sv = s4[i];
                acc[4 * i + 0] += sv.x * v;
                acc[4 * i + 1] += sv.y * v;
                acc[4 * i + 2] += sv.z * v;
                acc[4 * i + 3] += sv.w * v;
            }
        }
    }
    float* o = out + (size_t)which * (KC * KC);
#pragma unroll
    for (int i = 0; i < 64; ++i)
        atomicAdd(&o[(size_t)(k0 + i) * KC + f], acc[i]);
}

// ---------------------------------------------------------------------------
extern "C" void kernel_launch(void* const* d_in, const int* in_sizes, int n_in,
                              void* d_out, int out_size, void* d_ws, size_t ws_size,
                              hipStream_t stream)
{
    const float* x     = (const float*)d_in[0];
    const int*   erow  = (const int*)d_in[1];
    const int*   ecol  = (const int*)d_in[2];
    const float* eval_ = (const float*)d_in[3];
    const float* Wp    = (const float*)d_in[4];
    const float* We    = (const float*)d_in[5];
    float* out = (float*)d_out;

    const int n_nodes = in_sizes[0] / F_IN;
    const int n_edges = in_sizes[1];
    const int nbin = (n_nodes + (1 << BIN_SHIFT) - 1) >> BIN_SHIFT;
    const int M = nbin * NBLK_SORT;
    const int mchunks = (M + 1023) / 1024;
    const int epb = (n_edges + NBLK_SORT - 1) / NBLK_SORT;

    char* base = (char*)d_ws;
    size_t off = 0;
    auto alloc = [&](size_t bytes) -> void* {
        off = (off + 255) & ~(size_t)255;
        void* p = base + off;
        off += bytes;
        return p;
    };
    unsigned char* xw8  = (unsigned char*)alloc((size_t)n_nodes * F2);
    __half* pqh         = (__half*)alloc((size_t)n_nodes * F2 * 2);
    __half* ash         = (__half*)alloc((size_t)n_nodes * KC * 2);
    unsigned char* s8   = (unsigned char*)alloc((size_t)n_nodes * KC);
    int* row_start      = (int*)alloc(((size_t)n_nodes + 1) * 4);
    unsigned int* epack = (unsigned int*)alloc((size_t)n_edges * 4);
    unsigned int* ebin_cv = (unsigned int*)alloc((size_t)n_edges * 4);
    unsigned char* ebin_r8 = (unsigned char*)alloc((size_t)n_edges);
    int* Cmat           = (int*)alloc((size_t)M * 4);
    int* Coff           = (int*)alloc(((size_t)M + 1) * 4);
    int* chunk_sum      = (int*)alloc(1024 * 4);
    int* chunk_base     = (int*)alloc(1024 * 4);
    __half* wt          = (__half*)alloc((size_t)F2 * F_IN * 2);
    float* part         = (float*)alloc((size_t)2 * NB_COARSE * KC * KC * 4);
    float* part2        = (float*)alloc((size_t)NSPLIT * 2 * KC * KC * 4);
    const size_t needed_h = off;

    if (n_nodes <= 65535 && nbin <= MAXBIN && mchunks <= 1024 && ws_size >= needed_h) {
        // ---- fast fp8/fp16 counting-sort + MFMA path ----
        transpose_w<<<F2, 128, 0, stream>>>(Wp, We, wt);
        gemm_xw_mfma<<<(n_nodes + 31) / 32, 256, 0, stream>>>(x, wt, xw8, n_nodes);

        bin_count<<<NBLK_SORT, 256, 0, stream>>>(erow, Cmat, n_edges, nbin, epb);
        scan_local<<<mchunks, 1024, 0, stream>>>(Cmat, Coff, chunk_sum, M);
        scan_chunks<<<1, 1024, 0, stream>>>(chunk_sum, chunk_base, Coff, mchunks, M);
        scan_add<<<(M + 255) / 256, 256, 0, stream>>>(Coff, chunk_base, M);
        bin_place<<<NBLK_SORT, 256, 0, stream>>>(erow, ecol, eval_, Coff,
                                                 ebin_cv, ebin_r8, n_edges, nbin, epb);
        bin_final<<<nbin, 256, 0, stream>>>(ebin_cv, ebin_r8, Coff, epack,
                                            row_start, n_nodes, nbin);

        spmm_dual_csr<<<(n_nodes + 3) / 4, 256, 0, stream>>>(
            row_start, epack, xw8, pqh, s8, n_nodes);
        spmm_s_csr<<<(n_nodes + 3) / 4, 256, 0, stream>>>(
            row_start, epack, s8, ash, n_nodes);

        coarse_part_mfma<<<dim3(NB_COARSE, 2), 256, 0, stream>>>(pqh, ash, part, n_nodes);
        coarse_reduce1<<<dim3((2 * KC * KC) / 256, NSPLIT), 256, 0, stream>>>(
            part, part2, NB_COARSE);
        coarse_reduce2<<<(2 * KC * KC) / 256, 256, 0, stream>>>(part2, out);
    } else {
        // ---- f32 atomic fallback ----
        float* xw  = (float*)d_ws;
        float* pq  = xw + (size_t)n_nodes * F2;
        float* as_ = xw;
        hipMemsetAsync(d_out, 0, (size_t)out_size * sizeof(float), stream);
        gemm_xw_f<<<(n_nodes + 31) / 32, 256, 0, stream>>>(x, Wp, We, xw, n_nodes);
        hipMemsetAsync(pq, 0, (size_t)n_nodes * F2 * sizeof(float), stream);
        spmm_dual_kernel<<<(n_edges + 3) / 4, 256, 0, stream>>>(
            erow, ecol, eval_, xw, pq, n_edges);
        softmax_relu_kernel<<<n_nodes, 64, 0, stream>>>(pq, n_nodes);
        hipMemsetAsync(as_, 0, (size_t)n_nodes * KC * sizeof(float), stream);
        spmm_s_kernel<<<(n_edges + 3) / 4, 256, 0, stream>>>(
            erow, ecol, eval_, pq, as_, n_edges);
        coarse_f<<<dim3(128, 2), 256, 0, stream>>>(pq, as_, out, n_nodes);
    }
}